// Round 1
// baseline (2370.595 us; speedup 1.0000x reference)
//
#include <hip/hip_runtime.h>
#include <math.h>

#define N_ 8
#define C_ 128
#define T_ 64
#define V_ 204
#define K_ 3
#define H_ 3
#define QKD_ 32
#define O2_ 192            // 2*H*QKD
#define TV_ 13056          // T*V
#define CT_ 8192           // C*T
#define TT_ 4096           // T*T
#define NCTV_ 13369344ull  // N*C*T*V

// ---------------- positional encoding table pe[c*T+t] ----------------
__global__ void k_pe(float* __restrict__ pe) {
  int i = blockIdx.x * blockDim.x + threadIdx.x;
  if (i >= C_ * T_) return;
  int t = i % T_, c = i / T_;
  int j = c >> 1;
  float dv = expf((2.0f * j) * (-logf(10000.0f) / (float)C_));
  float ang = (float)t * dv;
  pe[i] = (c & 1) ? cosf(ang) : sinf(ang);
}

// ---------------- small transpose: out[c][r] = in[r][c] ----------------
__global__ void k_transpose(const float* __restrict__ in, float* __restrict__ out,
                            int R, int Cc) {
  int i = blockIdx.x * blockDim.x + threadIdx.x;
  if (i >= R * Cc) return;
  int r = i / Cc, c = i % Cc;
  out[c * R + r] = in[i];
}

// ---------------- s[n,c,t] = 1/max(||x[n,c,t,:]||,1e-12)^2 ----------------
__global__ void k_scale(const float* __restrict__ x, float* __restrict__ s) {
  int gid = blockIdx.x * blockDim.x + threadIdx.x;
  int w = gid >> 6, lane = gid & 63;
  if (w >= N_ * CT_) return;
  const float* row = x + (size_t)w * V_;
  float a = 0.f;
  for (int v = lane; v < V_; v += 64) { float t = row[v]; a += t * t; }
#pragma unroll
  for (int off = 32; off >= 1; off >>= 1) a += __shfl_down(a, off, 64);
  if (lane == 0) {
    float d = fmaxf(sqrtf(a), 1e-12f);
    s[w] = 1.0f / (d * d);
  }
}

// ---------------- dis[n,u,v] = sum_{ct} x[n,ct,u]*s[n,ct]*x[n,ct,v] ----------------
__global__ __launch_bounds__(256) void k_dis(const float* __restrict__ x,
                                             const float* __restrict__ s,
                                             float* __restrict__ dis) {
  int n = blockIdx.z;
  int u0 = blockIdx.y * 64, v0 = blockIdx.x * 64;
  __shared__ float Au[32][64], Av[32][64];
  int tid = threadIdx.x;
  int ty = tid >> 4, tx = tid & 15;
  float acc[4][4] = {};
  const float* xb = x + (size_t)n * CT_ * V_;
  const float* sb = s + (size_t)n * CT_;
  for (int k0 = 0; k0 < CT_; k0 += 32) {
    int uu = tid & 63, kk = tid >> 6;
#pragma unroll
    for (int it = 0; it < 8; ++it) {
      int krow = kk + it * 4;
      const float* xr = xb + (size_t)(k0 + krow) * V_;
      float sv = sb[k0 + krow];
      int u = u0 + uu, v = v0 + uu;
      Au[krow][uu] = (u < V_) ? xr[u] * sv : 0.f;
      Av[krow][uu] = (v < V_) ? xr[v] : 0.f;
    }
    __syncthreads();
#pragma unroll
    for (int kk2 = 0; kk2 < 32; ++kk2) {
      float4 a = *(const float4*)&Au[kk2][ty * 4];
      float4 b = *(const float4*)&Av[kk2][tx * 4];
      float av[4] = {a.x, a.y, a.z, a.w}, bv[4] = {b.x, b.y, b.z, b.w};
#pragma unroll
      for (int i = 0; i < 4; ++i)
#pragma unroll
        for (int j = 0; j < 4; ++j) acc[i][j] += av[i] * bv[j];
    }
    __syncthreads();
  }
#pragma unroll
  for (int i = 0; i < 4; ++i) {
    int u = u0 + ty * 4 + i;
    if (u >= V_) continue;
#pragma unroll
    for (int j = 0; j < 4; ++j) {
      int v = v0 + tx * 4 + j;
      if (v < V_) dis[((size_t)n * V_ + u) * V_ + v] = acc[i][j];
    }
  }
}

// ---------------- top-3 per (n,u) row, jax.lax.top_k tie semantics ----------------
__global__ void k_topk(const float* __restrict__ dis, int* __restrict__ idx) {
  int r = blockIdx.x * blockDim.x + threadIdx.x;
  if (r >= N_ * V_) return;
  const float* row = dis + (size_t)r * V_;
  float m0 = -INFINITY, m1 = -INFINITY, m2 = -INFINITY;
  int i0 = 0, i1 = 0, i2 = 0;
  for (int v = 0; v < V_; ++v) {
    float d = row[v];
    if (d > m0)      { m2 = m1; i2 = i1; m1 = m0; i1 = i0; m0 = d; i0 = v; }
    else if (d > m1) { m2 = m1; i2 = i1; m1 = d; i1 = v; }
    else if (d > m2) { m2 = d; i2 = v; }
  }
  idx[r * 3 + 0] = i0; idx[r * 3 + 1] = i1; idx[r * 3 + 2] = i2;
}

// ---------------- colmean[n,c,v] = mean_t x[n,c,t,v] ----------------
__global__ void k_colmean(const float* __restrict__ x, float* __restrict__ cm) {
  int nc = blockIdx.x;
  int v = threadIdx.x;
  if (v >= V_) return;
  const float* base = x + (size_t)nc * TV_;
  float acc = 0.f;
  for (int t = 0; t < T_; ++t) acc += base[t * V_ + v];
  cm[(size_t)nc * V_ + v] = acc * (1.0f / T_);
}

// ---------------- w2[n,v,g] = sum_p softmax_p(mult[n,v,g,:])*convk_w[p] ----------------
__global__ void k_w2(const float* __restrict__ cm, const int* __restrict__ idx,
                     const float* __restrict__ tw, const float* __restrict__ tb,
                     const float* __restrict__ ckw, float* __restrict__ w2) {
  int r = blockIdx.x;  // n*V + v
  int n = r / V_;
  int lane = threadIdx.x;
  __shared__ float mv[3][C_];
  const int* ib = idx + r * 3;
  int j0 = ib[0], j1 = ib[1], j2 = ib[2];
  const float* cmn = cm + (size_t)n * C_ * V_;
  for (int c = lane; c < C_; c += 64) {
    mv[0][c] = cmn[c * V_ + j0];
    mv[1][c] = cmn[c * V_ + j1];
    mv[2][c] = cmn[c * V_ + j2];
  }
  __syncthreads();
  float p[9];
#pragma unroll
  for (int gp = 0; gp < 9; ++gp) p[gp] = 0.f;
  for (int c = lane; c < C_; c += 64) {
#pragma unroll
    for (int g = 0; g < 3; ++g) {
      float m = mv[g][c];
#pragma unroll
      for (int pp = 0; pp < 3; ++pp) p[g * 3 + pp] += m * tw[(g * 3 + pp) * C_ + c];
    }
  }
#pragma unroll
  for (int off = 32; off >= 1; off >>= 1) {
#pragma unroll
    for (int gp = 0; gp < 9; ++gp) p[gp] += __shfl_down(p[gp], off, 64);
  }
  if (lane == 0) {
    float c0 = ckw[0], c1 = ckw[1], c2 = ckw[2];
#pragma unroll
    for (int g = 0; g < 3; ++g) {
      float m0 = p[g * 3 + 0] + tb[g * 3 + 0];
      float m1 = p[g * 3 + 1] + tb[g * 3 + 1];
      float m2 = p[g * 3 + 2] + tb[g * 3 + 2];
      float mx = fmaxf(m0, fmaxf(m1, m2));
      float e0 = expf(m0 - mx), e1 = expf(m1 - mx), e2 = expf(m2 - mx);
      float inv = 1.0f / (e0 + e1 + e2);
      w2[r * 3 + g] = (e0 * c0 + e1 * c1 + e2 * c2) * inv;
    }
  }
}

// ---------------- x1 = relu(sum_k x[...,idx_k]*w2_k + convk_b + x) ----------------
__global__ void k_x1(const float* __restrict__ x, const int* __restrict__ idx,
                     const float* __restrict__ w2, const float* __restrict__ ckb,
                     float* __restrict__ x1) {
  float cb = ckb[0];
  for (size_t i = blockIdx.x * 256ull + threadIdx.x; i < NCTV_;
       i += (size_t)gridDim.x * 256ull) {
    int v = (int)(i % V_);
    size_t r = i / V_;
    int n = (int)(r / CT_);
    const float* xrow = x + r * V_;
    int b = (n * V_ + v) * 3;
    float pooled = xrow[idx[b]] * w2[b] + xrow[idx[b + 1]] * w2[b + 1] +
                   xrow[idx[b + 2]] * w2[b + 2] + cb;
    float val = fmaxf(pooled + xrow[v], 0.f);
    x1[i] = val;
  }
}

// ---------------- generic GEMM: Y[n,m,l] = sum_k Wt[k,m]*(X[n,k,l]+pe?) (+bias / +=) ----
__global__ __launch_bounds__(256) void k_gemm(const float* __restrict__ Wt, int ldw,
                                              const float* __restrict__ X,
                                              const float* __restrict__ pe,
                                              const float* __restrict__ bias,
                                              float* __restrict__ Y,
                                              int M, int Kd, int accumulate) {
  int n = blockIdx.z;
  int m0 = blockIdx.y * 64;
  int l0 = blockIdx.x * 128;
  __shared__ float Ws[32][64];
  __shared__ float Xs[32][128];
  int tid = threadIdx.x;
  int ty = tid >> 5, tx = tid & 31;
  float acc[8][4] = {};
  const float* Xn = X + (size_t)n * Kd * TV_;
  int mm = tid & 63, kkw = tid >> 6;
  int ll = tid & 127, k2 = tid >> 7;
  int tpe = (l0 + ll) / V_;  // t index for pe (fixed per thread)
  for (int k0 = 0; k0 < Kd; k0 += 32) {
#pragma unroll
    for (int it = 0; it < 8; ++it) {
      int krow = kkw + it * 4;
      Ws[krow][mm] = Wt[(size_t)(k0 + krow) * ldw + m0 + mm];
    }
    if (pe) {
#pragma unroll
      for (int it = 0; it < 16; ++it) {
        int k = k0 + k2 + it * 2;
        Xs[k2 + it * 2][ll] = Xn[(size_t)k * TV_ + l0 + ll] + pe[k * T_ + tpe];
      }
    } else {
#pragma unroll
      for (int it = 0; it < 16; ++it) {
        int k = k0 + k2 + it * 2;
        Xs[k2 + it * 2][ll] = Xn[(size_t)k * TV_ + l0 + ll];
      }
    }
    __syncthreads();
#pragma unroll
    for (int kk = 0; kk < 32; ++kk) {
      float4 a0 = *(const float4*)&Ws[kk][ty * 8];
      float4 a1 = *(const float4*)&Ws[kk][ty * 8 + 4];
      float4 b = *(const float4*)&Xs[kk][tx * 4];
      float av[8] = {a0.x, a0.y, a0.z, a0.w, a1.x, a1.y, a1.z, a1.w};
      float bv[4] = {b.x, b.y, b.z, b.w};
#pragma unroll
      for (int i = 0; i < 8; ++i)
#pragma unroll
        for (int j = 0; j < 4; ++j) acc[i][j] += av[i] * bv[j];
    }
    __syncthreads();
  }
#pragma unroll
  for (int i = 0; i < 8; ++i) {
    int m = m0 + ty * 8 + i;
    size_t o = ((size_t)n * M + m) * TV_ + l0 + tx * 4;
    float4* yp = (float4*)(Y + o);
    float4 r = make_float4(acc[i][0], acc[i][1], acc[i][2], acc[i][3]);
    if (accumulate) {
      float4 old = *yp;
      r.x += old.x; r.y += old.y; r.z += old.z; r.w += old.w;
    } else {
      float bb = bias[m];
      r.x += bb; r.y += bb; r.z += bb; r.w += bb;
    }
    *yp = r;
  }
}

__global__ void k_zero(float* __restrict__ p, int nel) {
  int i = blockIdx.x * blockDim.x + threadIdx.x;
  if (i < nel) p[i] = 0.f;
}

// ---------------- attention raw: partial over c-pairs, atomicAdd ----------------
__global__ __launch_bounds__(256) void k_att(const float* __restrict__ qkv,
                                             float* __restrict__ attraw) {
  int n = blockIdx.z, h = blockIdx.y, cp = blockIdx.x;  // cp in [0,16)
  __shared__ float Qs[64][52], Ks[64][52];
  int tid = threadIdx.x;
  int ty = tid >> 4, tx = tid & 15;
  float acc[4][4] = {};
  const float* qb = qkv + ((size_t)n * O2_ + h * QKD_) * TV_;
  const float* kb = qkv + ((size_t)n * O2_ + H_ * QKD_ + h * QKD_) * TV_;
  for (int cc = 0; cc < 2; ++cc) {
    int c = cp * 2 + cc;
    for (int v0 = 0; v0 < V_; v0 += 51) {
      for (int i = tid; i < 64 * 51; i += 256) {
        int t = i / 51, vv = i % 51;
        size_t gi = (size_t)(c * T_ + t) * V_ + v0 + vv;
        Qs[t][vv] = qb[gi];
        Ks[t][vv] = kb[gi];
      }
      __syncthreads();
      for (int vv = 0; vv < 51; ++vv) {
        float av[4], bv[4];
#pragma unroll
        for (int i = 0; i < 4; ++i) av[i] = Qs[ty * 4 + i][vv];
#pragma unroll
        for (int j = 0; j < 4; ++j) bv[j] = Ks[tx * 4 + j][vv];
#pragma unroll
        for (int i = 0; i < 4; ++i)
#pragma unroll
          for (int j = 0; j < 4; ++j) acc[i][j] += av[i] * bv[j];
      }
      __syncthreads();
    }
  }
  float* ar = attraw + (size_t)(n * H_ + h) * TT_;
#pragma unroll
  for (int i = 0; i < 4; ++i)
#pragma unroll
    for (int j = 0; j < 4; ++j)
      atomicAdd(&ar[(ty * 4 + i) * T_ + tx * 4 + j], acc[i][j]);
}

__global__ void k_attfin(const float* __restrict__ raw, const float* __restrict__ alphas,
                         const float* __restrict__ att1s, float* __restrict__ att) {
  int i = blockIdx.x * blockDim.x + threadIdx.x;
  if (i >= N_ * H_ * TT_) return;
  int tt = i % TT_;
  int h = (i / TT_) % H_;
  att[i] = tanhf(raw[i] * (1.0f / 6528.0f)) * alphas[h] + att1s[h * TT_ + tt];
}

// ---------------- xs2_h[n,c,q,v] = sum_t att[n,h,t,q]*x1[n,c,t,v] ----------------
__global__ __launch_bounds__(256) void k_xs2(const float* __restrict__ x1,
                                             const float* __restrict__ att, int h,
                                             float* __restrict__ out) {
  int nc = blockIdx.x;
  int n = nc >> 7;
  __shared__ float As[TT_];        // [t][q]
  __shared__ float Xs[T_ * 208];   // padded rows
  int tid = threadIdx.x;
  const float* ab = att + (size_t)(n * H_ + h) * TT_;
  for (int i = tid; i < TT_; i += 256) As[i] = ab[i];
  const float* xb = x1 + (size_t)nc * TV_;
  for (int i = tid; i < TV_; i += 256) {
    int t = i / V_, v = i % V_;
    Xs[t * 208 + v] = xb[i];
  }
  for (int i = tid; i < T_; i += 256) {
    Xs[i * 208 + 204] = 0.f; Xs[i * 208 + 205] = 0.f;
    Xs[i * 208 + 206] = 0.f; Xs[i * 208 + 207] = 0.f;
  }
  __syncthreads();
  int ty = tid >> 4, tx = tid & 15;
  float* ob = out + (size_t)nc * TV_;
  for (int v0 = 0; v0 < V_; v0 += 64) {
    float acc[4][4] = {};
    for (int t = 0; t < T_; ++t) {
      float4 a = *(const float4*)&As[t * 64 + ty * 4];
      float4 b = *(const float4*)&Xs[t * 208 + v0 + tx * 4];
      float av[4] = {a.x, a.y, a.z, a.w}, bv[4] = {b.x, b.y, b.z, b.w};
#pragma unroll
      for (int i = 0; i < 4; ++i)
#pragma unroll
        for (int j = 0; j < 4; ++j) acc[i][j] += av[i] * bv[j];
    }
#pragma unroll
    for (int i = 0; i < 4; ++i) {
      int q = ty * 4 + i;
#pragma unroll
      for (int j = 0; j < 4; ++j) {
        int v = v0 + tx * 4 + j;
        if (v < V_) ob[q * V_ + v] = acc[i][j];
      }
    }
  }
}

// ---------------- BN stats per channel (biased var) ----------------
__global__ void k_bnstats(const float* __restrict__ xp, float* __restrict__ mu,
                          float* __restrict__ rstd) {
  int c = blockIdx.x;
  int tid = threadIdx.x;
  float s1 = 0.f, s2 = 0.f;
  for (int i = tid; i < N_ * TV_; i += 256) {
    int n = i / TV_, l = i - n * TV_;
    float v = xp[((size_t)n * C_ + c) * TV_ + l];
    s1 += v; s2 += v * v;
  }
  __shared__ float r1[256], r2[256];
  r1[tid] = s1; r2[tid] = s2;
  __syncthreads();
  for (int off = 128; off >= 1; off >>= 1) {
    if (tid < off) { r1[tid] += r1[tid + off]; r2[tid] += r2[tid + off]; }
    __syncthreads();
  }
  if (tid == 0) {
    const float cnt = (float)(N_ * TV_);
    float m = r1[0] / cnt;
    float var = r2[0] / cnt - m * m;
    mu[c] = m;
    rstd[c] = rsqrtf(var + 1e-5f);
  }
}

// ---------------- leaky_relu(bn(xp)+x1) ----------------
__global__ void k_bnres(const float* __restrict__ xp, const float* __restrict__ mu,
                        const float* __restrict__ rstd, const float* __restrict__ g,
                        const float* __restrict__ beta, const float* __restrict__ x1,
                        float* __restrict__ out) {
  for (size_t i = blockIdx.x * 256ull + threadIdx.x; i < NCTV_;
       i += (size_t)gridDim.x * 256ull) {
    int c = (int)((i / TV_) % C_);
    float v = (xp[i] - mu[c]) * rstd[c] * g[c] + beta[c] + x1[i];
    out[i] = v > 0.f ? v : 0.1f * v;
  }
}

extern "C" void kernel_launch(void* const* d_in, const int* in_sizes, int n_in,
                              void* d_out, int out_size, void* d_ws, size_t ws_size,
                              hipStream_t stream) {
  (void)in_sizes; (void)n_in; (void)out_size; (void)ws_size;
  const float* x        = (const float*)d_in[0];
  const float* trans_w  = (const float*)d_in[1];
  const float* trans_b  = (const float*)d_in[2];
  const float* convk_w  = (const float*)d_in[3];
  const float* convk_b  = (const float*)d_in[4];
  const float* qkv_w    = (const float*)d_in[5];
  const float* qkv_b    = (const float*)d_in[6];
  const float* alphas   = (const float*)d_in[7];
  const float* att1s    = (const float*)d_in[8];
  const float* out_w    = (const float*)d_in[9];
  const float* out_b    = (const float*)d_in[10];
  const float* out_g    = (const float*)d_in[11];
  const float* out_beta = (const float*)d_in[12];
  const float* ff_w     = (const float*)d_in[13];
  const float* ff_b     = (const float*)d_in[14];
  const float* ff_g     = (const float*)d_in[15];
  const float* ff_beta  = (const float*)d_in[16];

  float* ws = (float*)d_ws;
  size_t o_x1   = 0;                                  // N*C*T*V
  size_t o_big  = o_x1 + NCTV_;                       // N*192*T*V (qkv -> out_pre -> ff_pre)
  size_t o_s    = o_big + (size_t)N_ * O2_ * TV_;     // N*C*T
  size_t o_dis  = o_s + (size_t)N_ * CT_;             // N*V*V
  size_t o_idx  = o_dis + (size_t)N_ * V_ * V_;       // N*V*3 ints
  size_t o_cm   = o_idx + (size_t)N_ * V_ * 3;        // N*C*V
  size_t o_w2   = o_cm + (size_t)N_ * C_ * V_;        // N*V*3
  size_t o_pe   = o_w2 + (size_t)N_ * V_ * 3;         // C*T
  size_t o_araw = o_pe + (size_t)C_ * T_;             // N*H*T*T
  size_t o_att  = o_araw + (size_t)N_ * H_ * TT_;     // N*H*T*T
  size_t o_bn   = o_att + (size_t)N_ * H_ * TT_;      // 4*C
  size_t o_qkvT = o_bn + 4 * C_;                      // 128*192
  size_t o_outT = o_qkvT + 128 * 192;                 // 384*128
  size_t o_ffT  = o_outT + 384 * 128;                 // 128*128

  float* x1   = ws + o_x1;
  float* big  = ws + o_big;
  float* sbuf = ws + o_s;
  float* dis  = ws + o_dis;
  int*   idx  = (int*)(ws + o_idx);
  float* cm   = ws + o_cm;
  float* w2   = ws + o_w2;
  float* pe   = ws + o_pe;
  float* araw = ws + o_araw;
  float* att  = ws + o_att;
  float* bn   = ws + o_bn;
  float* qkvT = ws + o_qkvT;
  float* outT = ws + o_outT;
  float* ffT  = ws + o_ffT;
  float* dout = (float*)d_out;  // also used as scratch for xs2_h / xs3

  k_pe<<<(C_ * T_ + 255) / 256, 256, 0, stream>>>(pe);
  k_transpose<<<(192 * 128 + 255) / 256, 256, 0, stream>>>(qkv_w, qkvT, 192, 128);
  k_transpose<<<(128 * 384 + 255) / 256, 256, 0, stream>>>(out_w, outT, 128, 384);
  k_transpose<<<(128 * 128 + 255) / 256, 256, 0, stream>>>(ff_w, ffT, 128, 128);

  k_scale<<<(N_ * CT_ * 64) / 256, 256, 0, stream>>>(x, sbuf);
  k_dis<<<dim3(4, 4, N_), 256, 0, stream>>>(x, sbuf, dis);
  k_topk<<<(N_ * V_ + 255) / 256, 256, 0, stream>>>(dis, idx);
  k_colmean<<<N_ * C_, 256, 0, stream>>>(x, cm);
  k_w2<<<N_ * V_, 64, 0, stream>>>(cm, idx, trans_w, trans_b, convk_w, w2);
  k_x1<<<4096, 256, 0, stream>>>(x, idx, w2, convk_b, x1);

  // qkv = W(xs= x1+pe) + b  -> big
  k_gemm<<<dim3(102, 3, N_), 256, 0, stream>>>(qkvT, 192, x1, pe, qkv_b, big, O2_, C_, 0);

  k_zero<<<(N_ * H_ * TT_ + 255) / 256, 256, 0, stream>>>(araw, N_ * H_ * TT_);
  k_att<<<dim3(16, H_, N_), 256, 0, stream>>>(big, araw);
  k_attfin<<<(N_ * H_ * TT_ + 255) / 256, 256, 0, stream>>>(araw, alphas, att1s, att);

  // out_pre = out_b + sum_h W_h @ xs2_h   (xs2_h staged in d_out)
  for (int h = 0; h < H_; ++h) {
    k_xs2<<<N_ * C_, 256, 0, stream>>>(x1, att, h, dout);
    k_gemm<<<dim3(102, 2, N_), 256, 0, stream>>>(outT + h * 128 * 128, 128, dout,
                                                 nullptr, out_b, big, C_, C_, h);
  }
  k_bnstats<<<C_, 256, 0, stream>>>(big, bn, bn + C_);
  k_bnres<<<4096, 256, 0, stream>>>(big, bn, bn + C_, out_g, out_beta, x1, dout); // xs3

  k_gemm<<<dim3(102, 2, N_), 256, 0, stream>>>(ffT, 128, dout, nullptr, ff_b, big, C_, C_, 0);
  k_bnstats<<<C_, 256, 0, stream>>>(big, bn + 2 * C_, bn + 3 * C_);
  k_bnres<<<4096, 256, 0, stream>>>(big, bn + 2 * C_, bn + 3 * C_, ff_g, ff_beta, x1, dout);
}

// Round 2
// 1213.270 us; speedup vs baseline: 1.9539x; 1.9539x over previous
//
#include <hip/hip_runtime.h>
#include <math.h>

#define N_ 8
#define C_ 128
#define T_ 64
#define V_ 204
#define K_ 3
#define H_ 3
#define QKD_ 32
#define O2_ 192            // 2*H*QKD
#define TV_ 13056          // T*V
#define CT_ 8192           // C*T
#define TT_ 4096           // T*T
#define VV_ 41616          // V*V
#define NCTV_ 13369344ull  // N*C*T*V
#define DSPLIT_ 16         // K-split factor for k_dis

// ---------------- positional encoding table pe[c*T+t] ----------------
__global__ void k_pe(float* __restrict__ pe) {
  int i = blockIdx.x * blockDim.x + threadIdx.x;
  if (i >= C_ * T_) return;
  int t = i % T_, c = i / T_;
  int j = c >> 1;
  float dv = expf((2.0f * j) * (-logf(10000.0f) / (float)C_));
  float ang = (float)t * dv;
  pe[i] = (c & 1) ? cosf(ang) : sinf(ang);
}

// ---------------- small transpose: out[c][r] = in[r][c] ----------------
__global__ void k_transpose(const float* __restrict__ in, float* __restrict__ out,
                            int R, int Cc) {
  int i = blockIdx.x * blockDim.x + threadIdx.x;
  if (i >= R * Cc) return;
  int r = i / Cc, c = i % Cc;
  out[c * R + r] = in[i];
}

// ---------------- s[n,c,t] = 1/max(||x[n,c,t,:]||,1e-12)^2 ----------------
__global__ void k_scale(const float* __restrict__ x, float* __restrict__ s) {
  int gid = blockIdx.x * blockDim.x + threadIdx.x;
  int w = gid >> 6, lane = gid & 63;
  if (w >= N_ * CT_) return;
  const float* row = x + (size_t)w * V_;
  float a = 0.f;
  for (int v = lane; v < V_; v += 64) { float t = row[v]; a += t * t; }
#pragma unroll
  for (int off = 32; off >= 1; off >>= 1) a += __shfl_down(a, off, 64);
  if (lane == 0) {
    float d = fmaxf(sqrtf(a), 1e-12f);
    s[w] = 1.0f / (d * d);
  }
}

// ---- dis partial: pdis[sp][n][u][v] = sum_{ct in slice} x[n,ct,u]*s[n,ct]*x[n,ct,v] ----
// grid (4, 4, N_*DSPLIT_): split the 8192-deep K reduction 16 ways for occupancy.
__global__ __launch_bounds__(256) void k_dis(const float* __restrict__ x,
                                             const float* __restrict__ s,
                                             float* __restrict__ pdis) {
  int zz = blockIdx.z;
  int n = zz / DSPLIT_, sp = zz % DSPLIT_;
  const int KCH = CT_ / DSPLIT_;  // 512
  int u0 = blockIdx.y * 64, v0 = blockIdx.x * 64;
  __shared__ float Au[32][64], Av[32][64];
  int tid = threadIdx.x;
  int ty = tid >> 4, tx = tid & 15;
  float acc[4][4] = {};
  const float* xb = x + (size_t)n * CT_ * V_;
  const float* sb = s + (size_t)n * CT_;
  int kbase = sp * KCH;
  for (int k0 = kbase; k0 < kbase + KCH; k0 += 32) {
    int uu = tid & 63, kk = tid >> 6;
#pragma unroll
    for (int it = 0; it < 8; ++it) {
      int krow = kk + it * 4;
      const float* xr = xb + (size_t)(k0 + krow) * V_;
      float sv = sb[k0 + krow];
      int u = u0 + uu, v = v0 + uu;
      Au[krow][uu] = (u < V_) ? xr[u] * sv : 0.f;
      Av[krow][uu] = (v < V_) ? xr[v] : 0.f;
    }
    __syncthreads();
#pragma unroll
    for (int kk2 = 0; kk2 < 32; ++kk2) {
      float4 a = *(const float4*)&Au[kk2][ty * 4];
      float4 b = *(const float4*)&Av[kk2][tx * 4];
      float av[4] = {a.x, a.y, a.z, a.w}, bv[4] = {b.x, b.y, b.z, b.w};
#pragma unroll
      for (int i = 0; i < 4; ++i)
#pragma unroll
        for (int j = 0; j < 4; ++j) acc[i][j] += av[i] * bv[j];
    }
    __syncthreads();
  }
  float* pb = pdis + ((size_t)sp * N_ + n) * VV_;
#pragma unroll
  for (int i = 0; i < 4; ++i) {
    int u = u0 + ty * 4 + i;
    if (u >= V_) continue;
#pragma unroll
    for (int j = 0; j < 4; ++j) {
      int v = v0 + tx * 4 + j;
      if (v < V_) pb[u * V_ + v] = acc[i][j];
    }
  }
}

// ---------------- deterministic fixed-order reduce of the 16 partials ----------------
__global__ void k_disreduce(const float* __restrict__ pdis, float* __restrict__ dis) {
  int i = blockIdx.x * blockDim.x + threadIdx.x;
  if (i >= N_ * VV_) return;
  float a = 0.f;
#pragma unroll
  for (int sp = 0; sp < DSPLIT_; ++sp) a += pdis[(size_t)sp * N_ * VV_ + i];
  dis[i] = a;
}

// ---------------- top-3 per (n,u) row, jax.lax.top_k tie semantics ----------------
__global__ void k_topk(const float* __restrict__ dis, int* __restrict__ idx) {
  int r = blockIdx.x * blockDim.x + threadIdx.x;
  if (r >= N_ * V_) return;
  const float* row = dis + (size_t)r * V_;
  float m0 = -INFINITY, m1 = -INFINITY, m2 = -INFINITY;
  int i0 = 0, i1 = 0, i2 = 0;
  for (int v = 0; v < V_; ++v) {
    float d = row[v];
    if (d > m0)      { m2 = m1; i2 = i1; m1 = m0; i1 = i0; m0 = d; i0 = v; }
    else if (d > m1) { m2 = m1; i2 = i1; m1 = d; i1 = v; }
    else if (d > m2) { m2 = d; i2 = v; }
  }
  idx[r * 3 + 0] = i0; idx[r * 3 + 1] = i1; idx[r * 3 + 2] = i2;
}

// ---------------- colmean[n,c,v] = mean_t x[n,c,t,v] ----------------
__global__ void k_colmean(const float* __restrict__ x, float* __restrict__ cm) {
  int nc = blockIdx.x;
  int v = threadIdx.x;
  if (v >= V_) return;
  const float* base = x + (size_t)nc * TV_;
  float acc = 0.f;
  for (int t = 0; t < T_; ++t) acc += base[t * V_ + v];
  cm[(size_t)nc * V_ + v] = acc * (1.0f / T_);
}

// ---------------- w2[n,v,g] = sum_p softmax_p(mult[n,v,g,:])*convk_w[p] ----------------
__global__ void k_w2(const float* __restrict__ cm, const int* __restrict__ idx,
                     const float* __restrict__ tw, const float* __restrict__ tb,
                     const float* __restrict__ ckw, float* __restrict__ w2) {
  int r = blockIdx.x;  // n*V + v
  int n = r / V_;
  int lane = threadIdx.x;
  __shared__ float mv[3][C_];
  const int* ib = idx + r * 3;
  int j0 = ib[0], j1 = ib[1], j2 = ib[2];
  const float* cmn = cm + (size_t)n * C_ * V_;
  for (int c = lane; c < C_; c += 64) {
    mv[0][c] = cmn[c * V_ + j0];
    mv[1][c] = cmn[c * V_ + j1];
    mv[2][c] = cmn[c * V_ + j2];
  }
  __syncthreads();
  float p[9];
#pragma unroll
  for (int gp = 0; gp < 9; ++gp) p[gp] = 0.f;
  for (int c = lane; c < C_; c += 64) {
#pragma unroll
    for (int g = 0; g < 3; ++g) {
      float m = mv[g][c];
#pragma unroll
      for (int pp = 0; pp < 3; ++pp) p[g * 3 + pp] += m * tw[(g * 3 + pp) * C_ + c];
    }
  }
#pragma unroll
  for (int off = 32; off >= 1; off >>= 1) {
#pragma unroll
    for (int gp = 0; gp < 9; ++gp) p[gp] += __shfl_down(p[gp], off, 64);
  }
  if (lane == 0) {
    float c0 = ckw[0], c1 = ckw[1], c2 = ckw[2];
#pragma unroll
    for (int g = 0; g < 3; ++g) {
      float m0 = p[g * 3 + 0] + tb[g * 3 + 0];
      float m1 = p[g * 3 + 1] + tb[g * 3 + 1];
      float m2 = p[g * 3 + 2] + tb[g * 3 + 2];
      float mx = fmaxf(m0, fmaxf(m1, m2));
      float e0 = expf(m0 - mx), e1 = expf(m1 - mx), e2 = expf(m2 - mx);
      float inv = 1.0f / (e0 + e1 + e2);
      w2[r * 3 + g] = (e0 * c0 + e1 * c1 + e2 * c2) * inv;
    }
  }
}

// ---------------- x1 = relu(sum_k x[...,idx_k]*w2_k + convk_b + x) ----------------
__global__ void k_x1(const float* __restrict__ x, const int* __restrict__ idx,
                     const float* __restrict__ w2, const float* __restrict__ ckb,
                     float* __restrict__ x1) {
  float cb = ckb[0];
  for (size_t i = blockIdx.x * 256ull + threadIdx.x; i < NCTV_;
       i += (size_t)gridDim.x * 256ull) {
    int v = (int)(i % V_);
    size_t r = i / V_;
    int n = (int)(r / CT_);
    const float* xrow = x + r * V_;
    int b = (n * V_ + v) * 3;
    float pooled = xrow[idx[b]] * w2[b] + xrow[idx[b + 1]] * w2[b + 1] +
                   xrow[idx[b + 2]] * w2[b + 2] + cb;
    float val = fmaxf(pooled + xrow[v], 0.f);
    x1[i] = val;
  }
}

// ---------------- generic GEMM: Y[n,m,l] = sum_k Wt[k,m]*(X[n,k,l]+pe?) (+bias / +=) ----
__global__ __launch_bounds__(256) void k_gemm(const float* __restrict__ Wt, int ldw,
                                              const float* __restrict__ X,
                                              const float* __restrict__ pe,
                                              const float* __restrict__ bias,
                                              float* __restrict__ Y,
                                              int M, int Kd, int accumulate) {
  int n = blockIdx.z;
  int m0 = blockIdx.y * 64;
  int l0 = blockIdx.x * 128;
  __shared__ float Ws[32][64];
  __shared__ float Xs[32][128];
  int tid = threadIdx.x;
  int ty = tid >> 5, tx = tid & 31;
  float acc[8][4] = {};
  const float* Xn = X + (size_t)n * Kd * TV_;
  int mm = tid & 63, kkw = tid >> 6;
  int ll = tid & 127, k2 = tid >> 7;
  int tpe = (l0 + ll) / V_;  // t index for pe (fixed per thread)
  for (int k0 = 0; k0 < Kd; k0 += 32) {
#pragma unroll
    for (int it = 0; it < 8; ++it) {
      int krow = kkw + it * 4;
      Ws[krow][mm] = Wt[(size_t)(k0 + krow) * ldw + m0 + mm];
    }
    if (pe) {
#pragma unroll
      for (int it = 0; it < 16; ++it) {
        int k = k0 + k2 + it * 2;
        Xs[k2 + it * 2][ll] = Xn[(size_t)k * TV_ + l0 + ll] + pe[k * T_ + tpe];
      }
    } else {
#pragma unroll
      for (int it = 0; it < 16; ++it) {
        int k = k0 + k2 + it * 2;
        Xs[k2 + it * 2][ll] = Xn[(size_t)k * TV_ + l0 + ll];
      }
    }
    __syncthreads();
#pragma unroll
    for (int kk = 0; kk < 32; ++kk) {
      float4 a0 = *(const float4*)&Ws[kk][ty * 8];
      float4 a1 = *(const float4*)&Ws[kk][ty * 8 + 4];
      float4 b = *(const float4*)&Xs[kk][tx * 4];
      float av[8] = {a0.x, a0.y, a0.z, a0.w, a1.x, a1.y, a1.z, a1.w};
      float bv[4] = {b.x, b.y, b.z, b.w};
#pragma unroll
      for (int i = 0; i < 8; ++i)
#pragma unroll
        for (int j = 0; j < 4; ++j) acc[i][j] += av[i] * bv[j];
    }
    __syncthreads();
  }
#pragma unroll
  for (int i = 0; i < 8; ++i) {
    int m = m0 + ty * 8 + i;
    size_t o = ((size_t)n * M + m) * TV_ + l0 + tx * 4;
    float4* yp = (float4*)(Y + o);
    float4 r = make_float4(acc[i][0], acc[i][1], acc[i][2], acc[i][3]);
    if (accumulate) {
      float4 old = *yp;
      r.x += old.x; r.y += old.y; r.z += old.z; r.w += old.w;
    } else {
      float bb = bias[m];
      r.x += bb; r.y += bb; r.z += bb; r.w += bb;
    }
    *yp = r;
  }
}

__global__ void k_zero(float* __restrict__ p, int nel) {
  int i = blockIdx.x * blockDim.x + threadIdx.x;
  if (i < nel) p[i] = 0.f;
}

// ---------------- attention raw: partial over c-pairs, atomicAdd ----------------
__global__ __launch_bounds__(256) void k_att(const float* __restrict__ qkv,
                                             float* __restrict__ attraw) {
  int n = blockIdx.z, h = blockIdx.y, cp = blockIdx.x;  // cp in [0,16)
  __shared__ float Qs[64][52], Ks[64][52];
  int tid = threadIdx.x;
  int ty = tid >> 4, tx = tid & 15;
  float acc[4][4] = {};
  const float* qb = qkv + ((size_t)n * O2_ + h * QKD_) * TV_;
  const float* kb = qkv + ((size_t)n * O2_ + H_ * QKD_ + h * QKD_) * TV_;
  for (int cc = 0; cc < 2; ++cc) {
    int c = cp * 2 + cc;
    for (int v0 = 0; v0 < V_; v0 += 51) {
      for (int i = tid; i < 64 * 51; i += 256) {
        int t = i / 51, vv = i % 51;
        size_t gi = (size_t)(c * T_ + t) * V_ + v0 + vv;
        Qs[t][vv] = qb[gi];
        Ks[t][vv] = kb[gi];
      }
      __syncthreads();
      for (int vv = 0; vv < 51; ++vv) {
        float av[4], bv[4];
#pragma unroll
        for (int i = 0; i < 4; ++i) av[i] = Qs[ty * 4 + i][vv];
#pragma unroll
        for (int j = 0; j < 4; ++j) bv[j] = Ks[tx * 4 + j][vv];
#pragma unroll
        for (int i = 0; i < 4; ++i)
#pragma unroll
          for (int j = 0; j < 4; ++j) acc[i][j] += av[i] * bv[j];
      }
      __syncthreads();
    }
  }
  float* ar = attraw + (size_t)(n * H_ + h) * TT_;
#pragma unroll
  for (int i = 0; i < 4; ++i)
#pragma unroll
    for (int j = 0; j < 4; ++j)
      atomicAdd(&ar[(ty * 4 + i) * T_ + tx * 4 + j], acc[i][j]);
}

__global__ void k_attfin(const float* __restrict__ raw, const float* __restrict__ alphas,
                         const float* __restrict__ att1s, float* __restrict__ att) {
  int i = blockIdx.x * blockDim.x + threadIdx.x;
  if (i >= N_ * H_ * TT_) return;
  int tt = i % TT_;
  int h = (i / TT_) % H_;
  att[i] = tanhf(raw[i] * (1.0f / 6528.0f)) * alphas[h] + att1s[h * TT_ + tt];
}

// ---------------- xs2_h[n,c,q,v] = sum_t att[n,h,t,q]*x1[n,c,t,v] ----------------
__global__ __launch_bounds__(256) void k_xs2(const float* __restrict__ x1,
                                             const float* __restrict__ att, int h,
                                             float* __restrict__ out) {
  int nc = blockIdx.x;
  int n = nc >> 7;
  __shared__ float As[TT_];        // [t][q]
  __shared__ float Xs[T_ * 208];   // padded rows
  int tid = threadIdx.x;
  const float* ab = att + (size_t)(n * H_ + h) * TT_;
  for (int i = tid; i < TT_; i += 256) As[i] = ab[i];
  const float* xb = x1 + (size_t)nc * TV_;
  for (int i = tid; i < TV_; i += 256) {
    int t = i / V_, v = i % V_;
    Xs[t * 208 + v] = xb[i];
  }
  for (int i = tid; i < T_; i += 256) {
    Xs[i * 208 + 204] = 0.f; Xs[i * 208 + 205] = 0.f;
    Xs[i * 208 + 206] = 0.f; Xs[i * 208 + 207] = 0.f;
  }
  __syncthreads();
  int ty = tid >> 4, tx = tid & 15;
  float* ob = out + (size_t)nc * TV_;
  for (int v0 = 0; v0 < V_; v0 += 64) {
    float acc[4][4] = {};
    for (int t = 0; t < T_; ++t) {
      float4 a = *(const float4*)&As[t * 64 + ty * 4];
      float4 b = *(const float4*)&Xs[t * 208 + v0 + tx * 4];
      float av[4] = {a.x, a.y, a.z, a.w}, bv[4] = {b.x, b.y, b.z, b.w};
#pragma unroll
      for (int i = 0; i < 4; ++i)
#pragma unroll
        for (int j = 0; j < 4; ++j) acc[i][j] += av[i] * bv[j];
    }
#pragma unroll
    for (int i = 0; i < 4; ++i) {
      int q = ty * 4 + i;
#pragma unroll
      for (int j = 0; j < 4; ++j) {
        int v = v0 + tx * 4 + j;
        if (v < V_) ob[q * V_ + v] = acc[i][j];
      }
    }
  }
}

// ---------------- BN stats per channel (biased var) ----------------
__global__ void k_bnstats(const float* __restrict__ xp, float* __restrict__ mu,
                          float* __restrict__ rstd) {
  int c = blockIdx.x;
  int tid = threadIdx.x;
  float s1 = 0.f, s2 = 0.f;
  for (int i = tid; i < N_ * TV_; i += 256) {
    int n = i / TV_, l = i - n * TV_;
    float v = xp[((size_t)n * C_ + c) * TV_ + l];
    s1 += v; s2 += v * v;
  }
  __shared__ float r1[256], r2[256];
  r1[tid] = s1; r2[tid] = s2;
  __syncthreads();
  for (int off = 128; off >= 1; off >>= 1) {
    if (tid < off) { r1[tid] += r1[tid + off]; r2[tid] += r2[tid + off]; }
    __syncthreads();
  }
  if (tid == 0) {
    const float cnt = (float)(N_ * TV_);
    float m = r1[0] / cnt;
    float var = r2[0] / cnt - m * m;
    mu[c] = m;
    rstd[c] = rsqrtf(var + 1e-5f);
  }
}

// ---------------- leaky_relu(bn(xp)+x1) ----------------
__global__ void k_bnres(const float* __restrict__ xp, const float* __restrict__ mu,
                        const float* __restrict__ rstd, const float* __restrict__ g,
                        const float* __restrict__ beta, const float* __restrict__ x1,
                        float* __restrict__ out) {
  for (size_t i = blockIdx.x * 256ull + threadIdx.x; i < NCTV_;
       i += (size_t)gridDim.x * 256ull) {
    int c = (int)((i / TV_) % C_);
    float v = (xp[i] - mu[c]) * rstd[c] * g[c] + beta[c] + x1[i];
    out[i] = v > 0.f ? v : 0.1f * v;
  }
}

extern "C" void kernel_launch(void* const* d_in, const int* in_sizes, int n_in,
                              void* d_out, int out_size, void* d_ws, size_t ws_size,
                              hipStream_t stream) {
  (void)in_sizes; (void)n_in; (void)out_size; (void)ws_size;
  const float* x        = (const float*)d_in[0];
  const float* trans_w  = (const float*)d_in[1];
  const float* trans_b  = (const float*)d_in[2];
  const float* convk_w  = (const float*)d_in[3];
  const float* convk_b  = (const float*)d_in[4];
  const float* qkv_w    = (const float*)d_in[5];
  const float* qkv_b    = (const float*)d_in[6];
  const float* alphas   = (const float*)d_in[7];
  const float* att1s    = (const float*)d_in[8];
  const float* out_w    = (const float*)d_in[9];
  const float* out_b    = (const float*)d_in[10];
  const float* out_g    = (const float*)d_in[11];
  const float* out_beta = (const float*)d_in[12];
  const float* ff_w     = (const float*)d_in[13];
  const float* ff_b     = (const float*)d_in[14];
  const float* ff_g     = (const float*)d_in[15];
  const float* ff_beta  = (const float*)d_in[16];

  float* ws = (float*)d_ws;
  size_t o_x1   = 0;                                  // N*C*T*V
  size_t o_big  = o_x1 + NCTV_;                       // N*192*T*V (pdis -> qkv -> out_pre -> ff_pre)
  size_t o_s    = o_big + (size_t)N_ * O2_ * TV_;     // N*C*T
  size_t o_dis  = o_s + (size_t)N_ * CT_;             // N*V*V
  size_t o_idx  = o_dis + (size_t)N_ * VV_;           // N*V*3 ints
  size_t o_cm   = o_idx + (size_t)N_ * V_ * 3;        // N*C*V
  size_t o_w2   = o_cm + (size_t)N_ * C_ * V_;        // N*V*3
  size_t o_pe   = o_w2 + (size_t)N_ * V_ * 3;         // C*T
  size_t o_araw = o_pe + (size_t)C_ * T_;             // N*H*T*T
  size_t o_att  = o_araw + (size_t)N_ * H_ * TT_;     // N*H*T*T
  size_t o_bn   = o_att + (size_t)N_ * H_ * TT_;      // 4*C
  size_t o_qkvT = o_bn + 4 * C_;                      // 128*192
  size_t o_outT = o_qkvT + 128 * 192;                 // 384*128
  size_t o_ffT  = o_outT + 384 * 128;                 // 128*128

  float* x1   = ws + o_x1;
  float* big  = ws + o_big;
  float* sbuf = ws + o_s;
  float* dis  = ws + o_dis;
  int*   idx  = (int*)(ws + o_idx);
  float* cm   = ws + o_cm;
  float* w2   = ws + o_w2;
  float* pe   = ws + o_pe;
  float* araw = ws + o_araw;
  float* att  = ws + o_att;
  float* bn   = ws + o_bn;
  float* qkvT = ws + o_qkvT;
  float* outT = ws + o_outT;
  float* ffT  = ws + o_ffT;
  float* dout = (float*)d_out;  // also used as scratch for xs2_h / xs3

  k_pe<<<(C_ * T_ + 255) / 256, 256, 0, stream>>>(pe);
  k_transpose<<<(192 * 128 + 255) / 256, 256, 0, stream>>>(qkv_w, qkvT, 192, 128);
  k_transpose<<<(128 * 384 + 255) / 256, 256, 0, stream>>>(out_w, outT, 128, 384);
  k_transpose<<<(128 * 128 + 255) / 256, 256, 0, stream>>>(ff_w, ffT, 128, 128);

  k_scale<<<(N_ * CT_ * 64) / 256, 256, 0, stream>>>(x, sbuf);
  // dis partials land in `big` (free until qkv GEMM), reduced deterministically.
  k_dis<<<dim3(4, 4, N_ * DSPLIT_), 256, 0, stream>>>(x, sbuf, big);
  k_disreduce<<<(N_ * VV_ + 255) / 256, 256, 0, stream>>>(big, dis);
  k_topk<<<(N_ * V_ + 255) / 256, 256, 0, stream>>>(dis, idx);
  k_colmean<<<N_ * C_, 256, 0, stream>>>(x, cm);
  k_w2<<<N_ * V_, 64, 0, stream>>>(cm, idx, trans_w, trans_b, convk_w, w2);
  k_x1<<<4096, 256, 0, stream>>>(x, idx, w2, convk_b, x1);

  // qkv = W(xs= x1+pe) + b  -> big
  k_gemm<<<dim3(102, 3, N_), 256, 0, stream>>>(qkvT, 192, x1, pe, qkv_b, big, O2_, C_, 0);

  k_zero<<<(N_ * H_ * TT_ + 255) / 256, 256, 0, stream>>>(araw, N_ * H_ * TT_);
  k_att<<<dim3(16, H_, N_), 256, 0, stream>>>(big, araw);
  k_attfin<<<(N_ * H_ * TT_ + 255) / 256, 256, 0, stream>>>(araw, alphas, att1s, att);

  // out_pre = out_b + sum_h W_h @ xs2_h   (xs2_h staged in d_out)
  for (int h = 0; h < H_; ++h) {
    k_xs2<<<N_ * C_, 256, 0, stream>>>(x1, att, h, dout);
    k_gemm<<<dim3(102, 2, N_), 256, 0, stream>>>(outT + h * 128 * 128, 128, dout,
                                                 nullptr, out_b, big, C_, C_, h);
  }
  k_bnstats<<<C_, 256, 0, stream>>>(big, bn, bn + C_);
  k_bnres<<<4096, 256, 0, stream>>>(big, bn, bn + C_, out_g, out_beta, x1, dout); // xs3

  k_gemm<<<dim3(102, 2, N_), 256, 0, stream>>>(ffT, 128, dout, nullptr, ff_b, big, C_, C_, 0);
  k_bnstats<<<C_, 256, 0, stream>>>(big, bn + 2 * C_, bn + 3 * C_);
  k_bnres<<<4096, 256, 0, stream>>>(big, bn + 2 * C_, bn + 3 * C_, ff_g, ff_beta, x1, dout);
}

// Round 3
// 1075.449 us; speedup vs baseline: 2.2043x; 1.1282x over previous
//
#include <hip/hip_runtime.h>
#include <math.h>

#define N_ 8
#define C_ 128
#define T_ 64
#define V_ 204
#define K_ 3
#define H_ 3
#define QKD_ 32
#define O2_ 192            // 2*H*QKD
#define TV_ 13056          // T*V
#define CT_ 8192           // C*T
#define TT_ 4096           // T*T
#define VV_ 41616          // V*V
#define NCTV_ 13369344ull  // N*C*T*V
#define DSPLIT_ 16         // K-split factor for k_dis

typedef __attribute__((ext_vector_type(8))) short short8v;
typedef __attribute__((ext_vector_type(4))) float f32x4;

__device__ inline unsigned short bf16rnd(float f) {
  union { float f; unsigned u; } x; x.f = f;
  return (unsigned short)((x.u + 0x7FFFu + ((x.u >> 16) & 1u)) >> 16);
}

// ---------------- positional encoding table pe[c*T+t] ----------------
__global__ void k_pe(float* __restrict__ pe) {
  int i = blockIdx.x * blockDim.x + threadIdx.x;
  if (i >= C_ * T_) return;
  int t = i % T_, c = i / T_;
  int j = c >> 1;
  float dv = expf((2.0f * j) * (-logf(10000.0f) / (float)C_));
  float ang = (float)t * dv;
  pe[i] = (c & 1) ? cosf(ang) : sinf(ang);
}

// ---------------- qkvpe[m][t] = sum_c qkv_w[m][c] * pe[c][t] ----------------
__global__ void k_qkvpe(const float* __restrict__ qw, const float* __restrict__ pe,
                        float* __restrict__ qpe) {
  int i = blockIdx.x * blockDim.x + threadIdx.x;
  if (i >= O2_ * T_) return;
  int t = i & 63, m = i >> 6;
  float a = 0.f;
  for (int c = 0; c < C_; ++c) a += qw[m * C_ + c] * pe[c * T_ + t];
  qpe[i] = a;
}

// ---------------- s[n,c,t] = 1/max(||x[n,c,t,:]||,1e-12)^2 ----------------
__global__ void k_scale(const float* __restrict__ x, float* __restrict__ s) {
  int gid = blockIdx.x * blockDim.x + threadIdx.x;
  int w = gid >> 6, lane = gid & 63;
  if (w >= N_ * CT_) return;
  const float* row = x + (size_t)w * V_;
  float a = 0.f;
  for (int v = lane; v < V_; v += 64) { float t = row[v]; a += t * t; }
#pragma unroll
  for (int off = 32; off >= 1; off >>= 1) a += __shfl_down(a, off, 64);
  if (lane == 0) {
    float d = fmaxf(sqrtf(a), 1e-12f);
    s[w] = 1.0f / (d * d);
  }
}

// ---- dis partial: pdis[sp][n][u][v] = sum_{ct in slice} x[n,ct,u]*s[n,ct]*x[n,ct,v] ----
__global__ __launch_bounds__(256) void k_dis(const float* __restrict__ x,
                                             const float* __restrict__ s,
                                             float* __restrict__ pdis) {
  int zz = blockIdx.z;
  int n = zz / DSPLIT_, sp = zz % DSPLIT_;
  const int KCH = CT_ / DSPLIT_;  // 512
  int u0 = blockIdx.y * 64, v0 = blockIdx.x * 64;
  __shared__ float Au[32][64], Av[32][64];
  int tid = threadIdx.x;
  int ty = tid >> 4, tx = tid & 15;
  float acc[4][4] = {};
  const float* xb = x + (size_t)n * CT_ * V_;
  const float* sb = s + (size_t)n * CT_;
  int kbase = sp * KCH;
  for (int k0 = kbase; k0 < kbase + KCH; k0 += 32) {
    int uu = tid & 63, kk = tid >> 6;
#pragma unroll
    for (int it = 0; it < 8; ++it) {
      int krow = kk + it * 4;
      const float* xr = xb + (size_t)(k0 + krow) * V_;
      float sv = sb[k0 + krow];
      int u = u0 + uu, v = v0 + uu;
      Au[krow][uu] = (u < V_) ? xr[u] * sv : 0.f;
      Av[krow][uu] = (v < V_) ? xr[v] : 0.f;
    }
    __syncthreads();
#pragma unroll
    for (int kk2 = 0; kk2 < 32; ++kk2) {
      float4 a = *(const float4*)&Au[kk2][ty * 4];
      float4 b = *(const float4*)&Av[kk2][tx * 4];
      float av[4] = {a.x, a.y, a.z, a.w}, bv[4] = {b.x, b.y, b.z, b.w};
#pragma unroll
      for (int i = 0; i < 4; ++i)
#pragma unroll
        for (int j = 0; j < 4; ++j) acc[i][j] += av[i] * bv[j];
    }
    __syncthreads();
  }
  float* pb = pdis + ((size_t)sp * N_ + n) * VV_;
#pragma unroll
  for (int i = 0; i < 4; ++i) {
    int u = u0 + ty * 4 + i;
    if (u >= V_) continue;
#pragma unroll
    for (int j = 0; j < 4; ++j) {
      int v = v0 + tx * 4 + j;
      if (v < V_) pb[u * V_ + v] = acc[i][j];
    }
  }
}

// ---------------- deterministic fixed-order reduce of the 16 partials ----------------
__global__ void k_disreduce(const float* __restrict__ pdis, float* __restrict__ dis) {
  int i = blockIdx.x * blockDim.x + threadIdx.x;
  if (i >= N_ * VV_) return;
  float a = 0.f;
#pragma unroll
  for (int sp = 0; sp < DSPLIT_; ++sp) a += pdis[(size_t)sp * N_ * VV_ + i];
  dis[i] = a;
}

// ---------------- top-3 per (n,u) row ----------------
__global__ void k_topk(const float* __restrict__ dis, int* __restrict__ idx) {
  int r = blockIdx.x * blockDim.x + threadIdx.x;
  if (r >= N_ * V_) return;
  const float* row = dis + (size_t)r * V_;
  float m0 = -INFINITY, m1 = -INFINITY, m2 = -INFINITY;
  int i0 = 0, i1 = 0, i2 = 0;
  for (int v = 0; v < V_; ++v) {
    float d = row[v];
    if (d > m0)      { m2 = m1; i2 = i1; m1 = m0; i1 = i0; m0 = d; i0 = v; }
    else if (d > m1) { m2 = m1; i2 = i1; m1 = d; i1 = v; }
    else if (d > m2) { m2 = d; i2 = v; }
  }
  idx[r * 3 + 0] = i0; idx[r * 3 + 1] = i1; idx[r * 3 + 2] = i2;
}

// ---------------- colmean[n,c,v] = mean_t x[n,c,t,v] ----------------
__global__ void k_colmean(const float* __restrict__ x, float* __restrict__ cm) {
  int nc = blockIdx.x;
  int v = threadIdx.x;
  if (v >= V_) return;
  const float* base = x + (size_t)nc * TV_;
  float acc = 0.f;
  for (int t = 0; t < T_; ++t) acc += base[t * V_ + v];
  cm[(size_t)nc * V_ + v] = acc * (1.0f / T_);
}

// ---------------- w2[n,v,g] = sum_p softmax_p(mult[n,v,g,:])*convk_w[p] ----------------
__global__ void k_w2(const float* __restrict__ cm, const int* __restrict__ idx,
                     const float* __restrict__ tw, const float* __restrict__ tb,
                     const float* __restrict__ ckw, float* __restrict__ w2) {
  int r = blockIdx.x;  // n*V + v
  int n = r / V_;
  int lane = threadIdx.x;
  __shared__ float mv[3][C_];
  const int* ib = idx + r * 3;
  int j0 = ib[0], j1 = ib[1], j2 = ib[2];
  const float* cmn = cm + (size_t)n * C_ * V_;
  for (int c = lane; c < C_; c += 64) {
    mv[0][c] = cmn[c * V_ + j0];
    mv[1][c] = cmn[c * V_ + j1];
    mv[2][c] = cmn[c * V_ + j2];
  }
  __syncthreads();
  float p[9];
#pragma unroll
  for (int gp = 0; gp < 9; ++gp) p[gp] = 0.f;
  for (int c = lane; c < C_; c += 64) {
#pragma unroll
    for (int g = 0; g < 3; ++g) {
      float m = mv[g][c];
#pragma unroll
      for (int pp = 0; pp < 3; ++pp) p[g * 3 + pp] += m * tw[(g * 3 + pp) * C_ + c];
    }
  }
#pragma unroll
  for (int off = 32; off >= 1; off >>= 1) {
#pragma unroll
    for (int gp = 0; gp < 9; ++gp) p[gp] += __shfl_down(p[gp], off, 64);
  }
  if (lane == 0) {
    float c0 = ckw[0], c1 = ckw[1], c2 = ckw[2];
#pragma unroll
    for (int g = 0; g < 3; ++g) {
      float m0 = p[g * 3 + 0] + tb[g * 3 + 0];
      float m1 = p[g * 3 + 1] + tb[g * 3 + 1];
      float m2 = p[g * 3 + 2] + tb[g * 3 + 2];
      float mx = fmaxf(m0, fmaxf(m1, m2));
      float e0 = expf(m0 - mx), e1 = expf(m1 - mx), e2 = expf(m2 - mx);
      float inv = 1.0f / (e0 + e1 + e2);
      w2[r * 3 + g] = (e0 * c0 + e1 * c1 + e2 * c2) * inv;
    }
  }
}

// ---------------- x1 = relu(sum_k x[...,idx_k]*w2_k + convk_b + x) ----------------
__global__ void k_x1(const float* __restrict__ x, const int* __restrict__ idx,
                     const float* __restrict__ w2, const float* __restrict__ ckb,
                     float* __restrict__ x1) {
  float cb = ckb[0];
  for (size_t i = blockIdx.x * 256ull + threadIdx.x; i < NCTV_;
       i += (size_t)gridDim.x * 256ull) {
    int v = (int)(i % V_);
    size_t r = i / V_;
    int n = (int)(r / CT_);
    const float* xrow = x + r * V_;
    int b = (n * V_ + v) * 3;
    float pooled = xrow[idx[b]] * w2[b] + xrow[idx[b + 1]] * w2[b + 1] +
                   xrow[idx[b + 2]] * w2[b + 2] + cb;
    x1[i] = fmaxf(pooled + xrow[v], 0.f);
  }
}

// ---------------- transpose fp32 [n][128][TV] -> bf16 [n][TV][128] (+pe opt) --------
__global__ __launch_bounds__(256) void k_xpose(const float* __restrict__ src,
                                               const float* __restrict__ pe, int dope,
                                               unsigned short* __restrict__ dst) {
  int n = blockIdx.z, kt = blockIdx.y, lt = blockIdx.x;
  int l0 = lt * 64, k0 = kt * 32;
  __shared__ float Ts[32][65];
  int tid = threadIdx.x;
  int lc = tid & 63, kr = tid >> 6;
  const float* sb = src + (size_t)n * C_ * TV_;
  int tl = (l0 + lc) / V_;
#pragma unroll
  for (int it = 0; it < 8; ++it) {
    int k = kr + it * 4;
    float v = sb[(size_t)(k0 + k) * TV_ + l0 + lc];
    if (dope) v += pe[(k0 + k) * T_ + tl];
    Ts[k][lc] = v;
  }
  __syncthreads();
  int lrow = tid >> 2, ch = tid & 3;
  unsigned out[4];
#pragma unroll
  for (int q = 0; q < 4; ++q) {
    unsigned lo = bf16rnd(Ts[ch * 8 + 2 * q][lrow]);
    unsigned hi = bf16rnd(Ts[ch * 8 + 2 * q + 1][lrow]);
    out[q] = lo | (hi << 16);
  }
  size_t daddr = ((size_t)n * TV_ + l0 + lrow) * 128 + k0 + ch * 8;
  *(uint4*)(dst + daddr) = make_uint4(out[0], out[1], out[2], out[3]);
}

// ---- MFMA GEMM: Y[n][m][l] = sum_k W[m][k]*x1t[n][l][k] (+bias[m]) (+peb[m][t]) ----
// W row addr = W + (m & mmask)*ldk + (m>>7)*hstr.  obf: write bf16 else fp32.
__global__ __launch_bounds__(256) void k_gmm(
    const float* __restrict__ W, int ldk, int mmask, int hstr,
    const unsigned short* __restrict__ Xt,
    const float* __restrict__ bias, const float* __restrict__ peb,
    void* __restrict__ Yv, int M, int obf) {
  int n = blockIdx.z;
  int tid = threadIdx.x, lane = tid & 63, wid = tid >> 6;
  int m0 = blockIdx.y * 64 + (wid >> 1) * 32;
  int l0 = blockIdx.x * 128 + (wid & 1) * 64;
  int lr = lane & 15, lg = lane >> 4;
  short8v a[2][4];
#pragma unroll
  for (int mi = 0; mi < 2; ++mi) {
    int m = m0 + mi * 16 + lr;
    const float* wr = W + (size_t)(m & mmask) * ldk + (size_t)(m >> 7) * hstr;
#pragma unroll
    for (int ks = 0; ks < 4; ++ks) {
      f32x4 w0 = *(const f32x4*)(wr + ks * 32 + lg * 8);
      f32x4 w1 = *(const f32x4*)(wr + ks * 32 + lg * 8 + 4);
      short8v t;
      t[0] = (short)bf16rnd(w0[0]); t[1] = (short)bf16rnd(w0[1]);
      t[2] = (short)bf16rnd(w0[2]); t[3] = (short)bf16rnd(w0[3]);
      t[4] = (short)bf16rnd(w1[0]); t[5] = (short)bf16rnd(w1[1]);
      t[6] = (short)bf16rnd(w1[2]); t[7] = (short)bf16rnd(w1[3]);
      a[mi][ks] = t;
    }
  }
  f32x4 acc[2][4];
#pragma unroll
  for (int mi = 0; mi < 2; ++mi)
#pragma unroll
    for (int li = 0; li < 4; ++li) acc[mi][li] = (f32x4){0.f, 0.f, 0.f, 0.f};
  const unsigned short* xb = Xt + (size_t)n * TV_ * 128;
#pragma unroll
  for (int ks = 0; ks < 4; ++ks) {
#pragma unroll
    for (int li = 0; li < 4; ++li) {
      short8v b = *(const short8v*)(xb + (size_t)(l0 + li * 16 + lr) * 128 + ks * 32 + lg * 8);
      acc[0][li] = __builtin_amdgcn_mfma_f32_16x16x32_bf16(a[0][ks], b, acc[0][li], 0, 0, 0);
      acc[1][li] = __builtin_amdgcn_mfma_f32_16x16x32_bf16(a[1][ks], b, acc[1][li], 0, 0, 0);
    }
  }
  float* Yf = (float*)Yv;
  unsigned short* Yh = (unsigned short*)Yv;
#pragma unroll
  for (int mi = 0; mi < 2; ++mi) {
#pragma unroll
    for (int li = 0; li < 4; ++li) {
      int l = l0 + li * 16 + lr;
      int t = l / V_;
#pragma unroll
      for (int r = 0; r < 4; ++r) {
        int m = m0 + mi * 16 + lg * 4 + r;
        float val = acc[mi][li][r];
        if (bias) val += bias[m];
        if (peb) val += peb[m * T_ + t];
        size_t o = ((size_t)n * M + m) * TV_ + l;
        if (obf) Yh[o] = bf16rnd(val);
        else Yf[o] = val;
      }
    }
  }
}

__global__ void k_zero(float* __restrict__ p, int nel) {
  int i = blockIdx.x * blockDim.x + threadIdx.x;
  if (i < nel) p[i] = 0.f;
}

// ---------------- attention raw (fp32, atomic partials over c-pairs) ----------------
__global__ __launch_bounds__(256) void k_att(const float* __restrict__ qkv,
                                             float* __restrict__ attraw) {
  int n = blockIdx.z, h = blockIdx.y, cp = blockIdx.x;  // cp in [0,16)
  __shared__ float Qs[64][52], Ks[64][52];
  int tid = threadIdx.x;
  int ty = tid >> 4, tx = tid & 15;
  float acc[4][4] = {};
  const float* qb = qkv + ((size_t)n * O2_ + h * QKD_) * TV_;
  const float* kb = qkv + ((size_t)n * O2_ + H_ * QKD_ + h * QKD_) * TV_;
  for (int cc = 0; cc < 2; ++cc) {
    int c = cp * 2 + cc;
    for (int v0 = 0; v0 < V_; v0 += 51) {
      for (int i = tid; i < 64 * 51; i += 256) {
        int t = i / 51, vv = i % 51;
        size_t gi = (size_t)(c * T_ + t) * V_ + v0 + vv;
        Qs[t][vv] = qb[gi];
        Ks[t][vv] = kb[gi];
      }
      __syncthreads();
      for (int vv = 0; vv < 51; ++vv) {
        float av[4], bv[4];
#pragma unroll
        for (int i = 0; i < 4; ++i) av[i] = Qs[ty * 4 + i][vv];
#pragma unroll
        for (int j = 0; j < 4; ++j) bv[j] = Ks[tx * 4 + j][vv];
#pragma unroll
        for (int i = 0; i < 4; ++i)
#pragma unroll
          for (int j = 0; j < 4; ++j) acc[i][j] += av[i] * bv[j];
      }
      __syncthreads();
    }
  }
  float* ar = attraw + (size_t)(n * H_ + h) * TT_;
#pragma unroll
  for (int i = 0; i < 4; ++i)
#pragma unroll
    for (int j = 0; j < 4; ++j)
      atomicAdd(&ar[(ty * 4 + i) * T_ + tx * 4 + j], acc[i][j]);
}

// ---------------- attT[n][q][h*64+t] = bf16(tanh(raw/6528)*alpha + att1s) ----------
__global__ void k_attfin(const float* __restrict__ raw, const float* __restrict__ alphas,
                         const float* __restrict__ att1s, unsigned short* __restrict__ attT) {
  int i = blockIdx.x * blockDim.x + threadIdx.x;
  if (i >= N_ * H_ * TT_) return;
  int tt = i % TT_;
  int h = (i / TT_) % H_;
  int n = i / (H_ * TT_);
  int t = tt >> 6, q = tt & 63;
  float v = tanhf(raw[i] * (1.0f / 6528.0f)) * alphas[h] + att1s[h * TT_ + tt];
  attT[(size_t)(n * 64 + q) * 192 + h * 64 + t] = bf16rnd(v);
}

// ---- combine: out_pre[n][o][q][v] = sum_{ht} attT[n][q][ht]*Y3[n][h*128+o][t][v] + out_b[o]
__global__ __launch_bounds__(256) void k_comb(const unsigned short* __restrict__ Y3,
                                              const unsigned short* __restrict__ attT,
                                              const float* __restrict__ outb,
                                              float* __restrict__ op) {
  int n = blockIdx.z, o = blockIdx.y, vt = blockIdx.x;  // vt 0..3
  int v0 = vt * 64;
  __shared__ unsigned short Bt[64][200];  // [vloc][ht], 400B rows (16B-mult)
  int tid = threadIdx.x, lane = tid & 63, wv = tid >> 6;
  const unsigned short* yb = Y3 + (size_t)n * 384 * TV_;
#pragma unroll
  for (int p = 0; p < 24; ++p) {
    int g = tid + p * 256;          // 192 ht * 32 v-pairs
    int ht = g >> 5, pr = g & 31;
    int v = v0 + pr * 2;
    int row = (ht >> 6) * 128 + o;
    unsigned val = 0;
    if (v + 1 < V_) val = *(const unsigned*)(yb + (size_t)row * TV_ + (ht & 63) * V_ + v);
    Bt[pr * 2][ht] = (unsigned short)(val & 0xffffu);
    Bt[pr * 2 + 1][ht] = (unsigned short)(val >> 16);
  }
  __syncthreads();
  int lr = lane & 15, lg = lane >> 4;
  const unsigned short* ab = attT + (size_t)n * 64 * 192;
  f32x4 acc[4];
#pragma unroll
  for (int mi = 0; mi < 4; ++mi) acc[mi] = (f32x4){0.f, 0.f, 0.f, 0.f};
#pragma unroll
  for (int ks = 0; ks < 6; ++ks) {
    short8v b = *(const short8v*)&Bt[wv * 16 + lr][ks * 32 + lg * 8];
#pragma unroll
    for (int mi = 0; mi < 4; ++mi) {
      short8v a = *(const short8v*)(ab + (size_t)(mi * 16 + lr) * 192 + ks * 32 + lg * 8);
      acc[mi] = __builtin_amdgcn_mfma_f32_16x16x32_bf16(a, b, acc[mi], 0, 0, 0);
    }
  }
  float bo = outb[o];
  int v = v0 + wv * 16 + lr;
  if (v < V_) {
#pragma unroll
    for (int mi = 0; mi < 4; ++mi)
#pragma unroll
      for (int r = 0; r < 4; ++r) {
        int q = mi * 16 + lg * 4 + r;
        op[(((size_t)n * C_ + o) * T_ + q) * V_ + v] = acc[mi][r] + bo;
      }
  }
}

// ---------------- BN stats per channel (biased var) ----------------
__global__ void k_bnstats(const float* __restrict__ xp, float* __restrict__ mu,
                          float* __restrict__ rstd) {
  int c = blockIdx.x;
  int tid = threadIdx.x;
  float s1 = 0.f, s2 = 0.f;
  for (int i = tid; i < N_ * TV_; i += 256) {
    int n = i / TV_, l = i - n * TV_;
    float v = xp[((size_t)n * C_ + c) * TV_ + l];
    s1 += v; s2 += v * v;
  }
  __shared__ float r1[256], r2[256];
  r1[tid] = s1; r2[tid] = s2;
  __syncthreads();
  for (int off = 128; off >= 1; off >>= 1) {
    if (tid < off) { r1[tid] += r1[tid + off]; r2[tid] += r2[tid + off]; }
    __syncthreads();
  }
  if (tid == 0) {
    const float cnt = (float)(N_ * TV_);
    float m = r1[0] / cnt;
    float var = r2[0] / cnt - m * m;
    mu[c] = m;
    rstd[c] = rsqrtf(var + 1e-5f);
  }
}

// ---------------- leaky_relu(bn(xp)+x1) ----------------
__global__ void k_bnres(const float* __restrict__ xp, const float* __restrict__ mu,
                        const float* __restrict__ rstd, const float* __restrict__ g,
                        const float* __restrict__ beta, const float* __restrict__ x1,
                        float* __restrict__ out) {
  for (size_t i = blockIdx.x * 256ull + threadIdx.x; i < NCTV_;
       i += (size_t)gridDim.x * 256ull) {
    int c = (int)((i / TV_) % C_);
    float v = (xp[i] - mu[c]) * rstd[c] * g[c] + beta[c] + x1[i];
    out[i] = v > 0.f ? v : 0.1f * v;
  }
}

extern "C" void kernel_launch(void* const* d_in, const int* in_sizes, int n_in,
                              void* d_out, int out_size, void* d_ws, size_t ws_size,
                              hipStream_t stream) {
  (void)in_sizes; (void)n_in; (void)out_size; (void)ws_size;
  const float* x        = (const float*)d_in[0];
  const float* trans_w  = (const float*)d_in[1];
  const float* trans_b  = (const float*)d_in[2];
  const float* convk_w  = (const float*)d_in[3];
  const float* convk_b  = (const float*)d_in[4];
  const float* qkv_w    = (const float*)d_in[5];
  const float* qkv_b    = (const float*)d_in[6];
  const float* alphas   = (const float*)d_in[7];
  const float* att1s    = (const float*)d_in[8];
  const float* out_w    = (const float*)d_in[9];
  const float* out_b    = (const float*)d_in[10];
  const float* out_g    = (const float*)d_in[11];
  const float* out_beta = (const float*)d_in[12];
  const float* ff_w     = (const float*)d_in[13];
  const float* ff_b     = (const float*)d_in[14];
  const float* ff_g     = (const float*)d_in[15];
  const float* ff_beta  = (const float*)d_in[16];

  float* ws = (float*)d_ws;
  size_t off = 0;
  float* x1   = ws + off; off += NCTV_;                       // 13.37M
  float* big  = ws + off; off += (size_t)N_ * O2_ * TV_;      // 20.05M (pdis -> qkv fp32 -> Y3 bf16 -> ff_pre)
  float* sbuf = ws + off; off += (size_t)N_ * CT_;
  float* dis  = ws + off; off += (size_t)N_ * VV_;
  int*   idx  = (int*)(ws + off); off += (size_t)N_ * V_ * 3 + 16;
  float* cm   = ws + off; off += (size_t)N_ * C_ * V_;
  float* w2   = ws + off; off += (size_t)N_ * V_ * 3 + 16;
  float* pe   = ws + off; off += (size_t)C_ * T_;
  float* araw = ws + off; off += (size_t)N_ * H_ * TT_;
  unsigned short* attT = (unsigned short*)(ws + off); off += (size_t)N_ * 64 * 192 / 2;
  float* bn   = ws + off; off += 512;
  float* qpe  = ws + off; off += (size_t)O2_ * T_;
  unsigned short* x1t = (unsigned short*)(ws + off); off += NCTV_ / 2;  // bf16 [n][l][128]

  float* dout = (float*)d_out;  // out_pre -> xs3 (in place) -> final

  k_pe<<<(C_ * T_ + 255) / 256, 256, 0, stream>>>(pe);
  k_qkvpe<<<(O2_ * T_ + 255) / 256, 256, 0, stream>>>(qkv_w, pe, qpe);

  k_scale<<<(N_ * CT_ * 64) / 256, 256, 0, stream>>>(x, sbuf);
  k_dis<<<dim3(4, 4, N_ * DSPLIT_), 256, 0, stream>>>(x, sbuf, big);
  k_disreduce<<<(N_ * VV_ + 255) / 256, 256, 0, stream>>>(big, dis);
  k_topk<<<(N_ * V_ + 255) / 256, 256, 0, stream>>>(dis, idx);
  k_colmean<<<N_ * C_, 256, 0, stream>>>(x, cm);
  k_w2<<<N_ * V_, 64, 0, stream>>>(cm, idx, trans_w, trans_b, convk_w, w2);
  k_x1<<<4096, 256, 0, stream>>>(x, idx, w2, convk_b, x1);

  // x1t = bf16 transpose of x1 (pe-free; pe folded via qpe bias)
  k_xpose<<<dim3(204, 4, N_), 256, 0, stream>>>(x1, pe, 0, x1t);

  // qkv = W@x1 + qkv_b + qkvpe  -> big (fp32)
  k_gmm<<<dim3(102, 3, N_), 256, 0, stream>>>(qkv_w, 128, 255, 0, x1t, qkv_b, qpe,
                                              big, O2_, 0);

  k_zero<<<(N_ * H_ * TT_ + 255) / 256, 256, 0, stream>>>(araw, N_ * H_ * TT_);
  k_att<<<dim3(16, H_, N_), 256, 0, stream>>>(big, araw);
  k_attfin<<<(N_ * H_ * TT_ + 255) / 256, 256, 0, stream>>>(araw, alphas, att1s, attT);

  // Y3[n][h*128+o][t][v] = (W_h @ x1) bf16 -> big (reuse, 40.1M bf16 = 20.05M fl)
  k_gmm<<<dim3(102, 6, N_), 256, 0, stream>>>(out_w, 384, 127, 128, x1t, nullptr, nullptr,
                                              big, 384, 1);

  // out_pre = sum_ht attT * Y3 + out_b -> d_out
  k_comb<<<dim3(4, C_, N_), 256, 0, stream>>>((const unsigned short*)big, attT, out_b, dout);

  k_bnstats<<<C_, 256, 0, stream>>>(dout, bn, bn + C_);
  k_bnres<<<4096, 256, 0, stream>>>(dout, bn, bn + C_, out_g, out_beta, x1, dout); // xs3 in place

  // xs3t = bf16 transpose of xs3 (reuse x1t buffer)
  k_xpose<<<dim3(204, 4, N_), 256, 0, stream>>>(dout, pe, 0, x1t);

  // ff_pre = ff_w @ xs3 + ff_b -> big (fp32, Y3 dead)
  k_gmm<<<dim3(102, 2, N_), 256, 0, stream>>>(ff_w, 128, 255, 0, x1t, ff_b, nullptr,
                                              big, C_, 0);
  k_bnstats<<<C_, 256, 0, stream>>>(big, bn + 2 * C_, bn + 3 * C_);
  k_bnres<<<4096, 256, 0, stream>>>(big, bn + 2 * C_, bn + 3 * C_, ff_g, ff_beta, x1, dout);
}

// Round 4
// 638.537 us; speedup vs baseline: 3.7125x; 1.6842x over previous
//
#include <hip/hip_runtime.h>
#include <math.h>

#define N_ 8
#define C_ 128
#define T_ 64
#define V_ 204
#define K_ 3
#define H_ 3
#define QKD_ 32
#define O2_ 192            // 2*H*QKD
#define TV_ 13056          // T*V
#define CT_ 8192           // C*T
#define TT_ 4096           // T*T
#define VV_ 41616          // V*V
#define NCTV_ 13369344ull  // N*C*T*V
#define DSPLIT_ 16         // K-split factor for k_dis

typedef __attribute__((ext_vector_type(8))) short short8v;
typedef __attribute__((ext_vector_type(4))) float f32x4;

__device__ inline unsigned short bf16rnd(float f) {
  union { float f; unsigned u; } x; x.f = f;
  return (unsigned short)((x.u + 0x7FFFu + ((x.u >> 16) & 1u)) >> 16);
}
__device__ inline float bf2f(unsigned short u) {
  union { unsigned u; float f; } x; x.u = ((unsigned)u) << 16;
  return x.f;
}

// ---- qkvpe[m][t] = sum_c qkv_w[m][c]*pe[c][t]; pe built in LDS ----
__global__ void k_qkvpe(const float* __restrict__ qw, float* __restrict__ qpe) {
  __shared__ float pes[C_ * T_];  // 32 KB
  int tid = threadIdx.x;
  for (int i = tid; i < C_ * T_; i += 256) {
    int t = i & 63, c = i >> 6;
    int j = c >> 1;
    float dv = expf((2.0f * j) * (-logf(10000.0f) / (float)C_));
    float ang = (float)t * dv;
    pes[i] = (c & 1) ? cosf(ang) : sinf(ang);
  }
  __syncthreads();
  int g = blockIdx.x * 256 + tid;  // 48*256 = 12288 = 192*64
  int t = g & 63, m = g >> 6;
  float a = 0.f;
  for (int c = 0; c < C_; ++c) a += qw[m * C_ + c] * pes[c * T_ + t];
  qpe[g] = a;
}

// ---------------- s[n,c,t] = 1/max(||x||,1e-12)^2, float4 ----------------
__global__ void k_scale(const float* __restrict__ x, float* __restrict__ s) {
  int gid = blockIdx.x * blockDim.x + threadIdx.x;
  int w = gid >> 6, lane = gid & 63;
  if (w >= N_ * CT_) return;
  const f32x4* row = (const f32x4*)(x + (size_t)w * V_);
  float a = 0.f;
  for (int v4 = lane; v4 < 51; v4 += 64) {
    f32x4 t = row[v4];
    a += t.x * t.x + t.y * t.y + t.z * t.z + t.w * t.w;
  }
#pragma unroll
  for (int off = 32; off >= 1; off >>= 1) a += __shfl_down(a, off, 64);
  if (lane == 0) {
    float d = fmaxf(sqrtf(a), 1e-12f);
    s[w] = 1.0f / (d * d);
  }
}

// ---- dis partial, UPPER-TRIANGLE tiles only (dis is symmetric) ----
// grid (10, DSPLIT_, N_): 10 = #tiles with bu<=bv in a 4x4 tiling.
__global__ __launch_bounds__(256) void k_dis(const float* __restrict__ x,
                                             const float* __restrict__ s,
                                             float* __restrict__ pdis) {
  int q = blockIdx.x, sp = blockIdx.y, n = blockIdx.z;
  int bu, bv;
  if (q < 4)      { bu = 0; bv = q; }
  else if (q < 7) { bu = 1; bv = q - 3; }
  else if (q < 9) { bu = 2; bv = q - 5; }
  else            { bu = 3; bv = 3; }
  const int KCH = CT_ / DSPLIT_;  // 512
  int u0 = bu * 64, v0 = bv * 64;
  __shared__ float Au[32][64], Av[32][64];
  int tid = threadIdx.x;
  int ty = tid >> 4, tx = tid & 15;
  float acc[4][4] = {};
  const float* xb = x + (size_t)n * CT_ * V_;
  const float* sb = s + (size_t)n * CT_;
  int kbase = sp * KCH;
  for (int k0 = kbase; k0 < kbase + KCH; k0 += 32) {
    int uu = tid & 63, kk = tid >> 6;
#pragma unroll
    for (int it = 0; it < 8; ++it) {
      int krow = kk + it * 4;
      const float* xr = xb + (size_t)(k0 + krow) * V_;
      float sv = sb[k0 + krow];
      int u = u0 + uu, v = v0 + uu;
      Au[krow][uu] = (u < V_) ? xr[u] * sv : 0.f;
      Av[krow][uu] = (v < V_) ? xr[v] : 0.f;
    }
    __syncthreads();
#pragma unroll
    for (int kk2 = 0; kk2 < 32; ++kk2) {
      float4 a = *(const float4*)&Au[kk2][ty * 4];
      float4 b = *(const float4*)&Av[kk2][tx * 4];
      float av[4] = {a.x, a.y, a.z, a.w}, bv4[4] = {b.x, b.y, b.z, b.w};
#pragma unroll
      for (int i = 0; i < 4; ++i)
#pragma unroll
        for (int j = 0; j < 4; ++j) acc[i][j] += av[i] * bv4[j];
    }
    __syncthreads();
  }
  float* pb = pdis + ((size_t)sp * N_ + n) * VV_;
#pragma unroll
  for (int i = 0; i < 4; ++i) {
    int u = u0 + ty * 4 + i;
    if (u >= V_) continue;
#pragma unroll
    for (int j = 0; j < 4; ++j) {
      int v = v0 + tx * 4 + j;
      if (v < V_) {
        pb[(size_t)u * V_ + v] = acc[i][j];
        if (bu != bv) pb[(size_t)v * V_ + u] = acc[i][j];
      }
    }
  }
}

// ---- fused: sum 16 dis-partials + wave-parallel top-3 (lex (val desc, idx asc)) ----
__global__ void k_topk2(const float* __restrict__ pdis, int* __restrict__ idx) {
  int r = blockIdx.x;  // n*V + u
  int n = r / V_, u = r - n * V_;
  int lane = threadIdx.x;
  float m0 = -INFINITY, m1 = -INFINITY, m2 = -INFINITY;
  int i0 = 0x7fffffff, i1 = 0x7fffffff, i2 = 0x7fffffff;
#pragma unroll
  for (int g = 0; g < 4; ++g) {
    int v = g * 64 + lane;
    if (v >= V_) break;
    float a = 0.f;
#pragma unroll
    for (int sp = 0; sp < DSPLIT_; ++sp)
      a += pdis[((size_t)sp * N_ + n) * VV_ + (size_t)u * V_ + v];
    // insert (a, v)
    if (a > m0 || (a == m0 && v < i0)) {
      m2 = m1; i2 = i1; m1 = m0; i1 = i0; m0 = a; i0 = v;
    } else if (a > m1 || (a == m1 && v < i1)) {
      m2 = m1; i2 = i1; m1 = a; i1 = v;
    } else if (a > m2 || (a == m2 && v < i2)) {
      m2 = a; i2 = v;
    }
  }
#pragma unroll
  for (int msk = 1; msk < 64; msk <<= 1) {
    float o0 = __shfl_xor(m0, msk, 64), o1 = __shfl_xor(m1, msk, 64),
          o2 = __shfl_xor(m2, msk, 64);
    int p0 = __shfl_xor(i0, msk, 64), p1 = __shfl_xor(i1, msk, 64),
        p2 = __shfl_xor(i2, msk, 64);
    float ov[3] = {o0, o1, o2};
    int op[3] = {p0, p1, p2};
#pragma unroll
    for (int e = 0; e < 3; ++e) {
      float a = ov[e]; int v = op[e];
      if (a > m0 || (a == m0 && v < i0)) {
        m2 = m1; i2 = i1; m1 = m0; i1 = i0; m0 = a; i0 = v;
      } else if (a > m1 || (a == m1 && v < i1)) {
        m2 = m1; i2 = i1; m1 = a; i1 = v;
      } else if (a > m2 || (a == m2 && v < i2)) {
        m2 = a; i2 = v;
      }
    }
  }
  if (lane == 0) {
    idx[r * 3 + 0] = i0; idx[r * 3 + 1] = i1; idx[r * 3 + 2] = i2;
  }
}

// ---------------- colmean[n,c,v] = mean_t x[n,c,t,v], float4 ----------------
__global__ void k_colmean(const float* __restrict__ x, float* __restrict__ cm) {
  int nc = blockIdx.x;
  int v4 = threadIdx.x;
  if (v4 >= 51) return;
  const f32x4* base = (const f32x4*)(x + (size_t)nc * TV_);
  f32x4 acc = {0.f, 0.f, 0.f, 0.f};
  for (int t = 0; t < T_; ++t) {
    f32x4 a = base[t * 51 + v4];
    acc.x += a.x; acc.y += a.y; acc.z += a.z; acc.w += a.w;
  }
  const float sc = 1.0f / T_;
  acc.x *= sc; acc.y *= sc; acc.z *= sc; acc.w *= sc;
  ((f32x4*)(cm + (size_t)nc * V_))[v4] = acc;
}

// ---------------- w2[n,v,g] = sum_p softmax_p(mult)*convk_w[p] ----------------
__global__ void k_w2(const float* __restrict__ cm, const int* __restrict__ idx,
                     const float* __restrict__ tw, const float* __restrict__ tb,
                     const float* __restrict__ ckw, float* __restrict__ w2) {
  int r = blockIdx.x;  // n*V + v
  int n = r / V_;
  int lane = threadIdx.x;
  __shared__ float mv[3][C_];
  const int* ib = idx + r * 3;
  int j0 = ib[0], j1 = ib[1], j2 = ib[2];
  const float* cmn = cm + (size_t)n * C_ * V_;
  for (int c = lane; c < C_; c += 64) {
    mv[0][c] = cmn[c * V_ + j0];
    mv[1][c] = cmn[c * V_ + j1];
    mv[2][c] = cmn[c * V_ + j2];
  }
  __syncthreads();
  float p[9];
#pragma unroll
  for (int gp = 0; gp < 9; ++gp) p[gp] = 0.f;
  for (int c = lane; c < C_; c += 64) {
#pragma unroll
    for (int g = 0; g < 3; ++g) {
      float m = mv[g][c];
#pragma unroll
      for (int pp = 0; pp < 3; ++pp) p[g * 3 + pp] += m * tw[(g * 3 + pp) * C_ + c];
    }
  }
#pragma unroll
  for (int off = 32; off >= 1; off >>= 1) {
#pragma unroll
    for (int gp = 0; gp < 9; ++gp) p[gp] += __shfl_down(p[gp], off, 64);
  }
  if (lane == 0) {
    float c0 = ckw[0], c1 = ckw[1], c2 = ckw[2];
#pragma unroll
    for (int g = 0; g < 3; ++g) {
      float m0 = p[g * 3 + 0] + tb[g * 3 + 0];
      float m1 = p[g * 3 + 1] + tb[g * 3 + 1];
      float m2 = p[g * 3 + 2] + tb[g * 3 + 2];
      float mx = fmaxf(m0, fmaxf(m1, m2));
      float e0 = expf(m0 - mx), e1 = expf(m1 - mx), e2 = expf(m2 - mx);
      float inv = 1.0f / (e0 + e1 + e2);
      w2[r * 3 + g] = (e0 * c0 + e1 * c1 + e2 * c2) * inv;
    }
  }
}

// ---------------- x1 = relu(pooled + x), float4 over v ----------------
__global__ void k_x1(const float* __restrict__ x, const int* __restrict__ idx,
                     const float* __restrict__ w2, const float* __restrict__ ckb,
                     float* __restrict__ x1) {
  float cb = ckb[0];
  const unsigned NI4 = (unsigned)(NCTV_ / 4);
  for (unsigned i4 = blockIdx.x * 256u + threadIdx.x; i4 < NI4;
       i4 += gridDim.x * 256u) {
    unsigned v4 = i4 % 51u;
    unsigned r = i4 / 51u;
    int n = (int)(r >> 13);
    const float* xrow = x + (size_t)r * V_;
    f32x4 xv = ((const f32x4*)xrow)[v4];
    f32x4 o;
#pragma unroll
    for (int j = 0; j < 4; ++j) {
      int b = (n * V_ + (int)v4 * 4 + j) * 3;
      float pooled = xrow[idx[b]] * w2[b] + xrow[idx[b + 1]] * w2[b + 1] +
                     xrow[idx[b + 2]] * w2[b + 2] + cb;
      o[j] = fmaxf(pooled + xv[j], 0.f);
    }
    ((f32x4*)x1)[i4] = o;
  }
}

// ---------------- transpose fp32 [n][128][TV] -> bf16 [n][TV][128] --------
__global__ __launch_bounds__(256) void k_xpose(const float* __restrict__ src,
                                               unsigned short* __restrict__ dst) {
  int n = blockIdx.z, kt = blockIdx.y, lt = blockIdx.x;
  int l0 = lt * 64, k0 = kt * 32;
  __shared__ float Ts[32][65];
  int tid = threadIdx.x;
  int lc = tid & 63, kr = tid >> 6;
  const float* sb = src + (size_t)n * C_ * TV_;
#pragma unroll
  for (int it = 0; it < 8; ++it) {
    int k = kr + it * 4;
    Ts[k][lc] = sb[(size_t)(k0 + k) * TV_ + l0 + lc];
  }
  __syncthreads();
  int lrow = tid >> 2, ch = tid & 3;
  unsigned out[4];
#pragma unroll
  for (int q = 0; q < 4; ++q) {
    unsigned lo = bf16rnd(Ts[ch * 8 + 2 * q][lrow]);
    unsigned hi = bf16rnd(Ts[ch * 8 + 2 * q + 1][lrow]);
    out[q] = lo | (hi << 16);
  }
  size_t daddr = ((size_t)n * TV_ + l0 + lrow) * 128 + k0 + ch * 8;
  *(uint4*)(dst + daddr) = make_uint4(out[0], out[1], out[2], out[3]);
}

// ---- MFMA GEMM (MI m-subtiles/wave-half): Y = W@x1t (+bias) (+peb), fp32/bf16 out ----
template <int MI>
__global__ __launch_bounds__(256) void k_gmm(
    const float* __restrict__ W, int ldk, int mmask, int hstr,
    const unsigned short* __restrict__ Xt,
    const float* __restrict__ bias, const float* __restrict__ peb,
    void* __restrict__ Yv, int M, int obf) {
  int n = blockIdx.z;
  int tid = threadIdx.x, lane = tid & 63, wid = tid >> 6;
  int m0 = blockIdx.y * (MI * 32) + (wid >> 1) * (MI * 16);
  int l0 = blockIdx.x * 128 + (wid & 1) * 64;
  int lr = lane & 15, lg = lane >> 4;
  short8v a[MI][4];
#pragma unroll
  for (int mi = 0; mi < MI; ++mi) {
    int m = m0 + mi * 16 + lr;
    const float* wr = W + (size_t)(m & mmask) * ldk + (size_t)(m >> 7) * hstr;
#pragma unroll
    for (int ks = 0; ks < 4; ++ks) {
      f32x4 w0 = *(const f32x4*)(wr + ks * 32 + lg * 8);
      f32x4 w1 = *(const f32x4*)(wr + ks * 32 + lg * 8 + 4);
      short8v t;
      t[0] = (short)bf16rnd(w0[0]); t[1] = (short)bf16rnd(w0[1]);
      t[2] = (short)bf16rnd(w0[2]); t[3] = (short)bf16rnd(w0[3]);
      t[4] = (short)bf16rnd(w1[0]); t[5] = (short)bf16rnd(w1[1]);
      t[6] = (short)bf16rnd(w1[2]); t[7] = (short)bf16rnd(w1[3]);
      a[mi][ks] = t;
    }
  }
  f32x4 acc[MI][4];
#pragma unroll
  for (int mi = 0; mi < MI; ++mi)
#pragma unroll
    for (int li = 0; li < 4; ++li) acc[mi][li] = (f32x4){0.f, 0.f, 0.f, 0.f};
  const unsigned short* xb = Xt + (size_t)n * TV_ * 128;
#pragma unroll
  for (int ks = 0; ks < 4; ++ks) {
#pragma unroll
    for (int li = 0; li < 4; ++li) {
      short8v b = *(const short8v*)(xb + (size_t)(l0 + li * 16 + lr) * 128 + ks * 32 + lg * 8);
#pragma unroll
      for (int mi = 0; mi < MI; ++mi)
        acc[mi][li] = __builtin_amdgcn_mfma_f32_16x16x32_bf16(a[mi][ks], b, acc[mi][li], 0, 0, 0);
    }
  }
  float* Yf = (float*)Yv;
  unsigned short* Yh = (unsigned short*)Yv;
#pragma unroll
  for (int mi = 0; mi < MI; ++mi) {
#pragma unroll
    for (int li = 0; li < 4; ++li) {
      int l = l0 + li * 16 + lr;
      int t = l / V_;
#pragma unroll
      for (int r = 0; r < 4; ++r) {
        int m = m0 + mi * 16 + lg * 4 + r;
        float val = acc[mi][li][r];
        if (bias) val += bias[m];
        if (peb) val += peb[m * T_ + t];
        size_t o = ((size_t)n * M + m) * TV_ + l;
        if (obf) Yh[o] = bf16rnd(val);
        else Yf[o] = val;
      }
    }
  }
}

// ---- attention partials: attp[cp][n][h][t][q] = sum_{2c, v} q*k (bf16 in, fp32 out) ----
__global__ __launch_bounds__(256) void k_att(const unsigned short* __restrict__ qkv,
                                             float* __restrict__ attp) {
  int cp = blockIdx.x, h = blockIdx.y, n = blockIdx.z;
  __shared__ float Qs[102][68], Ks[102][68];
  int tid = threadIdx.x;
  int ty = tid >> 4, tx = tid & 15;
  float acc[4][4] = {};
  const unsigned short* qb = qkv + ((size_t)n * O2_ + h * QKD_) * TV_;
  const unsigned short* kb = qkv + ((size_t)n * O2_ + H_ * QKD_ + h * QKD_) * TV_;
  for (int cc = 0; cc < 2; ++cc) {
    int c = cp * 2 + cc;
    for (int vh = 0; vh < 2; ++vh) {
      for (int i = tid; i < 64 * 102; i += 256) {
        int t = i / 102, v = i - t * 102;
        int vg = vh * 102 + v;
        size_t gi = (size_t)(c * T_ + t) * V_ + vg;
        Qs[v][t] = bf2f(qb[gi]);
        Ks[v][t] = bf2f(kb[gi]);
      }
      __syncthreads();
      for (int vv = 0; vv < 102; ++vv) {
        f32x4 qa = *(const f32x4*)&Qs[vv][ty * 4];
        f32x4 ka = *(const f32x4*)&Ks[vv][tx * 4];
#pragma unroll
        for (int i = 0; i < 4; ++i)
#pragma unroll
          for (int j = 0; j < 4; ++j) acc[i][j] += qa[i] * ka[j];
      }
      __syncthreads();
    }
  }
  float* ar = attp + (((size_t)cp * N_ + n) * H_ + h) * TT_;
#pragma unroll
  for (int i = 0; i < 4; ++i)
#pragma unroll
    for (int j = 0; j < 4; ++j)
      ar[(ty * 4 + i) * T_ + tx * 4 + j] = acc[i][j];
}

// ---- attT[n][q][h*64+t] = bf16(tanh(sum_cp attp /6528)*alpha + att1s) ----
__global__ void k_attfin(const float* __restrict__ attp, const float* __restrict__ alphas,
                         const float* __restrict__ att1s, unsigned short* __restrict__ attT) {
  int i = blockIdx.x * blockDim.x + threadIdx.x;
  if (i >= N_ * H_ * TT_) return;
  int tt = i % TT_;
  int h = (i / TT_) % H_;
  int n = i / (H_ * TT_);
  float raw = 0.f;
#pragma unroll
  for (int cp = 0; cp < 16; ++cp)
    raw += attp[(((size_t)cp * N_ + n) * H_ + h) * TT_ + tt];
  int t = tt >> 6, q = tt & 63;
  float v = tanhf(raw * (1.0f / 6528.0f)) * alphas[h] + att1s[h * TT_ + tt];
  attT[(size_t)(n * 64 + q) * 192 + h * 64 + t] = bf16rnd(v);
}

// ---- combine: out_pre[n][o][q][v] = sum_{ht} attT[n][q][ht]*Y3[n][h*128+o][t][v] + b ----
__global__ __launch_bounds__(256) void k_comb(const unsigned short* __restrict__ Y3,
                                              const unsigned short* __restrict__ attT,
                                              const float* __restrict__ outb,
                                              float* __restrict__ op) {
  int n = blockIdx.z, o = blockIdx.y, vt = blockIdx.x;  // vt 0..3
  int v0 = vt * 64;
  __shared__ unsigned short Bt[64][200];
  int tid = threadIdx.x, lane = tid & 63, wv = tid >> 6;
  const unsigned short* yb = Y3 + (size_t)n * 384 * TV_;
#pragma unroll
  for (int p = 0; p < 24; ++p) {
    int g = tid + p * 256;
    int ht = g >> 5, pr = g & 31;
    int v = v0 + pr * 2;
    int row = (ht >> 6) * 128 + o;
    unsigned val = 0;
    if (v + 1 < V_) val = *(const unsigned*)(yb + (size_t)row * TV_ + (ht & 63) * V_ + v);
    Bt[pr * 2][ht] = (unsigned short)(val & 0xffffu);
    Bt[pr * 2 + 1][ht] = (unsigned short)(val >> 16);
  }
  __syncthreads();
  int lr = lane & 15, lg = lane >> 4;
  const unsigned short* ab = attT + (size_t)n * 64 * 192;
  f32x4 acc[4];
#pragma unroll
  for (int mi = 0; mi < 4; ++mi) acc[mi] = (f32x4){0.f, 0.f, 0.f, 0.f};
#pragma unroll
  for (int ks = 0; ks < 6; ++ks) {
    short8v b = *(const short8v*)&Bt[wv * 16 + lr][ks * 32 + lg * 8];
#pragma unroll
    for (int mi = 0; mi < 4; ++mi) {
      short8v a = *(const short8v*)(ab + (size_t)(mi * 16 + lr) * 192 + ks * 32 + lg * 8);
      acc[mi] = __builtin_amdgcn_mfma_f32_16x16x32_bf16(a, b, acc[mi], 0, 0, 0);
    }
  }
  float bo = outb[o];
  int v = v0 + wv * 16 + lr;
  if (v < V_) {
#pragma unroll
    for (int mi = 0; mi < 4; ++mi)
#pragma unroll
      for (int r = 0; r < 4; ++r) {
        int q = mi * 16 + lg * 4 + r;
        op[(((size_t)n * C_ + o) * T_ + q) * V_ + v] = acc[mi][r] + bo;
      }
  }
}

// ---------------- BN partial stats: grid (4, C_), 2 n per block, float4 ----------------
__global__ void k_bnstats(const float* __restrict__ xp, float* __restrict__ part) {
  int qd = blockIdx.x, c = blockIdx.y;
  int tid = threadIdx.x;
  float s1 = 0.f, s2 = 0.f;
#pragma unroll
  for (int nn = 0; nn < 2; ++nn) {
    const f32x4* base = (const f32x4*)(xp + ((size_t)(qd * 2 + nn) * C_ + c) * TV_);
    for (int i = tid; i < 3264; i += 256) {
      f32x4 v = base[i];
      s1 += v.x + v.y + v.z + v.w;
      s2 += v.x * v.x + v.y * v.y + v.z * v.z + v.w * v.w;
    }
  }
  __shared__ float r1[256], r2[256];
  r1[tid] = s1; r2[tid] = s2;
  __syncthreads();
  for (int off = 128; off >= 1; off >>= 1) {
    if (tid < off) { r1[tid] += r1[tid + off]; r2[tid] += r2[tid + off]; }
    __syncthreads();
  }
  if (tid == 0) {
    part[(c * 4 + qd) * 2] = r1[0];
    part[(c * 4 + qd) * 2 + 1] = r2[0];
  }
}

__global__ void k_bnfin(const float* __restrict__ part, float* __restrict__ mu,
                        float* __restrict__ rstd) {
  int c = threadIdx.x;
  float s1 = 0.f, s2 = 0.f;
#pragma unroll
  for (int qd = 0; qd < 4; ++qd) {
    s1 += part[(c * 4 + qd) * 2];
    s2 += part[(c * 4 + qd) * 2 + 1];
  }
  const float cnt = (float)(N_ * TV_);
  float m = s1 / cnt;
  mu[c] = m;
  rstd[c] = rsqrtf(s2 / cnt - m * m + 1e-5f);
}

// ---------------- leaky_relu(bn(xp)+x1), float4 ----------------
__global__ void k_bnres(const float* __restrict__ xp, const float* __restrict__ mu,
                        const float* __restrict__ rstd, const float* __restrict__ g,
                        const float* __restrict__ beta, const float* __restrict__ x1,
                        float* __restrict__ out) {
  const unsigned NI4 = (unsigned)(NCTV_ / 4);
  for (unsigned i4 = blockIdx.x * 256u + threadIdx.x; i4 < NI4;
       i4 += gridDim.x * 256u) {
    int c = (int)((i4 / 3264u) & 127u);
    float a = rstd[c] * g[c];
    float b = beta[c] - mu[c] * a;
    f32x4 v = ((const f32x4*)xp)[i4];
    f32x4 r = ((const f32x4*)x1)[i4];
    f32x4 o;
#pragma unroll
    for (int j = 0; j < 4; ++j) {
      float t = v[j] * a + b + r[j];
      o[j] = t > 0.f ? t : 0.1f * t;
    }
    ((f32x4*)out)[i4] = o;
  }
}

extern "C" void kernel_launch(void* const* d_in, const int* in_sizes, int n_in,
                              void* d_out, int out_size, void* d_ws, size_t ws_size,
                              hipStream_t stream) {
  (void)in_sizes; (void)n_in; (void)out_size; (void)ws_size;
  const float* x        = (const float*)d_in[0];
  const float* trans_w  = (const float*)d_in[1];
  const float* trans_b  = (const float*)d_in[2];
  const float* convk_w  = (const float*)d_in[3];
  const float* convk_b  = (const float*)d_in[4];
  const float* qkv_w    = (const float*)d_in[5];
  const float* qkv_b    = (const float*)d_in[6];
  const float* alphas   = (const float*)d_in[7];
  const float* att1s    = (const float*)d_in[8];
  const float* out_w    = (const float*)d_in[9];
  const float* out_b    = (const float*)d_in[10];
  const float* out_g    = (const float*)d_in[11];
  const float* out_beta = (const float*)d_in[12];
  const float* ff_w     = (const float*)d_in[13];
  const float* ff_b     = (const float*)d_in[14];
  const float* ff_g     = (const float*)d_in[15];
  const float* ff_beta  = (const float*)d_in[16];

  float* ws = (float*)d_ws;
  size_t off = 0;
  float* x1   = ws + off; off += NCTV_;                    // 13.37M fl
  float* big  = ws + off; off += (size_t)N_ * O2_ * TV_;   // 20.05M fl (pdis -> qkv bf16 -> Y3 bf16 -> ff_pre)
  float* sbuf = ws + off; off += (size_t)N_ * CT_;
  int*   idx  = (int*)(ws + off); off += (size_t)N_ * V_ * 3 + 4;
  float* cm   = ws + off; off += (size_t)N_ * C_ * V_;
  float* w2   = ws + off; off += (size_t)N_ * V_ * 3 + 4;
  float* attp = ws + off; off += (size_t)16 * N_ * H_ * TT_;   // 1.57M fl
  unsigned short* attT = (unsigned short*)(ws + off); off += (size_t)N_ * 64 * 192 / 2;
  float* bn   = ws + off; off += 512;
  float* part = ws + off; off += 1024;
  float* qpe  = ws + off; off += (size_t)O2_ * T_;
  unsigned short* x1t = (unsigned short*)(ws + off); off += NCTV_ / 2;

  float* dout = (float*)d_out;  // out_pre -> xs3 (in place) -> final

  k_qkvpe<<<48, 256, 0, stream>>>(qkv_w, qpe);
  k_scale<<<(N_ * CT_ * 64) / 256, 256, 0, stream>>>(x, sbuf);
  k_dis<<<dim3(10, DSPLIT_, N_), 256, 0, stream>>>(x, sbuf, big);
  k_topk2<<<N_ * V_, 64, 0, stream>>>(big, idx);
  k_colmean<<<N_ * C_, 64, 0, stream>>>(x, cm);
  k_w2<<<N_ * V_, 64, 0, stream>>>(cm, idx, trans_w, trans_b, convk_w, w2);
  k_x1<<<4096, 256, 0, stream>>>(x, idx, w2, convk_b, x1);

  // x1t = bf16 transpose of x1 (pe folded via qpe bias)
  k_xpose<<<dim3(204, 4, N_), 256, 0, stream>>>(x1, x1t);

  // qkv = W@x1 + qkv_b + qkvpe -> big (bf16)
  k_gmm<3><<<dim3(102, 2, N_), 256, 0, stream>>>(qkv_w, 128, 255, 0, x1t, qkv_b, qpe,
                                                 big, O2_, 1);

  k_att<<<dim3(16, H_, N_), 256, 0, stream>>>((const unsigned short*)big, attp);
  k_attfin<<<384, 256, 0, stream>>>(attp, alphas, att1s, attT);

  // Y3[n][h*128+o][t][v] = (W_h @ x1) bf16 -> big (overwrites qkv, consumed)
  k_gmm<4><<<dim3(102, 3, N_), 256, 0, stream>>>(out_w, 384, 127, 128, x1t, nullptr,
                                                 nullptr, big, 384, 1);

  // out_pre = sum_ht attT * Y3 + out_b -> d_out
  k_comb<<<dim3(4, C_, N_), 256, 0, stream>>>((const unsigned short*)big, attT, out_b, dout);

  k_bnstats<<<dim3(4, C_), 256, 0, stream>>>(dout, part);
  k_bnfin<<<1, 128, 0, stream>>>(part, bn, bn + C_);
  k_bnres<<<4096, 256, 0, stream>>>(dout, bn, bn + C_, out_g, out_beta, x1, dout);

  // xs3t = bf16 transpose of xs3 (reuse x1t)
  k_xpose<<<dim3(204, 4, N_), 256, 0, stream>>>(dout, x1t);

  // ff_pre = ff_w @ xs3 + ff_b -> big (fp32)
  k_gmm<4><<<dim3(102, 1, N_), 256, 0, stream>>>(ff_w, 128, 255, 0, x1t, ff_b, nullptr,
                                                 big, C_, 0);
  k_bnstats<<<dim3(4, C_), 256, 0, stream>>>(big, part);
  k_bnfin<<<1, 128, 0, stream>>>(part, bn + 2 * C_, bn + 3 * C_);
  k_bnres<<<4096, 256, 0, stream>>>(big, bn + 2 * C_, bn + 3 * C_, ff_g, ff_beta, x1, dout);
}

// Round 5
// 596.981 us; speedup vs baseline: 3.9710x; 1.0696x over previous
//
#include <hip/hip_runtime.h>
#include <math.h>

#define N_ 8
#define C_ 128
#define T_ 64
#define V_ 204
#define K_ 3
#define H_ 3
#define QKD_ 32
#define O2_ 192            // 2*H*QKD
#define TV_ 13056          // T*V
#define CT_ 8192           // C*T
#define TT_ 4096           // T*T
#define VV_ 41616          // V*V
#define NCTV_ 13369344ull  // N*C*T*V
#define DSPLIT_ 16         // K-split factor for dis
#define ZR_ 208            // padded row count for Z (204 -> 208)

typedef __attribute__((ext_vector_type(8))) short short8v;
typedef __attribute__((ext_vector_type(4))) float f32x4;

__device__ inline unsigned short bf16rnd(float f) {
  union { float f; unsigned u; } x; x.f = f;
  return (unsigned short)((x.u + 0x7FFFu + ((x.u >> 16) & 1u)) >> 16);
}
__device__ inline float bf2f(unsigned short u) {
  union { unsigned u; float f; } x; x.u = ((unsigned)u) << 16;
  return x.f;
}

// ---- qkvpe[m][t] = sum_c qkv_w[m][c]*pe[c][t]; pe built in LDS ----
__global__ void k_qkvpe(const float* __restrict__ qw, float* __restrict__ qpe) {
  __shared__ float pes[C_ * T_];
  int tid = threadIdx.x;
  for (int i = tid; i < C_ * T_; i += 256) {
    int t = i & 63, c = i >> 6;
    int j = c >> 1;
    float dv = expf((2.0f * j) * (-logf(10000.0f) / (float)C_));
    float ang = (float)t * dv;
    pes[i] = (c & 1) ? cosf(ang) : sinf(ang);
  }
  __syncthreads();
  int g = blockIdx.x * 256 + tid;
  int t = g & 63, m = g >> 6;
  float a = 0.f;
  for (int c = 0; c < C_; ++c) a += qw[m * C_ + c] * pes[c * T_ + t];
  qpe[g] = a;
}

// ---------------- s[n,c,t] = 1/max(||x||,1e-12)^2, float4 ----------------
__global__ void k_scale(const float* __restrict__ x, float* __restrict__ s) {
  int gid = blockIdx.x * blockDim.x + threadIdx.x;
  int w = gid >> 6, lane = gid & 63;
  if (w >= N_ * CT_) return;
  const f32x4* row = (const f32x4*)(x + (size_t)w * V_);
  float a = 0.f;
  for (int v4 = lane; v4 < 51; v4 += 64) {
    f32x4 t = row[v4];
    a += t.x * t.x + t.y * t.y + t.z * t.z + t.w * t.w;
  }
#pragma unroll
  for (int off = 32; off >= 1; off >>= 1) a += __shfl_down(a, off, 64);
  if (lane == 0) {
    float d = fmaxf(sqrtf(a), 1e-12f);
    s[w] = 1.0f / (d * d);
  }
}

// ---- Z-prep: z[k][u] = x[k][u]*sqrt(s[k]) -> fragment-major bf16 hi/lo
//      zhi/zlo layout: [n][k/8 (1024)][u (208)][8 bf16]; also colmean fused.
__global__ __launch_bounds__(256) void k_zprep(const float* __restrict__ x,
                                               const float* __restrict__ s,
                                               unsigned short* __restrict__ zhi,
                                               unsigned short* __restrict__ zlo,
                                               float* __restrict__ cm) {
  int kt = blockIdx.x, ut = blockIdx.y, n = blockIdx.z;  // kt = c (64 t-rows)
  int k0 = kt * 64, u0 = ut * 64;
  __shared__ float Ts[64][65];
  __shared__ float sq[64];
  int tid = threadIdx.x;
  int uu = tid & 63, kk = tid >> 6;
  int u = u0 + uu;
  bool uok = u < V_;
  const float* xb = x + (size_t)n * CT_ * V_;
#pragma unroll
  for (int it = 0; it < 16; ++it) {
    int kr = kk + it * 4;
    Ts[kr][uu] = uok ? xb[(size_t)(k0 + kr) * V_ + u] : 0.f;
  }
  if (tid < 64) sq[tid] = sqrtf(s[(size_t)n * CT_ + k0 + tid]);
  __syncthreads();
  // fused colmean: cm[n][c=kt][u] = mean_t x
  if (tid < 64 && uok) {
    float a = 0.f;
    for (int t = 0; t < 64; ++t) a += Ts[t][tid];
    cm[((size_t)n * C_ + kt) * V_ + u] = a * (1.0f / 64.0f);
  }
  // z write: 64u x 8oct x 2(hi/lo) 16B chunks = 1024 slots
#pragma unroll
  for (int it = 0; it < 4; ++it) {
    int sl = tid + it * 256;
    int u_l = sl & 63, oct = (sl >> 6) & 7, half = sl >> 9;
    int ug = u0 + u_l;
    if (ug >= ZR_) continue;
    unsigned short buf[8];
    if (ug < V_) {
#pragma unroll
      for (int j = 0; j < 8; ++j) {
        float z = Ts[oct * 8 + j][u_l] * sq[oct * 8 + j];
        unsigned short h = bf16rnd(z);
        buf[j] = half ? bf16rnd(z - bf2f(h)) : h;
      }
    } else {
#pragma unroll
      for (int j = 0; j < 8; ++j) buf[j] = 0;
    }
    unsigned short* dst = (half ? zlo : zhi) +
                          (((size_t)n * 1024 + kt * 8 + oct) * ZR_ + ug) * 8;
    *(uint4*)dst = *(const uint4*)buf;
  }
}

// ---- dis via split-bf16 MFMA: pdis[sp][n] partial Gram, 128^2 tiles, triangle ----
__global__ __launch_bounds__(256) void k_dism(const unsigned short* __restrict__ zhi,
                                              const unsigned short* __restrict__ zlo,
                                              float* __restrict__ pdis) {
  int q = blockIdx.x, sp = blockIdx.y, n = blockIdx.z;
  int bu = (q == 2) ? 1 : 0, bv = (q == 0) ? 0 : 1;
  int u0 = bu * 128, v0 = bv * 128;
  bool dg = (bu == bv);
  __shared__ unsigned short As[8 * 128 * 8];  // [(half*4+slot)][row][8]
  __shared__ unsigned short Bs[8 * 128 * 8];
  int tid = threadIdx.x, lane = tid & 63, wid = tid >> 6;
  int lr = lane & 15, lg = lane >> 4;
  f32x4 acc[2][8];
#pragma unroll
  for (int mi = 0; mi < 2; ++mi)
#pragma unroll
    for (int li = 0; li < 8; ++li) acc[mi][li] = (f32x4){0.f, 0.f, 0.f, 0.f};
  int kend = sp * 512 + 512;
  for (int kk = sp * 512; kk < kend; kk += 32) {
    int koct = kk >> 3;
    __syncthreads();
#pragma unroll
    for (int it = 0; it < 4; ++it) {
      int sl = tid + it * 256;
      int row = sl & 127, hs = sl >> 7;  // hs = half*4+slot
      int slot = hs & 3, half = hs >> 2;
      const unsigned short* src = half ? zlo : zhi;
      size_t ob = ((size_t)n * 1024 + koct + slot) * ZR_;
      int ra = u0 + row; ra = ra > 207 ? 207 : ra;
      *(uint4*)&As[(hs * 128 + row) * 8] = *(const uint4*)(src + (ob + ra) * 8);
      if (!dg) {
        int rb = v0 + row; rb = rb > 207 ? 207 : rb;
        *(uint4*)&Bs[(hs * 128 + row) * 8] = *(const uint4*)(src + (ob + rb) * 8);
      }
    }
    __syncthreads();
    const unsigned short* Bp = dg ? As : Bs;
    short8v ah[2], al[2];
#pragma unroll
    for (int mi = 0; mi < 2; ++mi) {
      int r = wid * 32 + mi * 16 + lr;
      ah[mi] = *(const short8v*)&As[(lg * 128 + r) * 8];
      al[mi] = *(const short8v*)&As[((4 + lg) * 128 + r) * 8];
    }
#pragma unroll
    for (int li = 0; li < 8; ++li) {
      int rv = li * 16 + lr;
      short8v bh = *(const short8v*)&Bp[(lg * 128 + rv) * 8];
      short8v bl = *(const short8v*)&Bp[((4 + lg) * 128 + rv) * 8];
#pragma unroll
      for (int mi = 0; mi < 2; ++mi) {
        acc[mi][li] = __builtin_amdgcn_mfma_f32_16x16x32_bf16(ah[mi], bh, acc[mi][li], 0, 0, 0);
        acc[mi][li] = __builtin_amdgcn_mfma_f32_16x16x32_bf16(ah[mi], bl, acc[mi][li], 0, 0, 0);
        acc[mi][li] = __builtin_amdgcn_mfma_f32_16x16x32_bf16(al[mi], bh, acc[mi][li], 0, 0, 0);
      }
    }
  }
  float* pb = pdis + ((size_t)sp * N_ + n) * VV_;
#pragma unroll
  for (int mi = 0; mi < 2; ++mi) {
#pragma unroll
    for (int li = 0; li < 8; ++li) {
      int v = v0 + li * 16 + lr;
      if (v >= V_) continue;
#pragma unroll
      for (int rr = 0; rr < 4; ++rr) {
        int u = u0 + wid * 32 + mi * 16 + lg * 4 + rr;
        if (u >= V_) continue;
        float val = acc[mi][li][rr];
        pb[(size_t)u * V_ + v] = val;
        if (!dg) pb[(size_t)v * V_ + u] = val;
      }
    }
  }
}

// ---- fused: sum 16 dis-partials + wave-parallel top-3 (lex (val desc, idx asc)) ----
__global__ void k_topk2(const float* __restrict__ pdis, int* __restrict__ idx) {
  int r = blockIdx.x;  // n*V + u
  int n = r / V_, u = r - n * V_;
  int lane = threadIdx.x;
  float m0 = -INFINITY, m1 = -INFINITY, m2 = -INFINITY;
  int i0 = 0x7fffffff, i1 = 0x7fffffff, i2 = 0x7fffffff;
#pragma unroll
  for (int g = 0; g < 4; ++g) {
    int v = g * 64 + lane;
    if (v >= V_) break;
    float a = 0.f;
#pragma unroll
    for (int sp = 0; sp < DSPLIT_; ++sp)
      a += pdis[((size_t)sp * N_ + n) * VV_ + (size_t)u * V_ + v];
    if (a > m0 || (a == m0 && v < i0)) {
      m2 = m1; i2 = i1; m1 = m0; i1 = i0; m0 = a; i0 = v;
    } else if (a > m1 || (a == m1 && v < i1)) {
      m2 = m1; i2 = i1; m1 = a; i1 = v;
    } else if (a > m2 || (a == m2 && v < i2)) {
      m2 = a; i2 = v;
    }
  }
#pragma unroll
  for (int msk = 1; msk < 64; msk <<= 1) {
    float o0 = __shfl_xor(m0, msk, 64), o1 = __shfl_xor(m1, msk, 64),
          o2 = __shfl_xor(m2, msk, 64);
    int p0 = __shfl_xor(i0, msk, 64), p1 = __shfl_xor(i1, msk, 64),
        p2 = __shfl_xor(i2, msk, 64);
    float ov[3] = {o0, o1, o2};
    int op[3] = {p0, p1, p2};
#pragma unroll
    for (int e = 0; e < 3; ++e) {
      float a = ov[e]; int v = op[e];
      if (a > m0 || (a == m0 && v < i0)) {
        m2 = m1; i2 = i1; m1 = m0; i1 = i0; m0 = a; i0 = v;
      } else if (a > m1 || (a == m1 && v < i1)) {
        m2 = m1; i2 = i1; m1 = a; i1 = v;
      } else if (a > m2 || (a == m2 && v < i2)) {
        m2 = a; i2 = v;
      }
    }
  }
  if (lane == 0) {
    idx[r * 3 + 0] = i0; idx[r * 3 + 1] = i1; idx[r * 3 + 2] = i2;
  }
}

// ---------------- w2[n,v,g] = sum_p softmax_p(mult)*convk_w[p] ----------------
__global__ void k_w2(const float* __restrict__ cm, const int* __restrict__ idx,
                     const float* __restrict__ tw, const float* __restrict__ tb,
                     const float* __restrict__ ckw, float* __restrict__ w2) {
  int r = blockIdx.x;  // n*V + v
  int n = r / V_;
  int lane = threadIdx.x;
  __shared__ float mv[3][C_];
  const int* ib = idx + r * 3;
  int j0 = ib[0], j1 = ib[1], j2 = ib[2];
  const float* cmn = cm + (size_t)n * C_ * V_;
  for (int c = lane; c < C_; c += 64) {
    mv[0][c] = cmn[c * V_ + j0];
    mv[1][c] = cmn[c * V_ + j1];
    mv[2][c] = cmn[c * V_ + j2];
  }
  __syncthreads();
  float p[9];
#pragma unroll
  for (int gp = 0; gp < 9; ++gp) p[gp] = 0.f;
  for (int c = lane; c < C_; c += 64) {
#pragma unroll
    for (int g = 0; g < 3; ++g) {
      float m = mv[g][c];
#pragma unroll
      for (int pp = 0; pp < 3; ++pp) p[g * 3 + pp] += m * tw[(g * 3 + pp) * C_ + c];
    }
  }
#pragma unroll
  for (int off = 32; off >= 1; off >>= 1) {
#pragma unroll
    for (int gp = 0; gp < 9; ++gp) p[gp] += __shfl_down(p[gp], off, 64);
  }
  if (lane == 0) {
    float c0 = ckw[0], c1 = ckw[1], c2 = ckw[2];
#pragma unroll
    for (int g = 0; g < 3; ++g) {
      float m0 = p[g * 3 + 0] + tb[g * 3 + 0];
      float m1 = p[g * 3 + 1] + tb[g * 3 + 1];
      float m2 = p[g * 3 + 2] + tb[g * 3 + 2];
      float mx = fmaxf(m0, fmaxf(m1, m2));
      float e0 = expf(m0 - mx), e1 = expf(m1 - mx), e2 = expf(m2 - mx);
      float inv = 1.0f / (e0 + e1 + e2);
      w2[r * 3 + g] = (e0 * c0 + e1 * c1 + e2 * c2) * inv;
    }
  }
}

// ---- fused x1 + transpose: x1 fp32 [n][c][l], x1t bf16 [n][l][c] ----
__global__ __launch_bounds__(256) void k_x1t(const float* __restrict__ x,
                                             const int* __restrict__ idx,
                                             const float* __restrict__ w2,
                                             const float* __restrict__ ckb,
                                             float* __restrict__ x1,
                                             unsigned short* __restrict__ x1t) {
  int lt = blockIdx.x, ct = blockIdx.y, n = blockIdx.z;
  int l0 = lt * 64, c0 = ct * 32;
  __shared__ float Ts[32][65];
  float cb = ckb[0];
  int tid = threadIdx.x;
  int lc = tid & 63, cr = tid >> 6;
  int l = l0 + lc;
  int v = l % V_, t = l / V_;
  int b = ((size_t)n * V_ + v) * 3;
  int i0 = idx[b], i1 = idx[b + 1], i2 = idx[b + 2];
  float wa = w2[b], wb = w2[b + 1], wc = w2[b + 2];
#pragma unroll
  for (int it = 0; it < 8; ++it) {
    int c = c0 + cr + it * 4;
    const float* xrow = x + ((size_t)(n * C_ + c)) * TV_ + t * V_;
    float pooled = xrow[i0] * wa + xrow[i1] * wb + xrow[i2] * wc + cb;
    float val = fmaxf(pooled + xrow[v], 0.f);
    Ts[cr + it * 4][lc] = val;
    x1[((size_t)(n * C_ + c)) * TV_ + l] = val;
  }
  __syncthreads();
  int lrow = tid >> 2, qo = tid & 3;
  unsigned short buf[8];
#pragma unroll
  for (int j = 0; j < 8; ++j) buf[j] = bf16rnd(Ts[qo * 8 + j][lrow]);
  *(uint4*)(x1t + ((size_t)n * TV_ + l0 + lrow) * 128 + c0 + qo * 8) = *(const uint4*)buf;
}

// ---- MFMA GEMM (MI m-subtiles/wave-half): Y = W@x1t (+bias) (+peb), fp32/bf16 out ----
template <int MI>
__global__ __launch_bounds__(256) void k_gmm(
    const float* __restrict__ W, int ldk, int mmask, int hstr,
    const unsigned short* __restrict__ Xt,
    const float* __restrict__ bias, const float* __restrict__ peb,
    void* __restrict__ Yv, int M, int obf) {
  int n = blockIdx.z;
  int tid = threadIdx.x, lane = tid & 63, wid = tid >> 6;
  int m0 = blockIdx.y * (MI * 32) + (wid >> 1) * (MI * 16);
  int l0 = blockIdx.x * 128 + (wid & 1) * 64;
  int lr = lane & 15, lg = lane >> 4;
  short8v a[MI][4];
#pragma unroll
  for (int mi = 0; mi < MI; ++mi) {
    int m = m0 + mi * 16 + lr;
    const float* wr = W + (size_t)(m & mmask) * ldk + (size_t)(m >> 7) * hstr;
#pragma unroll
    for (int ks = 0; ks < 4; ++ks) {
      f32x4 w0 = *(const f32x4*)(wr + ks * 32 + lg * 8);
      f32x4 w1 = *(const f32x4*)(wr + ks * 32 + lg * 8 + 4);
      short8v t;
      t[0] = (short)bf16rnd(w0[0]); t[1] = (short)bf16rnd(w0[1]);
      t[2] = (short)bf16rnd(w0[2]); t[3] = (short)bf16rnd(w0[3]);
      t[4] = (short)bf16rnd(w1[0]); t[5] = (short)bf16rnd(w1[1]);
      t[6] = (short)bf16rnd(w1[2]); t[7] = (short)bf16rnd(w1[3]);
      a[mi][ks] = t;
    }
  }
  f32x4 acc[MI][4];
#pragma unroll
  for (int mi = 0; mi < MI; ++mi)
#pragma unroll
    for (int li = 0; li < 4; ++li) acc[mi][li] = (f32x4){0.f, 0.f, 0.f, 0.f};
  const unsigned short* xb = Xt + (size_t)n * TV_ * 128;
#pragma unroll
  for (int ks = 0; ks < 4; ++ks) {
#pragma unroll
    for (int li = 0; li < 4; ++li) {
      short8v b = *(const short8v*)(xb + (size_t)(l0 + li * 16 + lr) * 128 + ks * 32 + lg * 8);
#pragma unroll
      for (int mi = 0; mi < MI; ++mi)
        acc[mi][li] = __builtin_amdgcn_mfma_f32_16x16x32_bf16(a[mi][ks], b, acc[mi][li], 0, 0, 0);
    }
  }
  float* Yf = (float*)Yv;
  unsigned short* Yh = (unsigned short*)Yv;
#pragma unroll
  for (int mi = 0; mi < MI; ++mi) {
#pragma unroll
    for (int li = 0; li < 4; ++li) {
      int l = l0 + li * 16 + lr;
      int t = l / V_;
#pragma unroll
      for (int r = 0; r < 4; ++r) {
        int m = m0 + mi * 16 + lg * 4 + r;
        float val = acc[mi][li][r];
        if (bias) val += bias[m];
        if (peb) val += peb[m * T_ + t];
        size_t o = ((size_t)n * M + m) * TV_ + l;
        if (obf) Yh[o] = bf16rnd(val);
        else Yf[o] = val;
      }
    }
  }
}

// ---- attention partials: attp[cp][n][h][t][q] (bf16 in, fp32 out) ----
__global__ __launch_bounds__(256) void k_att(const unsigned short* __restrict__ qkv,
                                             float* __restrict__ attp) {
  int cp = blockIdx.x, h = blockIdx.y, n = blockIdx.z;
  __shared__ float Qs[102][68], Ks[102][68];
  int tid = threadIdx.x;
  int ty = tid >> 4, tx = tid & 15;
  float acc[4][4] = {};
  const unsigned short* qb = qkv + ((size_t)n * O2_ + h * QKD_) * TV_;
  const unsigned short* kb = qkv + ((size_t)n * O2_ + H_ * QKD_ + h * QKD_) * TV_;
  for (int cc = 0; cc < 2; ++cc) {
    int c = cp * 2 + cc;
    for (int vh = 0; vh < 2; ++vh) {
      for (int i = tid; i < 64 * 102; i += 256) {
        int t = i / 102, v = i - t * 102;
        int vg = vh * 102 + v;
        size_t gi = (size_t)(c * T_ + t) * V_ + vg;
        Qs[v][t] = bf2f(qb[gi]);
        Ks[v][t] = bf2f(kb[gi]);
      }
      __syncthreads();
      for (int vv = 0; vv < 102; ++vv) {
        f32x4 qa = *(const f32x4*)&Qs[vv][ty * 4];
        f32x4 ka = *(const f32x4*)&Ks[vv][tx * 4];
#pragma unroll
        for (int i = 0; i < 4; ++i)
#pragma unroll
          for (int j = 0; j < 4; ++j) acc[i][j] += qa[i] * ka[j];
      }
      __syncthreads();
    }
  }
  float* ar = attp + (((size_t)cp * N_ + n) * H_ + h) * TT_;
#pragma unroll
  for (int i = 0; i < 4; ++i)
#pragma unroll
    for (int j = 0; j < 4; ++j)
      ar[(ty * 4 + i) * T_ + tx * 4 + j] = acc[i][j];
}

// ---- attT[n][q][h*64+t] = bf16(tanh(sum_cp attp /6528)*alpha + att1s) ----
__global__ void k_attfin(const float* __restrict__ attp, const float* __restrict__ alphas,
                         const float* __restrict__ att1s, unsigned short* __restrict__ attT) {
  int i = blockIdx.x * blockDim.x + threadIdx.x;
  if (i >= N_ * H_ * TT_) return;
  int tt = i % TT_;
  int h = (i / TT_) % H_;
  int n = i / (H_ * TT_);
  float raw = 0.f;
#pragma unroll
  for (int cp = 0; cp < 16; ++cp)
    raw += attp[(((size_t)cp * N_ + n) * H_ + h) * TT_ + tt];
  int t = tt >> 6, q = tt & 63;
  float v = tanhf(raw * (1.0f / 6528.0f)) * alphas[h] + att1s[h * TT_ + tt];
  attT[(size_t)(n * 64 + q) * 192 + h * 64 + t] = bf16rnd(v);
}

// ---- combine: out_pre[n][o][q][v] = sum_{ht} attT[n][q][ht]*Y3[n][h*128+o][t][v] + b ----
__global__ __launch_bounds__(256) void k_comb(const unsigned short* __restrict__ Y3,
                                              const unsigned short* __restrict__ attT,
                                              const float* __restrict__ outb,
                                              float* __restrict__ op) {
  int n = blockIdx.z, o = blockIdx.y, vt = blockIdx.x;  // vt 0..3
  int v0 = vt * 64;
  __shared__ unsigned short Bt[64][200];
  int tid = threadIdx.x, lane = tid & 63, wv = tid >> 6;
  const unsigned short* yb = Y3 + (size_t)n * 384 * TV_;
#pragma unroll
  for (int p = 0; p < 24; ++p) {
    int g = tid + p * 256;
    int ht = g >> 5, pr = g & 31;
    int v = v0 + pr * 2;
    int row = (ht >> 6) * 128 + o;
    unsigned val = 0;
    if (v + 1 < V_) val = *(const unsigned*)(yb + (size_t)row * TV_ + (ht & 63) * V_ + v);
    Bt[pr * 2][ht] = (unsigned short)(val & 0xffffu);
    Bt[pr * 2 + 1][ht] = (unsigned short)(val >> 16);
  }
  __syncthreads();
  int lr = lane & 15, lg = lane >> 4;
  const unsigned short* ab = attT + (size_t)n * 64 * 192;
  f32x4 acc[4];
#pragma unroll
  for (int mi = 0; mi < 4; ++mi) acc[mi] = (f32x4){0.f, 0.f, 0.f, 0.f};
#pragma unroll
  for (int ks = 0; ks < 6; ++ks) {
    short8v b = *(const short8v*)&Bt[wv * 16 + lr][ks * 32 + lg * 8];
#pragma unroll
    for (int mi = 0; mi < 4; ++mi) {
      short8v a = *(const short8v*)(ab + (size_t)(mi * 16 + lr) * 192 + ks * 32 + lg * 8);
      acc[mi] = __builtin_amdgcn_mfma_f32_16x16x32_bf16(a, b, acc[mi], 0, 0, 0);
    }
  }
  float bo = outb[o];
  int v = v0 + wv * 16 + lr;
  if (v < V_) {
#pragma unroll
    for (int mi = 0; mi < 4; ++mi)
#pragma unroll
      for (int r = 0; r < 4; ++r) {
        int q = mi * 16 + lg * 4 + r;
        op[(((size_t)n * C_ + o) * T_ + q) * V_ + v] = acc[mi][r] + bo;
      }
  }
}

// ---------------- BN partial stats: grid (4, C_), 2 n per block, float4 ----------------
__global__ void k_bnstats(const float* __restrict__ xp, float* __restrict__ part) {
  int qd = blockIdx.x, c = blockIdx.y;
  int tid = threadIdx.x;
  float s1 = 0.f, s2 = 0.f;
#pragma unroll
  for (int nn = 0; nn < 2; ++nn) {
    const f32x4* base = (const f32x4*)(xp + ((size_t)(qd * 2 + nn) * C_ + c) * TV_);
    for (int i = tid; i < 3264; i += 256) {
      f32x4 v = base[i];
      s1 += v.x + v.y + v.z + v.w;
      s2 += v.x * v.x + v.y * v.y + v.z * v.z + v.w * v.w;
    }
  }
  __shared__ float r1[256], r2[256];
  r1[tid] = s1; r2[tid] = s2;
  __syncthreads();
  for (int off = 128; off >= 1; off >>= 1) {
    if (tid < off) { r1[tid] += r1[tid + off]; r2[tid] += r2[tid + off]; }
    __syncthreads();
  }
  if (tid == 0) {
    part[(c * 4 + qd) * 2] = r1[0];
    part[(c * 4 + qd) * 2 + 1] = r2[0];
  }
}

// ---- fused bnfin + leaky(bn(op)+x1) + bf16 transpose -> xt (no fp32 xs3) ----
__global__ __launch_bounds__(256) void k_bnxt(const float* __restrict__ op,
                                              const float* __restrict__ x1,
                                              const float* __restrict__ part,
                                              const float* __restrict__ g,
                                              const float* __restrict__ beta,
                                              unsigned short* __restrict__ xt) {
  int lt = blockIdx.x, ct = blockIdx.y, n = blockIdx.z;
  int l0 = lt * 64, c0 = ct * 32;
  __shared__ float Ts[32][65];
  __shared__ float as_[32], bs_[32];
  int tid = threadIdx.x;
  if (tid < 32) {
    int c = c0 + tid;
    float s1 = 0.f, s2 = 0.f;
#pragma unroll
    for (int qd = 0; qd < 4; ++qd) {
      s1 += part[(c * 4 + qd) * 2];
      s2 += part[(c * 4 + qd) * 2 + 1];
    }
    const float cnt = (float)(N_ * TV_);
    float mu = s1 / cnt;
    float rstd = rsqrtf(s2 / cnt - mu * mu + 1e-5f);
    float a = rstd * g[c];
    as_[tid] = a;
    bs_[tid] = beta[c] - mu * a;
  }
  __syncthreads();
  int lc = tid & 63, cr = tid >> 6;
#pragma unroll
  for (int it = 0; it < 8; ++it) {
    int cl = cr + it * 4;
    size_t o = ((size_t)(n * C_ + c0 + cl)) * TV_ + l0 + lc;
    float vv = op[o] * as_[cl] + bs_[cl] + x1[o];
    Ts[cl][lc] = vv > 0.f ? vv : 0.1f * vv;
  }
  __syncthreads();
  int lrow = tid >> 2, qo = tid & 3;
  unsigned short buf[8];
#pragma unroll
  for (int j = 0; j < 8; ++j) buf[j] = bf16rnd(Ts[qo * 8 + j][lrow]);
  *(uint4*)(xt + ((size_t)n * TV_ + l0 + lrow) * 128 + c0 + qo * 8) = *(const uint4*)buf;
}

// ---- final: fused bnfin + leaky(bn(xp)+x1) -> out fp32 ----
__global__ void k_bnres2(const float* __restrict__ xp, const float* __restrict__ part,
                         const float* __restrict__ g, const float* __restrict__ beta,
                         const float* __restrict__ x1, float* __restrict__ out) {
  __shared__ float as_[128], bs_[128];
  int tid = threadIdx.x;
  if (tid < 128) {
    float s1 = 0.f, s2 = 0.f;
#pragma unroll
    for (int qd = 0; qd < 4; ++qd) {
      s1 += part[(tid * 4 + qd) * 2];
      s2 += part[(tid * 4 + qd) * 2 + 1];
    }
    const float cnt = (float)(N_ * TV_);
    float mu = s1 / cnt;
    float rstd = rsqrtf(s2 / cnt - mu * mu + 1e-5f);
    float a = rstd * g[tid];
    as_[tid] = a;
    bs_[tid] = beta[tid] - mu * a;
  }
  __syncthreads();
  const unsigned NI4 = (unsigned)(NCTV_ / 4);
  for (unsigned i4 = blockIdx.x * 256u + threadIdx.x; i4 < NI4;
       i4 += gridDim.x * 256u) {
    int c = (int)((i4 / 3264u) & 127u);
    float a = as_[c], b = bs_[c];
    f32x4 v = ((const f32x4*)xp)[i4];
    f32x4 r = ((const f32x4*)x1)[i4];
    f32x4 o;
#pragma unroll
    for (int j = 0; j < 4; ++j) {
      float t = v[j] * a + b + r[j];
      o[j] = t > 0.f ? t : 0.1f * t;
    }
    ((f32x4*)out)[i4] = o;
  }
}

extern "C" void kernel_launch(void* const* d_in, const int* in_sizes, int n_in,
                              void* d_out, int out_size, void* d_ws, size_t ws_size,
                              hipStream_t stream) {
  (void)in_sizes; (void)n_in; (void)out_size; (void)ws_size;
  const float* x        = (const float*)d_in[0];
  const float* trans_w  = (const float*)d_in[1];
  const float* trans_b  = (const float*)d_in[2];
  const float* convk_w  = (const float*)d_in[3];
  const float* convk_b  = (const float*)d_in[4];
  const float* qkv_w    = (const float*)d_in[5];
  const float* qkv_b    = (const float*)d_in[6];
  const float* alphas   = (const float*)d_in[7];
  const float* att1s    = (const float*)d_in[8];
  const float* out_w    = (const float*)d_in[9];
  const float* out_b    = (const float*)d_in[10];
  const float* out_g    = (const float*)d_in[11];
  const float* out_beta = (const float*)d_in[12];
  const float* ff_w     = (const float*)d_in[13];
  const float* ff_b     = (const float*)d_in[14];
  const float* ff_g     = (const float*)d_in[15];
  const float* ff_beta  = (const float*)d_in[16];

  float* ws = (float*)d_ws;
  size_t off = 0;
  float* x1   = ws + off; off += NCTV_;                    // 13.37M fl
  float* big  = ws + off; off += (size_t)N_ * O2_ * TV_;   // 20.05M fl (pdis -> qkv bf16 -> Y3 bf16 -> ff_pre)
  float* sbuf = ws + off; off += (size_t)N_ * CT_;
  int*   idx  = (int*)(ws + off); off += (size_t)N_ * V_ * 3 + 4;
  float* cm   = ws + off; off += (size_t)N_ * C_ * V_;
  float* w2   = ws + off; off += (size_t)N_ * V_ * 3 + 4;
  float* attp = ws + off; off += (size_t)16 * N_ * H_ * TT_;
  unsigned short* attT = (unsigned short*)(ws + off); off += (size_t)N_ * 64 * 192 / 2;
  float* part = ws + off; off += 1024;
  float* qpe  = ws + off; off += (size_t)O2_ * T_;
  // overlay region: zhi/zlo (consumed by k_dism) then reused as x1t
  const size_t ZEL = (size_t)N_ * 1024 * ZR_ * 8;  // shorts per array (13.63M)
  unsigned short* zhi = (unsigned short*)(ws + off);
  unsigned short* zlo = zhi + ZEL;
  unsigned short* x1t = zhi;  // reuse after dis path done
  off += ZEL;  // (2 arrays * ZEL shorts) / 2 shorts-per-float = ZEL floats

  float* dout = (float*)d_out;  // out_pre -> final

  k_qkvpe<<<48, 256, 0, stream>>>(qkv_w, qpe);
  k_scale<<<(N_ * CT_ * 64) / 256, 256, 0, stream>>>(x, sbuf);
  k_zprep<<<dim3(128, 4, N_), 256, 0, stream>>>(x, sbuf, zhi, zlo, cm);
  k_dism<<<dim3(3, DSPLIT_, N_), 256, 0, stream>>>(zhi, zlo, big);
  k_topk2<<<N_ * V_, 64, 0, stream>>>(big, idx);
  k_w2<<<N_ * V_, 64, 0, stream>>>(cm, idx, trans_w, trans_b, convk_w, w2);
  k_x1t<<<dim3(204, 4, N_), 256, 0, stream>>>(x, idx, w2, convk_b, x1, x1t);

  // qkv = W@x1 + qkv_b + qkvpe -> big (bf16)
  k_gmm<3><<<dim3(102, 2, N_), 256, 0, stream>>>(qkv_w, 128, 255, 0, x1t, qkv_b, qpe,
                                                 big, O2_, 1);
  k_att<<<dim3(16, H_, N_), 256, 0, stream>>>((const unsigned short*)big, attp);
  k_attfin<<<384, 256, 0, stream>>>(attp, alphas, att1s, attT);

  // Y3[n][h*128+o][t][v] = (W_h @ x1) bf16 -> big
  k_gmm<4><<<dim3(102, 3, N_), 256, 0, stream>>>(out_w, 384, 127, 128, x1t, nullptr,
                                                 nullptr, big, 384, 1);
  // out_pre = sum_ht attT * Y3 + out_b -> d_out
  k_comb<<<dim3(4, C_, N_), 256, 0, stream>>>((const unsigned short*)big, attT, out_b, dout);

  k_bnstats<<<dim3(4, C_), 256, 0, stream>>>(dout, part);
  // xs3t bf16 (transposed) directly; no fp32 xs3
  k_bnxt<<<dim3(204, 4, N_), 256, 0, stream>>>(dout, x1, part, out_g, out_beta, x1t);

  // ff_pre = ff_w @ xs3 + ff_b -> big (fp32)
  k_gmm<4><<<dim3(102, 1, N_), 256, 0, stream>>>(ff_w, 128, 255, 0, x1t, ff_b, nullptr,
                                                 big, C_, 0);
  k_bnstats<<<dim3(4, C_), 256, 0, stream>>>(big, part);
  k_bnres2<<<4096, 256, 0, stream>>>(big, part, ff_g, ff_beta, x1, dout);
}

// Round 7
// 382.605 us; speedup vs baseline: 6.1959x; 1.5603x over previous
//
#include <hip/hip_runtime.h>
#include <math.h>

#define N_ 8
#define C_ 128
#define T_ 64
#define V_ 204
#define H_ 3
#define QKD_ 32
#define O2_ 192            // 2*H*QKD
#define TV_ 13056          // T*V
#define CT_ 8192           // C*T
#define TT_ 4096           // T*T
#define VV_ 41616          // V*V
#define NCTV_ 13369344ull  // N*C*T*V
#define DSPLIT_ 16
#define ZR_ 208

typedef __attribute__((ext_vector_type(8))) short short8v;
typedef __attribute__((ext_vector_type(4))) float f32x4;

__device__ inline unsigned short bf16rnd(float f) {
  union { float f; unsigned u; } x; x.f = f;
  return (unsigned short)((x.u + 0x7FFFu + ((x.u >> 16) & 1u)) >> 16);
}
__device__ inline float bf2f(unsigned short u) {
  union { unsigned u; float f; } x; x.u = ((unsigned)u) << 16;
  return x.f;
}

// ---- weights -> bf16 rows [m][128]: qkv_wb(192) | w3b(384: [h][o]) | ff_wb(128) ----
__global__ void k_wprep(const float* __restrict__ qw, const float* __restrict__ ow,
                        const float* __restrict__ fw, unsigned short* __restrict__ wb) {
  int g = blockIdx.x * 256 + threadIdx.x;  // 704*16 = 11264 chunks of 8
  if (g >= 704 * 16) return;
  int row = g >> 4, ch = g & 15;
  const float* src;
  if (row < 192) src = qw + row * 128;
  else if (row < 576) { int r = row - 192; src = ow + (r & 127) * 384 + (r >> 7) * 128; }
  else src = fw + (row - 576) * 128;
  f32x4 a = *(const f32x4*)(src + ch * 8);
  f32x4 b = *(const f32x4*)(src + ch * 8 + 4);
  unsigned short buf[8];
  buf[0] = bf16rnd(a.x); buf[1] = bf16rnd(a.y); buf[2] = bf16rnd(a.z); buf[3] = bf16rnd(a.w);
  buf[4] = bf16rnd(b.x); buf[5] = bf16rnd(b.y); buf[6] = bf16rnd(b.z); buf[7] = bf16rnd(b.w);
  *(uint4*)(wb + (size_t)row * 128 + ch * 8) = *(const uint4*)buf;
}

// ---- qpe[m][t] = qkv_b[m] + sum_c qkv_w[m][c]*pe[c][t] ----
__global__ void k_qkvpe(const float* __restrict__ qw, const float* __restrict__ qb,
                        float* __restrict__ qpe) {
  __shared__ float pes[C_ * T_];
  int tid = threadIdx.x;
  for (int i = tid; i < C_ * T_; i += 256) {
    int t = i & 63, c = i >> 6;
    int j = c >> 1;
    float dv = expf((2.0f * j) * (-logf(10000.0f) / (float)C_));
    float ang = (float)t * dv;
    pes[i] = (c & 1) ? cosf(ang) : sinf(ang);
  }
  __syncthreads();
  int g = blockIdx.x * 256 + tid;
  int t = g & 63, m = g >> 6;
  float a = 0.f;
  for (int c = 0; c < C_; ++c) a += qw[m * C_ + c] * pes[c * T_ + t];
  qpe[g] = a + qb[m];
}

// ---------------- s[n,c,t] = 1/max(||x||,1e-12)^2 ----------------
__global__ void k_scale(const float* __restrict__ x, float* __restrict__ s) {
  int gid = blockIdx.x * blockDim.x + threadIdx.x;
  int w = gid >> 6, lane = gid & 63;
  if (w >= N_ * CT_) return;
  const f32x4* row = (const f32x4*)(x + (size_t)w * V_);
  float a = 0.f;
  for (int v4 = lane; v4 < 51; v4 += 64) {
    f32x4 t = row[v4];
    a += t.x * t.x + t.y * t.y + t.z * t.z + t.w * t.w;
  }
#pragma unroll
  for (int off = 32; off >= 1; off >>= 1) a += __shfl_down(a, off, 64);
  if (lane == 0) {
    float d = fmaxf(sqrtf(a), 1e-12f);
    s[w] = 1.0f / (d * d);
  }
}

// ---- Z-prep: fragment-major bf16 hi/lo + colmean ----
__global__ __launch_bounds__(256) void k_zprep(const float* __restrict__ x,
                                               const float* __restrict__ s,
                                               unsigned short* __restrict__ zhi,
                                               unsigned short* __restrict__ zlo,
                                               float* __restrict__ cm) {
  int kt = blockIdx.x, ut = blockIdx.y, n = blockIdx.z;
  int k0 = kt * 64, u0 = ut * 64;
  __shared__ float Ts[64][65];
  __shared__ float sq[64];
  int tid = threadIdx.x;
  int uu = tid & 63, kk = tid >> 6;
  int u = u0 + uu;
  bool uok = u < V_;
  const float* xb = x + (size_t)n * CT_ * V_;
#pragma unroll
  for (int it = 0; it < 16; ++it) {
    int kr = kk + it * 4;
    Ts[kr][uu] = uok ? xb[(size_t)(k0 + kr) * V_ + u] : 0.f;
  }
  if (tid < 64) sq[tid] = sqrtf(s[(size_t)n * CT_ + k0 + tid]);
  __syncthreads();
  if (tid < 64 && uok) {
    float a = 0.f;
    for (int t = 0; t < 64; ++t) a += Ts[t][tid];
    cm[((size_t)n * C_ + kt) * V_ + u] = a * (1.0f / 64.0f);
  }
#pragma unroll
  for (int it = 0; it < 4; ++it) {
    int sl = tid + it * 256;
    int u_l = sl & 63, oct = (sl >> 6) & 7, half = sl >> 9;
    int ug = u0 + u_l;
    if (ug >= ZR_) continue;
    unsigned short buf[8];
    if (ug < V_) {
#pragma unroll
      for (int j = 0; j < 8; ++j) {
        float z = Ts[oct * 8 + j][u_l] * sq[oct * 8 + j];
        unsigned short h = bf16rnd(z);
        buf[j] = half ? bf16rnd(z - bf2f(h)) : h;
      }
    } else {
#pragma unroll
      for (int j = 0; j < 8; ++j) buf[j] = 0;
    }
    unsigned short* dst = (half ? zlo : zhi) +
                          (((size_t)n * 1024 + kt * 8 + oct) * ZR_ + ug) * 8;
    *(uint4*)dst = *(const uint4*)buf;
  }
}

// ---- dis via split-bf16 MFMA ----
__global__ __launch_bounds__(256) void k_dism(const unsigned short* __restrict__ zhi,
                                              const unsigned short* __restrict__ zlo,
                                              float* __restrict__ pdis) {
  int q = blockIdx.x, sp = blockIdx.y, n = blockIdx.z;
  int bu = (q == 2) ? 1 : 0, bv = (q == 0) ? 0 : 1;
  int u0 = bu * 128, v0 = bv * 128;
  bool dg = (bu == bv);
  __shared__ unsigned short As[8 * 128 * 8];
  __shared__ unsigned short Bs[8 * 128 * 8];
  int tid = threadIdx.x, lane = tid & 63, wid = tid >> 6;
  int lr = lane & 15, lg = lane >> 4;
  f32x4 acc[2][8];
#pragma unroll
  for (int mi = 0; mi < 2; ++mi)
#pragma unroll
    for (int li = 0; li < 8; ++li) acc[mi][li] = (f32x4){0.f, 0.f, 0.f, 0.f};
  int kend = sp * 512 + 512;
  for (int kk = sp * 512; kk < kend; kk += 32) {
    int koct = kk >> 3;
    __syncthreads();
#pragma unroll
    for (int it = 0; it < 4; ++it) {
      int sl = tid + it * 256;
      int row = sl & 127, hs = sl >> 7;
      int slot = hs & 3, half = hs >> 2;
      const unsigned short* src = half ? zlo : zhi;
      size_t ob = ((size_t)n * 1024 + koct + slot) * ZR_;
      int ra = u0 + row; ra = ra > 207 ? 207 : ra;
      *(uint4*)&As[(hs * 128 + row) * 8] = *(const uint4*)(src + (ob + ra) * 8);
      if (!dg) {
        int rb = v0 + row; rb = rb > 207 ? 207 : rb;
        *(uint4*)&Bs[(hs * 128 + row) * 8] = *(const uint4*)(src + (ob + rb) * 8);
      }
    }
    __syncthreads();
    const unsigned short* Bp = dg ? As : Bs;
    short8v ah[2], al[2];
#pragma unroll
    for (int mi = 0; mi < 2; ++mi) {
      int r = wid * 32 + mi * 16 + lr;
      ah[mi] = *(const short8v*)&As[(lg * 128 + r) * 8];
      al[mi] = *(const short8v*)&As[((4 + lg) * 128 + r) * 8];
    }
#pragma unroll
    for (int li = 0; li < 8; ++li) {
      int rv = li * 16 + lr;
      short8v bh = *(const short8v*)&Bp[(lg * 128 + rv) * 8];
      short8v bl = *(const short8v*)&Bp[((4 + lg) * 128 + rv) * 8];
#pragma unroll
      for (int mi = 0; mi < 2; ++mi) {
        acc[mi][li] = __builtin_amdgcn_mfma_f32_16x16x32_bf16(ah[mi], bh, acc[mi][li], 0, 0, 0);
        acc[mi][li] = __builtin_amdgcn_mfma_f32_16x16x32_bf16(ah[mi], bl, acc[mi][li], 0, 0, 0);
        acc[mi][li] = __builtin_amdgcn_mfma_f32_16x16x32_bf16(al[mi], bh, acc[mi][li], 0, 0, 0);
      }
    }
  }
  float* pb = pdis + ((size_t)sp * N_ + n) * VV_;
#pragma unroll
  for (int mi = 0; mi < 2; ++mi) {
#pragma unroll
    for (int li = 0; li < 8; ++li) {
      int v = v0 + li * 16 + lr;
      if (v >= V_) continue;
#pragma unroll
      for (int rr = 0; rr < 4; ++rr) {
        int u = u0 + wid * 32 + mi * 16 + lg * 4 + rr;
        if (u >= V_) continue;
        float val = acc[mi][li][rr];
        pb[(size_t)u * V_ + v] = val;
        if (!dg) pb[(size_t)v * V_ + u] = val;
      }
    }
  }
}

// ---- fused partial-sum + wave-parallel top-3 ----
__global__ void k_topk2(const float* __restrict__ pdis, int* __restrict__ idx) {
  int r = blockIdx.x;
  int n = r / V_, u = r - n * V_;
  int lane = threadIdx.x;
  float m0 = -INFINITY, m1 = -INFINITY, m2 = -INFINITY;
  int i0 = 0x7fffffff, i1 = 0x7fffffff, i2 = 0x7fffffff;
#pragma unroll
  for (int g = 0; g < 4; ++g) {
    int v = g * 64 + lane;
    if (v >= V_) break;
    float a = 0.f;
#pragma unroll
    for (int sp = 0; sp < DSPLIT_; ++sp)
      a += pdis[((size_t)sp * N_ + n) * VV_ + (size_t)u * V_ + v];
    if (a > m0 || (a == m0 && v < i0)) {
      m2 = m1; i2 = i1; m1 = m0; i1 = i0; m0 = a; i0 = v;
    } else if (a > m1 || (a == m1 && v < i1)) {
      m2 = m1; i2 = i1; m1 = a; i1 = v;
    } else if (a > m2 || (a == m2 && v < i2)) {
      m2 = a; i2 = v;
    }
  }
#pragma unroll
  for (int msk = 1; msk < 64; msk <<= 1) {
    float o0 = __shfl_xor(m0, msk, 64), o1 = __shfl_xor(m1, msk, 64),
          o2 = __shfl_xor(m2, msk, 64);
    int p0 = __shfl_xor(i0, msk, 64), p1 = __shfl_xor(i1, msk, 64),
        p2 = __shfl_xor(i2, msk, 64);
    float ov[3] = {o0, o1, o2};
    int op[3] = {p0, p1, p2};
#pragma unroll
    for (int e = 0; e < 3; ++e) {
      float a = ov[e]; int v = op[e];
      if (a > m0 || (a == m0 && v < i0)) {
        m2 = m1; i2 = i1; m1 = m0; i1 = i0; m0 = a; i0 = v;
      } else if (a > m1 || (a == m1 && v < i1)) {
        m2 = m1; i2 = i1; m1 = a; i1 = v;
      } else if (a > m2 || (a == m2 && v < i2)) {
        m2 = a; i2 = v;
      }
    }
  }
  if (lane == 0) {
    idx[r * 3 + 0] = i0; idx[r * 3 + 1] = i1; idx[r * 3 + 2] = i2;
  }
}

// ---------------- w2 ----------------
__global__ void k_w2(const float* __restrict__ cm, const int* __restrict__ idx,
                     const float* __restrict__ tw, const float* __restrict__ tb,
                     const float* __restrict__ ckw, float* __restrict__ w2) {
  int r = blockIdx.x;
  int n = r / V_;
  int lane = threadIdx.x;
  __shared__ float mv[3][C_];
  const int* ib = idx + r * 3;
  int j0 = ib[0], j1 = ib[1], j2 = ib[2];
  const float* cmn = cm + (size_t)n * C_ * V_;
  for (int c = lane; c < C_; c += 64) {
    mv[0][c] = cmn[c * V_ + j0];
    mv[1][c] = cmn[c * V_ + j1];
    mv[2][c] = cmn[c * V_ + j2];
  }
  __syncthreads();
  float p[9];
#pragma unroll
  for (int gp = 0; gp < 9; ++gp) p[gp] = 0.f;
  for (int c = lane; c < C_; c += 64) {
#pragma unroll
    for (int g = 0; g < 3; ++g) {
      float m = mv[g][c];
#pragma unroll
      for (int pp = 0; pp < 3; ++pp) p[g * 3 + pp] += m * tw[(g * 3 + pp) * C_ + c];
    }
  }
#pragma unroll
  for (int off = 32; off >= 1; off >>= 1) {
#pragma unroll
    for (int gp = 0; gp < 9; ++gp) p[gp] += __shfl_down(p[gp], off, 64);
  }
  if (lane == 0) {
    float c0 = ckw[0], c1 = ckw[1], c2 = ckw[2];
#pragma unroll
    for (int g = 0; g < 3; ++g) {
      float m0 = p[g * 3 + 0] + tb[g * 3 + 0];
      float m1 = p[g * 3 + 1] + tb[g * 3 + 1];
      float m2 = p[g * 3 + 2] + tb[g * 3 + 2];
      float mx = fmaxf(m0, fmaxf(m1, m2));
      float e0 = expf(m0 - mx), e1 = expf(m1 - mx), e2 = expf(m2 - mx);
      float inv = 1.0f / (e0 + e1 + e2);
      w2[r * 3 + g] = (e0 * c0 + e1 * c1 + e2 * c2) * inv;
    }
  }
}

// ---- x1 producer -> [n][v][t][c] layouts: x1p fp32 + x1pb bf16 ----
__global__ __launch_bounds__(256) void k_x1p(const float* __restrict__ x,
                                             const int* __restrict__ idx,
                                             const float* __restrict__ w2,
                                             const float* __restrict__ ckb,
                                             float* __restrict__ x1p,
                                             unsigned short* __restrict__ x1pb) {
  int t = blockIdx.x, ct = blockIdx.y, n = blockIdx.z;
  int c0 = ct * 32;
  __shared__ float Ts[32][209];
  __shared__ int iw[V_ * 3];
  __shared__ float ww[V_ * 3];
  int tid = threadIdx.x;
  const float* xb = x + ((size_t)n * C_ + c0) * TV_ + t * V_;
  for (int i = tid; i < 32 * V_; i += 256) {
    int c = i / V_, v = i - c * V_;
    Ts[c][v] = xb[(size_t)c * TV_ + v];
  }
  for (int i = tid; i < V_ * 3; i += 256) {
    iw[i] = idx[(size_t)n * V_ * 3 + i];
    ww[i] = w2[(size_t)n * V_ * 3 + i];
  }
  __syncthreads();
  float cb = ckb[0];
  for (int i = tid; i < 32 * V_; i += 256) {
    int v = i >> 5, cl = i & 31;
    int b = v * 3;
    float pooled = Ts[cl][iw[b]] * ww[b] + Ts[cl][iw[b + 1]] * ww[b + 1] +
                   Ts[cl][iw[b + 2]] * ww[b + 2] + cb;
    float val = fmaxf(pooled + Ts[cl][v], 0.f);
    size_t o = ((size_t)(n * V_ + v) * T_ + t) * C_ + c0 + cl;
    x1p[o] = val;
    x1pb[o] = bf16rnd(val);
  }
}

// ---- MFMA GEMM: Y = W@X (X=[l'][c] bf16), M-loop in block, LDS-staged ----
template <int MCH, int OBF>
__global__ __launch_bounds__(256) void k_gmm2(const unsigned short* __restrict__ Wb,
                                              const unsigned short* __restrict__ Xp,
                                              const float* __restrict__ addv,
                                              void* __restrict__ Yv) {
  int l0 = blockIdx.x * 128, n = blockIdx.z;
  __shared__ unsigned short Xs[128 * 136];
  __shared__ unsigned short Ys[64 * 128];
  int tid = threadIdx.x, lane = tid & 63, wid = tid >> 6;
  int wm = wid >> 1, wl = wid & 1;
  int lr = lane & 15, lg = lane >> 4;
  const unsigned short* xb = Xp + ((size_t)n * TV_ + l0) * 128;
#pragma unroll
  for (int it = 0; it < 8; ++it) {
    int g = tid + it * 256;
    int row = g >> 4, ch = g & 15;
    *(uint4*)&Xs[row * 136 + ch * 8] = *(const uint4*)(xb + (size_t)row * 128 + ch * 8);
  }
  __syncthreads();
  for (int mc = 0; mc < MCH; ++mc) {
    short8v a[2][4];
#pragma unroll
    for (int mi = 0; mi < 2; ++mi) {
      int m = mc * 64 + wm * 32 + mi * 16 + lr;
#pragma unroll
      for (int ks = 0; ks < 4; ++ks)
        a[mi][ks] = *(const short8v*)(Wb + (size_t)m * 128 + ks * 32 + lg * 8);
    }
    f32x4 acc[2][4];
#pragma unroll
    for (int mi = 0; mi < 2; ++mi)
#pragma unroll
      for (int li = 0; li < 4; ++li) acc[mi][li] = (f32x4){0.f, 0.f, 0.f, 0.f};
#pragma unroll
    for (int ks = 0; ks < 4; ++ks) {
#pragma unroll
      for (int li = 0; li < 4; ++li) {
        short8v b = *(const short8v*)&Xs[(wl * 64 + li * 16 + lr) * 136 + ks * 32 + lg * 8];
#pragma unroll
        for (int mi = 0; mi < 2; ++mi)
          acc[mi][li] = __builtin_amdgcn_mfma_f32_16x16x32_bf16(a[mi][ks], b, acc[mi][li], 0, 0, 0);
      }
    }
    if (OBF) {
      __syncthreads();
#pragma unroll
      for (int mi = 0; mi < 2; ++mi)
#pragma unroll
        for (int li = 0; li < 4; ++li) {
          int lloc = wl * 64 + li * 16 + lr;
          int tt = (l0 + lloc) & 63;
#pragma unroll
          for (int r = 0; r < 4; ++r) {
            int mloc = wm * 32 + mi * 16 + lg * 4 + r;
            float val = acc[mi][li][r] + addv[(mc * 64 + mloc) * 64 + tt];
            Ys[mloc * 128 + lloc] = bf16rnd(val);
          }
        }
      __syncthreads();
      unsigned short* Yh = (unsigned short*)Yv;
#pragma unroll
      for (int it = 0; it < 4; ++it) {
        int g = tid + it * 256;
        int row = g >> 4, ch = g & 15;
        *(uint4*)(Yh + ((size_t)n * O2_ + mc * 64 + row) * TV_ + l0 + ch * 8) =
            *(const uint4*)&Ys[row * 128 + ch * 8];
      }
    } else {
      float* Yf = (float*)Yv;
#pragma unroll
      for (int mi = 0; mi < 2; ++mi)
#pragma unroll
        for (int li = 0; li < 4; ++li) {
          int lp = l0 + wl * 64 + li * 16 + lr;
          int m = mc * 64 + wm * 32 + mi * 16 + lg * 4;
          f32x4 o;
#pragma unroll
          for (int r = 0; r < 4; ++r) o[r] = acc[mi][li][r] + addv[m + r];
          *(f32x4*)(Yf + ((size_t)n * TV_ + lp) * 128 + m) = o;
        }
    }
  }
}

// ---- attention partials (qkv bf16 [m][v][t]): attp[cp][n][h][t][q] ----
__global__ __launch_bounds__(256) void k_att(const unsigned short* __restrict__ qkv,
                                             float* __restrict__ attp) {
  int cp = blockIdx.x, h = blockIdx.y, n = blockIdx.z;
  __shared__ float Qs[102][68], Ks[102][68];
  int tid = threadIdx.x;
  int ty = tid >> 4, tx = tid & 15;
  float acc[4][4] = {};
  for (int cc = 0; cc < 2; ++cc) {
    int c = cp * 2 + cc;
    const unsigned short* qb = qkv + ((size_t)n * O2_ + h * QKD_ + c) * TV_;
    const unsigned short* kb = qkv + ((size_t)n * O2_ + H_ * QKD_ + h * QKD_ + c) * TV_;
    for (int vh = 0; vh < 2; ++vh) {
      for (int g = tid; g < 816; g += 256) {
        int v = g >> 3, t0 = (g & 7) * 8;
        uint4 qv = *(const uint4*)(qb + vh * 6528 + g * 8);
        uint4 kv = *(const uint4*)(kb + vh * 6528 + g * 8);
        const unsigned short* qs = (const unsigned short*)&qv;
        const unsigned short* ks2 = (const unsigned short*)&kv;
#pragma unroll
        for (int j = 0; j < 8; ++j) {
          Qs[v][t0 + j] = bf2f(qs[j]);
          Ks[v][t0 + j] = bf2f(ks2[j]);
        }
      }
      __syncthreads();
      for (int vv = 0; vv < 102; ++vv) {
        f32x4 qa = *(const f32x4*)&Qs[vv][ty * 4];
        f32x4 ka = *(const f32x4*)&Ks[vv][tx * 4];
#pragma unroll
        for (int i = 0; i < 4; ++i)
#pragma unroll
          for (int j = 0; j < 4; ++j) acc[i][j] += qa[i] * ka[j];
      }
      __syncthreads();
    }
  }
  float* ar = attp + (((size_t)cp * N_ + n) * H_ + h) * TT_;
#pragma unroll
  for (int i = 0; i < 4; ++i)
#pragma unroll
    for (int j = 0; j < 4; ++j)
      ar[(ty * 4 + i) * T_ + tx * 4 + j] = acc[i][j];
}

// ---- attT[n][q][h*64+t] = bf16(tanh(sum_cp attp /6528)*alpha + att1s) ----
__global__ void k_attfin(const float* __restrict__ attp, const float* __restrict__ alphas,
                         const float* __restrict__ att1s, unsigned short* __restrict__ attT) {
  int i = blockIdx.x * blockDim.x + threadIdx.x;
  if (i >= N_ * H_ * TT_) return;
  int tt = i % TT_;
  int h = (i / TT_) % H_;
  int n = i / (H_ * TT_);
  float raw = 0.f;
#pragma unroll
  for (int cp = 0; cp < 16; ++cp)
    raw += attp[(((size_t)cp * N_ + n) * H_ + h) * TT_ + tt];
  int t = tt >> 6, q = tt & 63;
  float v = tanhf(raw * (1.0f / 6528.0f)) * alphas[h] + att1s[h * TT_ + tt];
  attT[(size_t)(n * 64 + q) * 192 + h * 64 + t] = bf16rnd(v);
}

// ---- fused Y3+comb: per (v,n): O[q][o] = sum_h attn_h @ (W3h @ x1v), out [l'][c] ----
__global__ __launch_bounds__(256) void k_fcomb(const unsigned short* __restrict__ x1pb,
                                               const unsigned short* __restrict__ w3b,
                                               const unsigned short* __restrict__ attT,
                                               const float* __restrict__ outb,
                                               float* __restrict__ op) {
  int v = blockIdx.x, n = blockIdx.z;
  __shared__ unsigned short Xv[64 * 136];  // [t][c] padded
  __shared__ unsigned short Yv[128 * 72];  // [o][t] padded
  int tid = threadIdx.x, lane = tid & 63, wid = tid >> 6;
  int lr = lane & 15, lg = lane >> 4;
  const unsigned short* xb = x1pb + ((size_t)(n * V_ + v) * T_) * 128;
#pragma unroll
  for (int it = 0; it < 4; ++it) {
    int g = tid + it * 256;
    int row = g >> 4, ch = g & 15;
    *(uint4*)&Xv[row * 136 + ch * 8] = *(const uint4*)(xb + (size_t)row * 128 + ch * 8);
  }
  __syncthreads();  // FIX (R5 bug): Xv staging must complete before h=0 MFMA reads it
  f32x4 acc2[4][2];
#pragma unroll
  for (int mq = 0; mq < 4; ++mq)
#pragma unroll
    for (int oi = 0; oi < 2; ++oi) acc2[mq][oi] = (f32x4){0.f, 0.f, 0.f, 0.f};
  const unsigned short* ab = attT + (size_t)n * 64 * 192;
  for (int h = 0; h < H_; ++h) {
    short8v a1[2][4];
#pragma unroll
    for (int mi = 0; mi < 2; ++mi) {
      int m = wid * 32 + mi * 16 + lr;
#pragma unroll
      for (int ks = 0; ks < 4; ++ks)
        a1[mi][ks] = *(const short8v*)(w3b + ((size_t)(h * 128 + m)) * 128 + ks * 32 + lg * 8);
    }
    f32x4 acc1[2][4];
#pragma unroll
    for (int mi = 0; mi < 2; ++mi)
#pragma unroll
      for (int li = 0; li < 4; ++li) acc1[mi][li] = (f32x4){0.f, 0.f, 0.f, 0.f};
#pragma unroll
    for (int ks = 0; ks < 4; ++ks) {
#pragma unroll
      for (int li = 0; li < 4; ++li) {
        short8v b = *(const short8v*)&Xv[(li * 16 + lr) * 136 + ks * 32 + lg * 8];
#pragma unroll
        for (int mi = 0; mi < 2; ++mi)
          acc1[mi][li] = __builtin_amdgcn_mfma_f32_16x16x32_bf16(a1[mi][ks], b, acc1[mi][li], 0, 0, 0);
      }
    }
    __syncthreads();  // prior acc2 reads of Yv done before overwrite
#pragma unroll
    for (int mi = 0; mi < 2; ++mi)
#pragma unroll
      for (int li = 0; li < 4; ++li) {
        int t = li * 16 + lr;
#pragma unroll
        for (int r = 0; r < 4; ++r) {
          int o = wid * 32 + mi * 16 + lg * 4 + r;
          Yv[o * 72 + t] = bf16rnd(acc1[mi][li][r]);
        }
      }
    __syncthreads();
#pragma unroll
    for (int ks2 = 0; ks2 < 2; ++ks2) {
      short8v bY[2];
#pragma unroll
      for (int oi = 0; oi < 2; ++oi)
        bY[oi] = *(const short8v*)&Yv[(wid * 32 + oi * 16 + lr) * 72 + ks2 * 32 + lg * 8];
#pragma unroll
      for (int mq = 0; mq < 4; ++mq) {
        short8v a2 = *(const short8v*)(ab + (size_t)(mq * 16 + lr) * 192 + h * 64 + ks2 * 32 + lg * 8);
#pragma unroll
        for (int oi = 0; oi < 2; ++oi)
          acc2[mq][oi] = __builtin_amdgcn_mfma_f32_16x16x32_bf16(a2, bY[oi], acc2[mq][oi], 0, 0, 0);
      }
    }
  }
#pragma unroll
  for (int mq = 0; mq < 4; ++mq)
#pragma unroll
    for (int oi = 0; oi < 2; ++oi) {
      int o = wid * 32 + oi * 16 + lr;
      float bo = outb[o];
#pragma unroll
      for (int r = 0; r < 4; ++r) {
        int q = mq * 16 + lg * 4 + r;
        op[((size_t)(n * V_ + v) * T_ + q) * 128 + o] = acc2[mq][oi][r] + bo;
      }
    }
}

// ---- BN partial stats over [l'][c] rows ----
__global__ void k_bnstats_p(const float* __restrict__ xp, float* __restrict__ part) {
  int blk = blockIdx.x;  // 204 blocks x 512 rows
  int tid = threadIdx.x;
  int c4 = tid & 31, rg = tid >> 5;
  const f32x4* x4 = (const f32x4*)xp;
  size_t base = (size_t)blk * 512;
  f32x4 s1 = {0.f, 0.f, 0.f, 0.f}, s2 = {0.f, 0.f, 0.f, 0.f};
  for (int r = rg; r < 512; r += 8) {
    f32x4 val = x4[(base + r) * 32 + c4];
#pragma unroll
    for (int j = 0; j < 4; ++j) { s1[j] += val[j]; s2[j] += val[j] * val[j]; }
  }
  __shared__ f32x4 red1[8][32], red2[8][32];
  red1[rg][c4] = s1; red2[rg][c4] = s2;
  __syncthreads();
  if (tid < 32) {
    f32x4 a1 = red1[0][tid], a2 = red2[0][tid];
#pragma unroll
    for (int g = 1; g < 8; ++g) {
#pragma unroll
      for (int j = 0; j < 4; ++j) { a1[j] += red1[g][tid][j]; a2[j] += red2[g][tid][j]; }
    }
    *(f32x4*)(part + blk * 256 + tid * 4) = a1;
    *(f32x4*)(part + blk * 256 + 128 + tid * 4) = a2;
  }
}

// ---- fold partials -> ab[c]=a, ab[128+c]=b ----
__global__ void k_bnab(const float* __restrict__ part, const float* __restrict__ g,
                       const float* __restrict__ beta, float* __restrict__ ab) {
  int c = threadIdx.x;
  float s1 = 0.f, s2 = 0.f;
  for (int b = 0; b < 204; ++b) {
    s1 += part[b * 256 + c];
    s2 += part[b * 256 + 128 + c];
  }
  const float cnt = (float)(N_ * TV_);
  float mu = s1 / cnt;
  float rstd = rsqrtf(s2 / cnt - mu * mu + 1e-5f);
  float a = rstd * g[c];
  ab[c] = a;
  ab[128 + c] = beta[c] - mu * a;
}

// ---- xs3pb = bf16(leaky(bn(op)+x1p)), elementwise [l'][c] ----
__global__ void k_bnxt(const float* __restrict__ op, const float* __restrict__ x1p,
                       const float* __restrict__ ab, unsigned short* __restrict__ xt) {
  __shared__ float sa[128], sb[128];
  int tid = threadIdx.x;
  if (tid < 128) { sa[tid] = ab[tid]; sb[tid] = ab[128 + tid]; }
  __syncthreads();
  const unsigned NU = (unsigned)(NCTV_ / 8);
  const f32x4* o4 = (const f32x4*)op;
  const f32x4* r4 = (const f32x4*)x1p;
  for (unsigned u = blockIdx.x * 256u + tid; u < NU; u += gridDim.x * 256u) {
    unsigned row = u >> 4, ch = u & 15;
    unsigned bi = row * 32 + ch * 2;
    f32x4 v0 = o4[bi], v1 = o4[bi + 1];
    f32x4 q0 = r4[bi], q1 = r4[bi + 1];
    int c8 = ch * 8;
    unsigned short buf[8];
#pragma unroll
    for (int j = 0; j < 4; ++j) {
      float t0 = v0[j] * sa[c8 + j] + sb[c8 + j] + q0[j];
      float t1 = v1[j] * sa[c8 + 4 + j] + sb[c8 + 4 + j] + q1[j];
      buf[j] = bf16rnd(t0 > 0.f ? t0 : 0.1f * t0);
      buf[4 + j] = bf16rnd(t1 > 0.f ? t1 : 0.1f * t1);
    }
    *(uint4*)(xt + (size_t)u * 8) = *(const uint4*)buf;
  }
}

// ---- final: leaky(bn(ff)+x1p), transpose [v][t][c] -> d_out [c][t][v] ----
__global__ __launch_bounds__(256) void k_bnfinal(const float* __restrict__ ff,
                                                 const float* __restrict__ x1p,
                                                 const float* __restrict__ ab,
                                                 float* __restrict__ dout) {
  int ct = blockIdx.x, t = blockIdx.y, n = blockIdx.z;
  int c0 = ct * 32;
  __shared__ float Tf[V_][33];
  __shared__ float sa[32], sb[32];
  int tid = threadIdx.x;
  if (tid < 32) { sa[tid] = ab[c0 + tid]; sb[tid] = ab[128 + c0 + tid]; }
  __syncthreads();
  for (int i = tid; i < V_ * 32; i += 256) {
    int v = i >> 5, cl = i & 31;
    size_t a = ((size_t)(n * V_ + v) * T_ + t) * 128 + c0 + cl;
    float val = ff[a] * sa[cl] + sb[cl] + x1p[a];
    Tf[v][cl] = val > 0.f ? val : 0.1f * val;
  }
  __syncthreads();
  for (int i = tid; i < 32 * V_; i += 256) {
    int cl = i / V_, v = i - cl * V_;
    dout[((size_t)(n * C_ + c0 + cl) * T_ + t) * V_ + v] = Tf[v][cl];
  }
}

extern "C" void kernel_launch(void* const* d_in, const int* in_sizes, int n_in,
                              void* d_out, int out_size, void* d_ws, size_t ws_size,
                              hipStream_t stream) {
  (void)in_sizes; (void)n_in; (void)out_size; (void)ws_size;
  const float* x        = (const float*)d_in[0];
  const float* trans_w  = (const float*)d_in[1];
  const float* trans_b  = (const float*)d_in[2];
  const float* convk_w  = (const float*)d_in[3];
  const float* convk_b  = (const float*)d_in[4];
  const float* qkv_w    = (const float*)d_in[5];
  const float* qkv_b    = (const float*)d_in[6];
  const float* alphas   = (const float*)d_in[7];
  const float* att1s    = (const float*)d_in[8];
  const float* out_w    = (const float*)d_in[9];
  const float* out_b    = (const float*)d_in[10];
  const float* out_g    = (const float*)d_in[11];
  const float* out_beta = (const float*)d_in[12];
  const float* ff_w     = (const float*)d_in[13];
  const float* ff_b     = (const float*)d_in[14];
  const float* ff_g     = (const float*)d_in[15];
  const float* ff_beta  = (const float*)d_in[16];

  float* ws = (float*)d_ws;
  size_t off = 0;
  float* x1p  = ws + off; off += NCTV_;                      // fp32 [v][t][c]
  float* big  = ws + off; off += (size_t)N_ * O2_ * TV_ / 2; // pdis fp32 | qkv bf16 [m][v][t]
  float* pre  = ws + off; off += NCTV_;                      // out_pre -> ff_pre fp32 [v][t][c]
  float* sbuf = ws + off; off += (size_t)N_ * CT_;
  int*   idx  = (int*)(ws + off); off += (size_t)N_ * V_ * 3 + 4;
  float* cm   = ws + off; off += (size_t)N_ * C_ * V_;
  float* w2   = ws + off; off += (size_t)N_ * V_ * 3 + 4;
  float* attp = ws + off; off += (size_t)16 * N_ * H_ * TT_;
  unsigned short* attT = (unsigned short*)(ws + off); off += (size_t)N_ * 64 * 192 / 2;
  float* part = ws + off; off += 204 * 256;
  float* ab   = ws + off; off += 512;
  float* qpe  = ws + off; off += (size_t)O2_ * T_;
  unsigned short* wb = (unsigned short*)(ws + off); off += 704 * 128 / 2;
  const size_t ZEL = (size_t)N_ * 1024 * ZR_ * 8;  // shorts per z array
  unsigned short* zhi = (unsigned short*)(ws + off);  // overlay: x1pb after dis
  unsigned short* zlo = zhi + ZEL;                    // overlay: xs3pb after dis
  off += ZEL;
  unsigned short* x1pb  = zhi;
  unsigned short* xs3pb = zlo;
  unsigned short* qkvb  = (unsigned short*)big;
  float* dout = (float*)d_out;

  k_wprep<<<44, 256, 0, stream>>>(qkv_w, out_w, ff_w, wb);
  k_qkvpe<<<48, 256, 0, stream>>>(qkv_w, qkv_b, qpe);
  k_scale<<<(N_ * CT_ * 64) / 256, 256, 0, stream>>>(x, sbuf);
  k_zprep<<<dim3(128, 4, N_), 256, 0, stream>>>(x, sbuf, zhi, zlo, cm);
  k_dism<<<dim3(3, DSPLIT_, N_), 256, 0, stream>>>(zhi, zlo, big);
  k_topk2<<<N_ * V_, 64, 0, stream>>>(big, idx);
  k_w2<<<N_ * V_, 64, 0, stream>>>(cm, idx, trans_w, trans_b, convk_w, w2);
  k_x1p<<<dim3(64, 4, N_), 256, 0, stream>>>(x, idx, w2, convk_b, x1p, x1pb);

  // qkv = Wq@x1 + qkv_b + pe-bias -> qkvb bf16 [m][v][t]
  k_gmm2<3, 1><<<dim3(102, 1, N_), 256, 0, stream>>>(wb, x1pb, qpe, qkvb);
  k_att<<<dim3(16, H_, N_), 256, 0, stream>>>(qkvb, attp);
  k_attfin<<<384, 256, 0, stream>>>(attp, alphas, att1s, attT);

  // out_pre = fused (W3h@x1v) x attn -> pre fp32 [v][t][c]
  k_fcomb<<<dim3(204, 1, N_), 256, 0, stream>>>(x1pb, wb + 192 * 128, attT, out_b, pre);

  k_bnstats_p<<<204, 256, 0, stream>>>(pre, part);
  k_bnab<<<1, 128, 0, stream>>>(part, out_g, out_beta, ab);
  k_bnxt<<<2048, 256, 0, stream>>>(pre, x1p, ab, xs3pb);

  // ff_pre = Wff@xs3 + ff_b -> pre fp32 [v][t][c] (overwrite)
  k_gmm2<2, 0><<<dim3(102, 1, N_), 256, 0, stream>>>(wb + 576 * 128, xs3pb, ff_b, pre);
  k_bnstats_p<<<204, 256, 0, stream>>>(pre, part);
  k_bnab<<<1, 128, 0, stream>>>(part, ff_g, ff_beta, ab + 256);
  k_bnfinal<<<dim3(4, 64, N_), 256, 0, stream>>>(pre, x1p, ab + 256, dout);
}

// Round 8
// 364.125 us; speedup vs baseline: 6.5104x; 1.0508x over previous
//
#include <hip/hip_runtime.h>
#include <math.h>

#define N_ 8
#define C_ 128
#define T_ 64
#define V_ 204
#define H_ 3
#define QKD_ 32
#define O2_ 192            // 2*H*QKD
#define TV_ 13056          // T*V
#define CT_ 8192           // C*T
#define TT_ 4096           // T*T
#define VV_ 41616          // V*V
#define NCTV_ 13369344ull  // N*C*T*V
#define DSPLIT_ 32
#define ZR_ 208
#define NBLK_ 1632         // stat-partial blocks (fcomb: 8*204; ff: 8*102*2)

typedef __attribute__((ext_vector_type(8))) short short8v;
typedef __attribute__((ext_vector_type(4))) float f32x4;

__device__ inline unsigned short bf16rnd(float f) {
  union { float f; unsigned u; } x; x.f = f;
  return (unsigned short)((x.u + 0x7FFFu + ((x.u >> 16) & 1u)) >> 16);
}
__device__ inline float bf2f(unsigned short u) {
  union { unsigned u; float f; } x; x.u = ((unsigned)u) << 16;
  return x.f;
}

// ---- weights -> bf16 rows [m][128]: qkv_wb(192) | w3b(384: [h][o]) | ff_wb(128) ----
__global__ void k_wprep(const float* __restrict__ qw, const float* __restrict__ ow,
                        const float* __restrict__ fw, unsigned short* __restrict__ wb) {
  int g = blockIdx.x * 256 + threadIdx.x;
  if (g >= 704 * 16) return;
  int row = g >> 4, ch = g & 15;
  const float* src;
  if (row < 192) src = qw + row * 128;
  else if (row < 576) { int r = row - 192; src = ow + (r & 127) * 384 + (r >> 7) * 128; }
  else src = fw + (row - 576) * 128;
  f32x4 a = *(const f32x4*)(src + ch * 8);
  f32x4 b = *(const f32x4*)(src + ch * 8 + 4);
  unsigned short buf[8];
  buf[0] = bf16rnd(a.x); buf[1] = bf16rnd(a.y); buf[2] = bf16rnd(a.z); buf[3] = bf16rnd(a.w);
  buf[4] = bf16rnd(b.x); buf[5] = bf16rnd(b.y); buf[6] = bf16rnd(b.z); buf[7] = bf16rnd(b.w);
  *(uint4*)(wb + (size_t)row * 128 + ch * 8) = *(const uint4*)buf;
}

// ---- qpe[m][t] = qkv_b[m] + sum_c qkv_w[m][c]*pe[c][t] ----
__global__ void k_qkvpe(const float* __restrict__ qw, const float* __restrict__ qb,
                        float* __restrict__ qpe) {
  __shared__ float pes[C_ * T_];
  int tid = threadIdx.x;
  for (int i = tid; i < C_ * T_; i += 256) {
    int t = i & 63, c = i >> 6;
    int j = c >> 1;
    float dv = expf((2.0f * j) * (-logf(10000.0f) / (float)C_));
    float ang = (float)t * dv;
    pes[i] = (c & 1) ? cosf(ang) : sinf(ang);
  }
  __syncthreads();
  int g = blockIdx.x * 256 + tid;
  int t = g & 63, m = g >> 6;
  float a = 0.f;
  for (int c = 0; c < C_; ++c) a += qw[m * C_ + c] * pes[c * T_ + t];
  qpe[g] = a + qb[m];
}

// ---------------- s[n,c,t] = 1/max(||x||,1e-12)^2 ----------------
__global__ void k_scale(const float* __restrict__ x, float* __restrict__ s) {
  int gid = blockIdx.x * blockDim.x + threadIdx.x;
  int w = gid >> 6, lane = gid & 63;
  if (w >= N_ * CT_) return;
  const f32x4* row = (const f32x4*)(x + (size_t)w * V_);
  float a = 0.f;
  for (int v4 = lane; v4 < 51; v4 += 64) {
    f32x4 t = row[v4];
    a += t.x * t.x + t.y * t.y + t.z * t.z + t.w * t.w;
  }
#pragma unroll
  for (int off = 32; off >= 1; off >>= 1) a += __shfl_down(a, off, 64);
  if (lane == 0) {
    float d = fmaxf(sqrtf(a), 1e-12f);
    s[w] = 1.0f / (d * d);
  }
}

// ---- Z-prep: fragment-major bf16 hi/lo + colmean ----
__global__ __launch_bounds__(256) void k_zprep(const float* __restrict__ x,
                                               const float* __restrict__ s,
                                               unsigned short* __restrict__ zhi,
                                               unsigned short* __restrict__ zlo,
                                               float* __restrict__ cm) {
  int kt = blockIdx.x, ut = blockIdx.y, n = blockIdx.z;
  int k0 = kt * 64, u0 = ut * 64;
  __shared__ float Ts[64][65];
  __shared__ float sq[64];
  int tid = threadIdx.x;
  int uu = tid & 63, kk = tid >> 6;
  int u = u0 + uu;
  bool uok = u < V_;
  const float* xb = x + (size_t)n * CT_ * V_;
#pragma unroll
  for (int it = 0; it < 16; ++it) {
    int kr = kk + it * 4;
    Ts[kr][uu] = uok ? xb[(size_t)(k0 + kr) * V_ + u] : 0.f;
  }
  if (tid < 64) sq[tid] = sqrtf(s[(size_t)n * CT_ + k0 + tid]);
  __syncthreads();
  if (tid < 64 && uok) {
    float a = 0.f;
    for (int t = 0; t < 64; ++t) a += Ts[t][tid];
    cm[((size_t)n * C_ + kt) * V_ + u] = a * (1.0f / 64.0f);
  }
#pragma unroll
  for (int it = 0; it < 4; ++it) {
    int sl = tid + it * 256;
    int u_l = sl & 63, oct = (sl >> 6) & 7, half = sl >> 9;
    int ug = u0 + u_l;
    if (ug >= ZR_) continue;
    unsigned short buf[8];
    if (ug < V_) {
#pragma unroll
      for (int j = 0; j < 8; ++j) {
        float z = Ts[oct * 8 + j][u_l] * sq[oct * 8 + j];
        unsigned short h = bf16rnd(z);
        buf[j] = half ? bf16rnd(z - bf2f(h)) : h;
      }
    } else {
#pragma unroll
      for (int j = 0; j < 8; ++j) buf[j] = 0;
    }
    unsigned short* dst = (half ? zlo : zhi) +
                          (((size_t)n * 1024 + kt * 8 + oct) * ZR_ + ug) * 8;
    *(uint4*)dst = *(const uint4*)buf;
  }
}

// ---- dis via split-bf16 MFMA; K-split 32 for occupancy ----
__global__ __launch_bounds__(256) void k_dism(const unsigned short* __restrict__ zhi,
                                              const unsigned short* __restrict__ zlo,
                                              float* __restrict__ pdis) {
  int q = blockIdx.x, sp = blockIdx.y, n = blockIdx.z;
  int bu = (q == 2) ? 1 : 0, bv = (q == 0) ? 0 : 1;
  int u0 = bu * 128, v0 = bv * 128;
  bool dg = (bu == bv);
  __shared__ unsigned short As[8 * 128 * 8];
  __shared__ unsigned short Bs[8 * 128 * 8];
  int tid = threadIdx.x, lane = tid & 63, wid = tid >> 6;
  int lr = lane & 15, lg = lane >> 4;
  f32x4 acc[2][8];
#pragma unroll
  for (int mi = 0; mi < 2; ++mi)
#pragma unroll
    for (int li = 0; li < 8; ++li) acc[mi][li] = (f32x4){0.f, 0.f, 0.f, 0.f};
  const int KCH = CT_ / DSPLIT_;  // 256
  int kbase = sp * KCH, kend = kbase + KCH;
  for (int kk = kbase; kk < kend; kk += 32) {
    int koct = kk >> 3;
    __syncthreads();
#pragma unroll
    for (int it = 0; it < 4; ++it) {
      int sl = tid + it * 256;
      int row = sl & 127, hs = sl >> 7;
      int slot = hs & 3, half = hs >> 2;
      const unsigned short* src = half ? zlo : zhi;
      size_t ob = ((size_t)n * 1024 + koct + slot) * ZR_;
      int ra = u0 + row; ra = ra > 207 ? 207 : ra;
      *(uint4*)&As[(hs * 128 + row) * 8] = *(const uint4*)(src + (ob + ra) * 8);
      if (!dg) {
        int rb = v0 + row; rb = rb > 207 ? 207 : rb;
        *(uint4*)&Bs[(hs * 128 + row) * 8] = *(const uint4*)(src + (ob + rb) * 8);
      }
    }
    __syncthreads();
    const unsigned short* Bp = dg ? As : Bs;
    short8v ah[2], al[2];
#pragma unroll
    for (int mi = 0; mi < 2; ++mi) {
      int r = wid * 32 + mi * 16 + lr;
      ah[mi] = *(const short8v*)&As[(lg * 128 + r) * 8];
      al[mi] = *(const short8v*)&As[((4 + lg) * 128 + r) * 8];
    }
#pragma unroll
    for (int li = 0; li < 8; ++li) {
      int rv = li * 16 + lr;
      short8v bh = *(const short8v*)&Bp[(lg * 128 + rv) * 8];
      short8v bl = *(const short8v*)&Bp[((4 + lg) * 128 + rv) * 8];
#pragma unroll
      for (int mi = 0; mi < 2; ++mi) {
        acc[mi][li] = __builtin_amdgcn_mfma_f32_16x16x32_bf16(ah[mi], bh, acc[mi][li], 0, 0, 0);
        acc[mi][li] = __builtin_amdgcn_mfma_f32_16x16x32_bf16(ah[mi], bl, acc[mi][li], 0, 0, 0);
        acc[mi][li] = __builtin_amdgcn_mfma_f32_16x16x32_bf16(al[mi], bh, acc[mi][li], 0, 0, 0);
      }
    }
  }
  float* pb = pdis + ((size_t)sp * N_ + n) * VV_;
#pragma unroll
  for (int mi = 0; mi < 2; ++mi) {
#pragma unroll
    for (int li = 0; li < 8; ++li) {
      int v = v0 + li * 16 + lr;
      if (v >= V_) continue;
#pragma unroll
      for (int rr = 0; rr < 4; ++rr) {
        int u = u0 + wid * 32 + mi * 16 + lg * 4 + rr;
        if (u >= V_) continue;
        float val = acc[mi][li][rr];
        pb[(size_t)u * V_ + v] = val;
        if (!dg) pb[(size_t)v * V_ + u] = val;
      }
    }
  }
}

// ---- fused partial-sum + wave-parallel top-3 ----
__global__ void k_topk2(const float* __restrict__ pdis, int* __restrict__ idx) {
  int r = blockIdx.x;
  int n = r / V_, u = r - n * V_;
  int lane = threadIdx.x;
  float m0 = -INFINITY, m1 = -INFINITY, m2 = -INFINITY;
  int i0 = 0x7fffffff, i1 = 0x7fffffff, i2 = 0x7fffffff;
#pragma unroll
  for (int g = 0; g < 4; ++g) {
    int v = g * 64 + lane;
    if (v >= V_) break;
    float a = 0.f;
#pragma unroll
    for (int sp = 0; sp < DSPLIT_; ++sp)
      a += pdis[((size_t)sp * N_ + n) * VV_ + (size_t)u * V_ + v];
    if (a > m0 || (a == m0 && v < i0)) {
      m2 = m1; i2 = i1; m1 = m0; i1 = i0; m0 = a; i0 = v;
    } else if (a > m1 || (a == m1 && v < i1)) {
      m2 = m1; i2 = i1; m1 = a; i1 = v;
    } else if (a > m2 || (a == m2 && v < i2)) {
      m2 = a; i2 = v;
    }
  }
#pragma unroll
  for (int msk = 1; msk < 64; msk <<= 1) {
    float o0 = __shfl_xor(m0, msk, 64), o1 = __shfl_xor(m1, msk, 64),
          o2 = __shfl_xor(m2, msk, 64);
    int p0 = __shfl_xor(i0, msk, 64), p1 = __shfl_xor(i1, msk, 64),
        p2 = __shfl_xor(i2, msk, 64);
    float ov[3] = {o0, o1, o2};
    int op[3] = {p0, p1, p2};
#pragma unroll
    for (int e = 0; e < 3; ++e) {
      float a = ov[e]; int v = op[e];
      if (a > m0 || (a == m0 && v < i0)) {
        m2 = m1; i2 = i1; m1 = m0; i1 = i0; m0 = a; i0 = v;
      } else if (a > m1 || (a == m1 && v < i1)) {
        m2 = m1; i2 = i1; m1 = a; i1 = v;
      } else if (a > m2 || (a == m2 && v < i2)) {
        m2 = a; i2 = v;
      }
    }
  }
  if (lane == 0) {
    idx[r * 3 + 0] = i0; idx[r * 3 + 1] = i1; idx[r * 3 + 2] = i2;
  }
}

// ---------------- w2 ----------------
__global__ void k_w2(const float* __restrict__ cm, const int* __restrict__ idx,
                     const float* __restrict__ tw, const float* __restrict__ tb,
                     const float* __restrict__ ckw, float* __restrict__ w2) {
  int r = blockIdx.x;
  int n = r / V_;
  int lane = threadIdx.x;
  __shared__ float mv[3][C_];
  const int* ib = idx + r * 3;
  int j0 = ib[0], j1 = ib[1], j2 = ib[2];
  const float* cmn = cm + (size_t)n * C_ * V_;
  for (int c = lane; c < C_; c += 64) {
    mv[0][c] = cmn[c * V_ + j0];
    mv[1][c] = cmn[c * V_ + j1];
    mv[2][c] = cmn[c * V_ + j2];
  }
  __syncthreads();
  float p[9];
#pragma unroll
  for (int gp = 0; gp < 9; ++gp) p[gp] = 0.f;
  for (int c = lane; c < C_; c += 64) {
#pragma unroll
    for (int g = 0; g < 3; ++g) {
      float m = mv[g][c];
#pragma unroll
      for (int pp = 0; pp < 3; ++pp) p[g * 3 + pp] += m * tw[(g * 3 + pp) * C_ + c];
    }
  }
#pragma unroll
  for (int off = 32; off >= 1; off >>= 1) {
#pragma unroll
    for (int gp = 0; gp < 9; ++gp) p[gp] += __shfl_down(p[gp], off, 64);
  }
  if (lane == 0) {
    float c0 = ckw[0], c1 = ckw[1], c2 = ckw[2];
#pragma unroll
    for (int g = 0; g < 3; ++g) {
      float m0 = p[g * 3 + 0] + tb[g * 3 + 0];
      float m1 = p[g * 3 + 1] + tb[g * 3 + 1];
      float m2 = p[g * 3 + 2] + tb[g * 3 + 2];
      float mx = fmaxf(m0, fmaxf(m1, m2));
      float e0 = expf(m0 - mx), e1 = expf(m1 - mx), e2 = expf(m2 - mx);
      float inv = 1.0f / (e0 + e1 + e2);
      w2[r * 3 + g] = (e0 * c0 + e1 * c1 + e2 * c2) * inv;
    }
  }
}

// ---- x1 producer -> [n][v][t][c] layouts: x1p fp32 + x1pb bf16 ----
__global__ __launch_bounds__(256) void k_x1p(const float* __restrict__ x,
                                             const int* __restrict__ idx,
                                             const float* __restrict__ w2,
                                             const float* __restrict__ ckb,
                                             float* __restrict__ x1p,
                                             unsigned short* __restrict__ x1pb) {
  int t = blockIdx.x, ct = blockIdx.y, n = blockIdx.z;
  int c0 = ct * 32;
  __shared__ float Ts[32][209];
  __shared__ int iw[V_ * 3];
  __shared__ float ww[V_ * 3];
  int tid = threadIdx.x;
  const float* xb = x + ((size_t)n * C_ + c0) * TV_ + t * V_;
  for (int i = tid; i < 32 * V_; i += 256) {
    int c = i / V_, v = i - c * V_;
    Ts[c][v] = xb[(size_t)c * TV_ + v];
  }
  for (int i = tid; i < V_ * 3; i += 256) {
    iw[i] = idx[(size_t)n * V_ * 3 + i];
    ww[i] = w2[(size_t)n * V_ * 3 + i];
  }
  __syncthreads();
  float cb = ckb[0];
  for (int i = tid; i < 32 * V_; i += 256) {
    int v = i >> 5, cl = i & 31;
    int b = v * 3;
    float pooled = Ts[cl][iw[b]] * ww[b] + Ts[cl][iw[b + 1]] * ww[b + 1] +
                   Ts[cl][iw[b + 2]] * ww[b + 2] + cb;
    float val = fmaxf(pooled + Ts[cl][v], 0.f);
    size_t o = ((size_t)(n * V_ + v) * T_ + t) * C_ + c0 + cl;
    x1p[o] = val;
    x1pb[o] = bf16rnd(val);
  }
}

// ---- MFMA GEMM: Y = W@X (X=[l'][c] bf16), M-loop in block, LDS-staged ----
// STATS=1 (OBF=0 only): fused BN partial sums into part[(blk*2+wl)*256 + {m,128+m}]
template <int MCH, int OBF, int STATS>
__global__ __launch_bounds__(256) void k_gmm2(const unsigned short* __restrict__ Wb,
                                              const unsigned short* __restrict__ Xp,
                                              const float* __restrict__ addv,
                                              void* __restrict__ Yv,
                                              float* __restrict__ part) {
  int l0 = blockIdx.x * 128, n = blockIdx.z;
  __shared__ unsigned short Xs[128 * 136];
  __shared__ unsigned short Ys[64 * 128];
  int tid = threadIdx.x, lane = tid & 63, wid = tid >> 6;
  int wm = wid >> 1, wl = wid & 1;
  int lr = lane & 15, lg = lane >> 4;
  const unsigned short* xb = Xp + ((size_t)n * TV_ + l0) * 128;
#pragma unroll
  for (int it = 0; it < 8; ++it) {
    int g = tid + it * 256;
    int row = g >> 4, ch = g & 15;
    *(uint4*)&Xs[row * 136 + ch * 8] = *(const uint4*)(xb + (size_t)row * 128 + ch * 8);
  }
  __syncthreads();
  for (int mc = 0; mc < MCH; ++mc) {
    short8v a[2][4];
#pragma unroll
    for (int mi = 0; mi < 2; ++mi) {
      int m = mc * 64 + wm * 32 + mi * 16 + lr;
#pragma unroll
      for (int ks = 0; ks < 4; ++ks)
        a[mi][ks] = *(const short8v*)(Wb + (size_t)m * 128 + ks * 32 + lg * 8);
    }
    f32x4 acc[2][4];
#pragma unroll
    for (int mi = 0; mi < 2; ++mi)
#pragma unroll
      for (int li = 0; li < 4; ++li) acc[mi][li] = (f32x4){0.f, 0.f, 0.f, 0.f};
#pragma unroll
    for (int ks = 0; ks < 4; ++ks) {
#pragma unroll
      for (int li = 0; li < 4; ++li) {
        short8v b = *(const short8v*)&Xs[(wl * 64 + li * 16 + lr) * 136 + ks * 32 + lg * 8];
#pragma unroll
        for (int mi = 0; mi < 2; ++mi)
          acc[mi][li] = __builtin_amdgcn_mfma_f32_16x16x32_bf16(a[mi][ks], b, acc[mi][li], 0, 0, 0);
      }
    }
    if (OBF) {
      __syncthreads();
#pragma unroll
      for (int mi = 0; mi < 2; ++mi)
#pragma unroll
        for (int li = 0; li < 4; ++li) {
          int lloc = wl * 64 + li * 16 + lr;
          int tt = (l0 + lloc) & 63;
#pragma unroll
          for (int r = 0; r < 4; ++r) {
            int mloc = wm * 32 + mi * 16 + lg * 4 + r;
            float val = acc[mi][li][r] + addv[(mc * 64 + mloc) * 64 + tt];
            Ys[mloc * 128 + lloc] = bf16rnd(val);
          }
        }
      __syncthreads();
      unsigned short* Yh = (unsigned short*)Yv;
#pragma unroll
      for (int it = 0; it < 4; ++it) {
        int g = tid + it * 256;
        int row = g >> 4, ch = g & 15;
        *(uint4*)(Yh + ((size_t)n * O2_ + mc * 64 + row) * TV_ + l0 + ch * 8) =
            *(const uint4*)&Ys[row * 128 + ch * 8];
      }
    } else {
      float* Yf = (float*)Yv;
      float st1[2][4] = {}, st2[2][4] = {};
#pragma unroll
      for (int mi = 0; mi < 2; ++mi)
#pragma unroll
        for (int li = 0; li < 4; ++li) {
          int lp = l0 + wl * 64 + li * 16 + lr;
          int m = mc * 64 + wm * 32 + mi * 16 + lg * 4;
          f32x4 o;
#pragma unroll
          for (int r = 0; r < 4; ++r) {
            o[r] = acc[mi][li][r] + addv[m + r];
            if (STATS) { st1[mi][r] += o[r]; st2[mi][r] += o[r] * o[r]; }
          }
          *(f32x4*)(Yf + ((size_t)n * TV_ + lp) * 128 + m) = o;
        }
      if (STATS) {
        int blk2 = ((n * gridDim.x + blockIdx.x) * 2 + wl) * 256;
#pragma unroll
        for (int mi = 0; mi < 2; ++mi)
#pragma unroll
          for (int r = 0; r < 4; ++r) {
            float a1 = st1[mi][r], a2 = st2[mi][r];
            a1 += __shfl_xor(a1, 1, 64); a2 += __shfl_xor(a2, 1, 64);
            a1 += __shfl_xor(a1, 2, 64); a2 += __shfl_xor(a2, 2, 64);
            a1 += __shfl_xor(a1, 4, 64); a2 += __shfl_xor(a2, 4, 64);
            a1 += __shfl_xor(a1, 8, 64); a2 += __shfl_xor(a2, 8, 64);
            if (lr == 0) {
              int m = mc * 64 + wm * 32 + mi * 16 + lg * 4 + r;
              part[blk2 + m] = a1;
              part[blk2 + 128 + m] = a2;
            }
          }
      }
    }
  }
}

// ---- attention partials (qkv bf16 [m][v][t]): attp[cp][n][h][t][q] ----
__global__ __launch_bounds__(256) void k_att(const unsigned short* __restrict__ qkv,
                                             float* __restrict__ attp) {
  int cp = blockIdx.x, h = blockIdx.y, n = blockIdx.z;
  __shared__ float Qs[102][68], Ks[102][68];
  int tid = threadIdx.x;
  int ty = tid >> 4, tx = tid & 15;
  float acc[4][4] = {};
  for (int cc = 0; cc < 2; ++cc) {
    int c = cp * 2 + cc;
    const unsigned short* qb = qkv + ((size_t)n * O2_ + h * QKD_ + c) * TV_;
    const unsigned short* kb = qkv + ((size_t)n * O2_ + H_ * QKD_ + h * QKD_ + c) * TV_;
    for (int vh = 0; vh < 2; ++vh) {
      for (int g = tid; g < 816; g += 256) {
        int v = g >> 3, t0 = (g & 7) * 8;
        uint4 qv = *(const uint4*)(qb + vh * 6528 + g * 8);
        uint4 kv = *(const uint4*)(kb + vh * 6528 + g * 8);
        const unsigned short* qs = (const unsigned short*)&qv;
        const unsigned short* ks2 = (const unsigned short*)&kv;
#pragma unroll
        for (int j = 0; j < 8; ++j) {
          Qs[v][t0 + j] = bf2f(qs[j]);
          Ks[v][t0 + j] = bf2f(ks2[j]);
        }
      }
      __syncthreads();
      for (int vv = 0; vv < 102; ++vv) {
        f32x4 qa = *(const f32x4*)&Qs[vv][ty * 4];
        f32x4 ka = *(const f32x4*)&Ks[vv][tx * 4];
#pragma unroll
        for (int i = 0; i < 4; ++i)
#pragma unroll
          for (int j = 0; j < 4; ++j) acc[i][j] += qa[i] * ka[j];
      }
      __syncthreads();
    }
  }
  float* ar = attp + (((size_t)cp * N_ + n) * H_ + h) * TT_;
#pragma unroll
  for (int i = 0; i < 4; ++i)
#pragma unroll
    for (int j = 0; j < 4; ++j)
      ar[(ty * 4 + i) * T_ + tx * 4 + j] = acc[i][j];
}

// ---- attT[n][q][h*64+t] = bf16(tanh(sum_cp attp /6528)*alpha + att1s) ----
__global__ void k_attfin(const float* __restrict__ attp, const float* __restrict__ alphas,
                         const float* __restrict__ att1s, unsigned short* __restrict__ attT) {
  int i = blockIdx.x * blockDim.x + threadIdx.x;
  if (i >= N_ * H_ * TT_) return;
  int tt = i % TT_;
  int h = (i / TT_) % H_;
  int n = i / (H_ * TT_);
  float raw = 0.f;
#pragma unroll
  for (int cp = 0; cp < 16; ++cp)
    raw += attp[(((size_t)cp * N_ + n) * H_ + h) * TT_ + tt];
  int t = tt >> 6, q = tt & 63;
  float v = tanhf(raw * (1.0f / 6528.0f)) * alphas[h] + att1s[h * TT_ + tt];
  attT[(size_t)(n * 64 + q) * 192 + h * 64 + t] = bf16rnd(v);
}

// ---- fused Y3+comb, no Xv stage (global B-frags, L1/L2-hot), fused BN stats ----
__global__ __launch_bounds__(256) void k_fcomb(const unsigned short* __restrict__ x1pb,
                                               const unsigned short* __restrict__ w3b,
                                               const unsigned short* __restrict__ attT,
                                               const float* __restrict__ outb,
                                               float* __restrict__ op,
                                               float* __restrict__ part) {
  int v = blockIdx.x, n = blockIdx.z;
  __shared__ unsigned short Yv[128 * 72];  // [o][t] padded
  int tid = threadIdx.x, lane = tid & 63, wid = tid >> 6;
  int lr = lane & 15, lg = lane >> 4;
  const unsigned short* xb = x1pb + ((size_t)(n * V_ + v) * T_) * 128;
  f32x4 acc2[4][2];
#pragma unroll
  for (int mq = 0; mq < 4; ++mq)
#pragma unroll
    for (int oi = 0; oi < 2; ++oi) acc2[mq][oi] = (f32x4){0.f, 0.f, 0.f, 0.f};
  const unsigned short* ab = attT + (size_t)n * 64 * 192;
  for (int h = 0; h < H_; ++h) {
    short8v a1[2][4];
#pragma unroll
    for (int mi = 0; mi < 2; ++mi) {
      int m = wid * 32 + mi * 16 + lr;
#pragma unroll
      for (int ks = 0; ks < 4; ++ks)
        a1[mi][ks] = *(const short8v*)(w3b + ((size_t)(h * 128 + m)) * 128 + ks * 32 + lg * 8);
    }
    f32x4 acc1[2][4];
#pragma unroll
    for (int mi = 0; mi < 2; ++mi)
#pragma unroll
      for (int li = 0; li < 4; ++li) acc1[mi][li] = (f32x4){0.f, 0.f, 0.f, 0.f};
#pragma unroll
    for (int ks = 0; ks < 4; ++ks) {
#pragma unroll
      for (int li = 0; li < 4; ++li) {
        short8v b = *(const short8v*)(xb + (size_t)(li * 16 + lr) * 128 + ks * 32 + lg * 8);
#pragma unroll
        for (int mi = 0; mi < 2; ++mi)
          acc1[mi][li] = __builtin_amdgcn_mfma_f32_16x16x32_bf16(a1[mi][ks], b, acc1[mi][li], 0, 0, 0);
      }
    }
    __syncthreads();  // prior acc2 reads of Yv done before overwrite (h=0: no-op)
#pragma unroll
    for (int mi = 0; mi < 2; ++mi)
#pragma unroll
      for (int li = 0; li < 4; ++li) {
        int t = li * 16 + lr;
#pragma unroll
        for (int r = 0; r < 4; ++r) {
          int o = wid * 32 + mi * 16 + lg * 4 + r;
          Yv[o * 72 + t] = bf16rnd(acc1[mi][li][r]);
        }
      }
    __syncthreads();
#pragma unroll
    for (int ks2 = 0; ks2 < 2; ++ks2) {
      short8v bY[2];
#pragma unroll
      for (int oi = 0; oi < 2; ++oi)
        bY[oi] = *(const short8v*)&Yv[(wid * 32 + oi * 16 + lr) * 72 + ks2 * 32 + lg * 8];
#pragma unroll
      for (int mq = 0; mq < 4; ++mq) {
        short8v a2 = *(const short8v*)(ab + (size_t)(mq * 16 + lr) * 192 + h * 64 + ks2 * 32 + lg * 8);
#pragma unroll
        for (int oi = 0; oi < 2; ++oi)
          acc2[mq][oi] = __builtin_amdgcn_mfma_f32_16x16x32_bf16(a2, bY[oi], acc2[mq][oi], 0, 0, 0);
      }
    }
  }
  float s1[2] = {0.f, 0.f}, s2[2] = {0.f, 0.f};
#pragma unroll
  for (int mq = 0; mq < 4; ++mq)
#pragma unroll
    for (int oi = 0; oi < 2; ++oi) {
      int o = wid * 32 + oi * 16 + lr;
      float bo = outb[o];
#pragma unroll
      for (int r = 0; r < 4; ++r) {
        int q = mq * 16 + lg * 4 + r;
        float val = acc2[mq][oi][r] + bo;
        op[((size_t)(n * V_ + v) * T_ + q) * 128 + o] = val;
        s1[oi] += val; s2[oi] += val * val;
      }
    }
  int blk = (n * V_ + v) * 256;
#pragma unroll
  for (int oi = 0; oi < 2; ++oi) {
    float a1 = s1[oi], a2 = s2[oi];
    a1 += __shfl_xor(a1, 16, 64); a2 += __shfl_xor(a2, 16, 64);
    a1 += __shfl_xor(a1, 32, 64); a2 += __shfl_xor(a2, 32, 64);
    if ((lane & 48) == 0) {
      int o = wid * 32 + oi * 16 + lr;
      part[blk + o] = a1;
      part[blk + 128 + o] = a2;
    }
  }
}

// ---- fold NBLK_ stat partials -> ab[c]=a, ab[128+c]=b; grid 128 (c) ----
__global__ void k_bnab(const float* __restrict__ part, const float* __restrict__ g,
                       const float* __restrict__ beta, float* __restrict__ ab) {
  int c = blockIdx.x;
  int tid = threadIdx.x;
  float s1 = 0.f, s2 = 0.f;
  for (int b = tid; b < NBLK_; b += 256) {
    s1 += part[b * 256 + c];
    s2 += part[b * 256 + 128 + c];
  }
  __shared__ float r1[256], r2[256];
  r1[tid] = s1; r2[tid] = s2;
  __syncthreads();
  for (int off = 128; off >= 1; off >>= 1) {
    if (tid < off) { r1[tid] += r1[tid + off]; r2[tid] += r2[tid + off]; }
    __syncthreads();
  }
  if (tid == 0) {
    const float cnt = (float)(N_ * TV_);
    float mu = r1[0] / cnt;
    float rstd = rsqrtf(r2[0] / cnt - mu * mu + 1e-5f);
    float a = rstd * g[c];
    ab[c] = a;
    ab[128 + c] = beta[c] - mu * a;
  }
}

// ---- xs3pb = bf16(leaky(bn(op)+x1p)), elementwise [l'][c] ----
__global__ void k_bnxt(const float* __restrict__ op, const float* __restrict__ x1p,
                       const float* __restrict__ ab, unsigned short* __restrict__ xt) {
  __shared__ float sa[128], sb[128];
  int tid = threadIdx.x;
  if (tid < 128) { sa[tid] = ab[tid]; sb[tid] = ab[128 + tid]; }
  __syncthreads();
  const unsigned NU = (unsigned)(NCTV_ / 8);
  const f32x4* o4 = (const f32x4*)op;
  const f32x4* r4 = (const f32x4*)x1p;
  for (unsigned u = blockIdx.x * 256u + tid; u < NU; u += gridDim.x * 256u) {
    unsigned row = u >> 4, ch = u & 15;
    unsigned bi = row * 32 + ch * 2;
    f32x4 v0 = o4[bi], v1 = o4[bi + 1];
    f32x4 q0 = r4[bi], q1 = r4[bi + 1];
    int c8 = ch * 8;
    unsigned short buf[8];
#pragma unroll
    for (int j = 0; j < 4; ++j) {
      float t0 = v0[j] * sa[c8 + j] + sb[c8 + j] + q0[j];
      float t1 = v1[j] * sa[c8 + 4 + j] + sb[c8 + 4 + j] + q1[j];
      buf[j] = bf16rnd(t0 > 0.f ? t0 : 0.1f * t0);
      buf[4 + j] = bf16rnd(t1 > 0.f ? t1 : 0.1f * t1);
    }
    *(uint4*)(xt + (size_t)u * 8) = *(const uint4*)buf;
  }
}

// ---- final: leaky(bn(ff)+x1p), transpose [v][t][c] -> d_out [c][t][v] ----
__global__ __launch_bounds__(256) void k_bnfinal(const float* __restrict__ ff,
                                                 const float* __restrict__ x1p,
                                                 const float* __restrict__ ab,
                                                 float* __restrict__ dout) {
  int ct = blockIdx.x, t = blockIdx.y, n = blockIdx.z;
  int c0 = ct * 32;
  __shared__ float Tf[V_][33];
  __shared__ float sa[32], sb[32];
  int tid = threadIdx.x;
  if (tid < 32) { sa[tid] = ab[c0 + tid]; sb[tid] = ab[128 + c0 + tid]; }
  __syncthreads();
  for (int i = tid; i < V_ * 32; i += 256) {
    int v = i >> 5, cl = i & 31;
    size_t a = ((size_t)(n * V_ + v) * T_ + t) * 128 + c0 + cl;
    float val = ff[a] * sa[cl] + sb[cl] + x1p[a];
    Tf[v][cl] = val > 0.f ? val : 0.1f * val;
  }
  __syncthreads();
  for (int i = tid; i < 32 * V_; i += 256) {
    int cl = i / V_, v = i - cl * V_;
    dout[((size_t)(n * C_ + c0 + cl) * T_ + t) * V_ + v] = Tf[v][cl];
  }
}

extern "C" void kernel_launch(void* const* d_in, const int* in_sizes, int n_in,
                              void* d_out, int out_size, void* d_ws, size_t ws_size,
                              hipStream_t stream) {
  (void)in_sizes; (void)n_in; (void)out_size; (void)ws_size;
  const float* x        = (const float*)d_in[0];
  const float* trans_w  = (const float*)d_in[1];
  const float* trans_b  = (const float*)d_in[2];
  const float* convk_w  = (const float*)d_in[3];
  const float* convk_b  = (const float*)d_in[4];
  const float* qkv_w    = (const float*)d_in[5];
  const float* qkv_b    = (const float*)d_in[6];
  const float* alphas   = (const float*)d_in[7];
  const float* att1s    = (const float*)d_in[8];
  const float* out_w    = (const float*)d_in[9];
  const float* out_b    = (const float*)d_in[10];
  const float* out_g    = (const float*)d_in[11];
  const float* out_beta = (const float*)d_in[12];
  const float* ff_w     = (const float*)d_in[13];
  const float* ff_b     = (const float*)d_in[14];
  const float* ff_g     = (const float*)d_in[15];
  const float* ff_beta  = (const float*)d_in[16];

  float* ws = (float*)d_ws;
  size_t off = 0;
  float* x1p  = ws + off; off += NCTV_;                      // fp32 [v][t][c]
  float* big  = ws + off; off += (size_t)N_ * O2_ * TV_ / 2; // qkv bf16 [m][v][t]
  float* pre  = ws + off; off += NCTV_;                      // pdis(32sp) -> out_pre -> ff_pre
  float* sbuf = ws + off; off += (size_t)N_ * CT_;
  int*   idx  = (int*)(ws + off); off += (size_t)N_ * V_ * 3 + 4;
  float* cm   = ws + off; off += (size_t)N_ * C_ * V_;
  float* w2   = ws + off; off += (size_t)N_ * V_ * 3 + 4;
  float* attp = ws + off; off += (size_t)16 * N_ * H_ * TT_;
  unsigned short* attT = (unsigned short*)(ws + off); off += (size_t)N_ * 64 * 192 / 2;
  float* part = ws + off; off += (size_t)NBLK_ * 256;        // 1.67 MB
  float* ab   = ws + off; off += 512;
  float* qpe  = ws + off; off += (size_t)O2_ * T_;
  unsigned short* wb = (unsigned short*)(ws + off); off += 704 * 128 / 2;
  const size_t ZEL = (size_t)N_ * 1024 * ZR_ * 8;  // shorts per z array
  unsigned short* zhi = (unsigned short*)(ws + off);  // overlay: x1pb after dis
  unsigned short* zlo = zhi + ZEL;                    // overlay: xs3pb after dis
  off += ZEL;
  unsigned short* x1pb  = zhi;
  unsigned short* xs3pb = zlo;
  unsigned short* qkvb  = (unsigned short*)big;
  float* dout = (float*)d_out;

  k_wprep<<<44, 256, 0, stream>>>(qkv_w, out_w, ff_w, wb);
  k_qkvpe<<<48, 256, 0, stream>>>(qkv_w, qkv_b, qpe);
  k_scale<<<(N_ * CT_ * 64) / 256, 256, 0, stream>>>(x, sbuf);
  k_zprep<<<dim3(128, 4, N_), 256, 0, stream>>>(x, sbuf, zhi, zlo, cm);
  // pdis partials (32 K-splits) land in `pre` (free until fcomb)
  k_dism<<<dim3(3, DSPLIT_, N_), 256, 0, stream>>>(zhi, zlo, pre);
  k_topk2<<<N_ * V_, 64, 0, stream>>>(pre, idx);
  k_w2<<<N_ * V_, 64, 0, stream>>>(cm, idx, trans_w, trans_b, convk_w, w2);
  k_x1p<<<dim3(64, 4, N_), 256, 0, stream>>>(x, idx, w2, convk_b, x1p, x1pb);

  // qkv = Wq@x1 + qkv_b + pe-bias -> qkvb bf16 [m][v][t]
  k_gmm2<3, 1, 0><<<dim3(102, 1, N_), 256, 0, stream>>>(wb, x1pb, qpe, qkvb, nullptr);
  k_att<<<dim3(16, H_, N_), 256, 0, stream>>>(qkvb, attp);
  k_attfin<<<384, 256, 0, stream>>>(attp, alphas, att1s, attT);

  // out_pre = fused (W3h@x1v) x attn -> pre fp32 [v][t][c], + BN stat partials
  k_fcomb<<<dim3(204, 1, N_), 256, 0, stream>>>(x1pb, wb + 192 * 128, attT, out_b, pre, part);

  k_bnab<<<128, 256, 0, stream>>>(part, out_g, out_beta, ab);
  k_bnxt<<<2048, 256, 0, stream>>>(pre, x1p, ab, xs3pb);

  // ff_pre = Wff@xs3 + ff_b -> pre fp32 (overwrite), + BN stat partials
  k_gmm2<2, 0, 1><<<dim3(102, 1, N_), 256, 0, stream>>>(wb + 576 * 128, xs3pb, ff_b, pre, part);
  k_bnab<<<128, 256, 0, stream>>>(part, ff_g, ff_beta, ab + 256);
  k_bnfinal<<<dim3(4, 64, N_), 256, 0, stream>>>(pre, x1p, ab + 256, dout);
}

// Round 9
// 323.610 us; speedup vs baseline: 7.3255x; 1.1252x over previous
//
#include <hip/hip_runtime.h>
#include <math.h>

#define N_ 8
#define C_ 128
#define T_ 64
#define V_ 204
#define H_ 3
#define QKD_ 32
#define O2_ 192            // 2*H*QKD
#define TV_ 13056          // T*V
#define CT_ 8192           // C*T
#define TT_ 4096           // T*T
#define VV_ 41616          // V*V
#define NCTV_ 13369344ull  // N*C*T*V
#define DSPLIT_ 32
#define ZR_ 208
#define NBLK_ 1632         // stat-partial blocks (fcomb: 8*204; ff: 8*102*2)

typedef __attribute__((ext_vector_type(8))) short short8v;
typedef __attribute__((ext_vector_type(4))) float f32x4;

__device__ inline unsigned short bf16rnd(float f) {
  union { float f; unsigned u; } x; x.f = f;
  return (unsigned short)((x.u + 0x7FFFu + ((x.u >> 16) & 1u)) >> 16);
}
__device__ inline float bf2f(unsigned short u) {
  union { unsigned u; float f; } x; x.u = ((unsigned)u) << 16;
  return x.f;
}

// ---- weights -> bf16 rows [m][128]: qkv_wb(192) | w3b(384: [h][o]) | ff_wb(128) ----
__global__ void k_wprep(const float* __restrict__ qw, const float* __restrict__ ow,
                        const float* __restrict__ fw, unsigned short* __restrict__ wb) {
  int g = blockIdx.x * 256 + threadIdx.x;
  if (g >= 704 * 16) return;
  int row = g >> 4, ch = g & 15;
  const float* src;
  if (row < 192) src = qw + row * 128;
  else if (row < 576) { int r = row - 192; src = ow + (r & 127) * 384 + (r >> 7) * 128; }
  else src = fw + (row - 576) * 128;
  f32x4 a = *(const f32x4*)(src + ch * 8);
  f32x4 b = *(const f32x4*)(src + ch * 8 + 4);
  unsigned short buf[8];
  buf[0] = bf16rnd(a.x); buf[1] = bf16rnd(a.y); buf[2] = bf16rnd(a.z); buf[3] = bf16rnd(a.w);
  buf[4] = bf16rnd(b.x); buf[5] = bf16rnd(b.y); buf[6] = bf16rnd(b.z); buf[7] = bf16rnd(b.w);
  *(uint4*)(wb + (size_t)row * 128 + ch * 8) = *(const uint4*)buf;
}

// ---- qpe[m][t] = qkv_b[m] + sum_c qkv_w[m][c]*pe[c][t] ----
__global__ void k_qkvpe(const float* __restrict__ qw, const float* __restrict__ qb,
                        float* __restrict__ qpe) {
  __shared__ float pes[C_ * T_];
  int tid = threadIdx.x;
  for (int i = tid; i < C_ * T_; i += 256) {
    int t = i & 63, c = i >> 6;
    int j = c >> 1;
    float dv = expf((2.0f * j) * (-logf(10000.0f) / (float)C_));
    float ang = (float)t * dv;
    pes[i] = (c & 1) ? cosf(ang) : sinf(ang);
  }
  __syncthreads();
  int g = blockIdx.x * 256 + tid;
  int t = g & 63, m = g >> 6;
  float a = 0.f;
  for (int c = 0; c < C_; ++c) a += qw[m * C_ + c] * pes[c * T_ + t];
  qpe[g] = a + qb[m];
}

// ---------------- s[n,c,t] = 1/max(||x||,1e-12)^2 ----------------
__global__ void k_scale(const float* __restrict__ x, float* __restrict__ s) {
  int gid = blockIdx.x * blockDim.x + threadIdx.x;
  int w = gid >> 6, lane = gid & 63;
  if (w >= N_ * CT_) return;
  const f32x4* row = (const f32x4*)(x + (size_t)w * V_);
  float a = 0.f;
  for (int v4 = lane; v4 < 51; v4 += 64) {
    f32x4 t = row[v4];
    a += t.x * t.x + t.y * t.y + t.z * t.z + t.w * t.w;
  }
#pragma unroll
  for (int off = 32; off >= 1; off >>= 1) a += __shfl_down(a, off, 64);
  if (lane == 0) {
    float d = fmaxf(sqrtf(a), 1e-12f);
    s[w] = 1.0f / (d * d);
  }
}

// ---- Z-prep: fragment-major bf16 hi/lo + colmean ----
__global__ __launch_bounds__(256) void k_zprep(const float* __restrict__ x,
                                               const float* __restrict__ s,
                                               unsigned short* __restrict__ zhi,
                                               unsigned short* __restrict__ zlo,
                                               float* __restrict__ cm) {
  int kt = blockIdx.x, ut = blockIdx.y, n = blockIdx.z;
  int k0 = kt * 64, u0 = ut * 64;
  __shared__ float Ts[64][65];
  __shared__ float sq[64];
  int tid = threadIdx.x;
  int uu = tid & 63, kk = tid >> 6;
  int u = u0 + uu;
  bool uok = u < V_;
  const float* xb = x + (size_t)n * CT_ * V_;
#pragma unroll
  for (int it = 0; it < 16; ++it) {
    int kr = kk + it * 4;
    Ts[kr][uu] = uok ? xb[(size_t)(k0 + kr) * V_ + u] : 0.f;
  }
  if (tid < 64) sq[tid] = sqrtf(s[(size_t)n * CT_ + k0 + tid]);
  __syncthreads();
  if (tid < 64 && uok) {
    float a = 0.f;
    for (int t = 0; t < 64; ++t) a += Ts[t][tid];
    cm[((size_t)n * C_ + kt) * V_ + u] = a * (1.0f / 64.0f);
  }
#pragma unroll
  for (int it = 0; it < 4; ++it) {
    int sl = tid + it * 256;
    int u_l = sl & 63, oct = (sl >> 6) & 7, half = sl >> 9;
    int ug = u0 + u_l;
    if (ug >= ZR_) continue;
    unsigned short buf[8];
    if (ug < V_) {
#pragma unroll
      for (int j = 0; j < 8; ++j) {
        float z = Ts[oct * 8 + j][u_l] * sq[oct * 8 + j];
        unsigned short h = bf16rnd(z);
        buf[j] = half ? bf16rnd(z - bf2f(h)) : h;
      }
    } else {
#pragma unroll
      for (int j = 0; j < 8; ++j) buf[j] = 0;
    }
    unsigned short* dst = (half ? zlo : zhi) +
                          (((size_t)n * 1024 + kt * 8 + oct) * ZR_ + ug) * 8;
    *(uint4*)dst = *(const uint4*)buf;
  }
}

// ---- dis via split-bf16 MFMA; K-split 32 for occupancy ----
__global__ __launch_bounds__(256) void k_dism(const unsigned short* __restrict__ zhi,
                                              const unsigned short* __restrict__ zlo,
                                              float* __restrict__ pdis) {
  int q = blockIdx.x, sp = blockIdx.y, n = blockIdx.z;
  int bu = (q == 2) ? 1 : 0, bv = (q == 0) ? 0 : 1;
  int u0 = bu * 128, v0 = bv * 128;
  bool dg = (bu == bv);
  __shared__ unsigned short As[8 * 128 * 8];
  __shared__ unsigned short Bs[8 * 128 * 8];
  int tid = threadIdx.x, lane = tid & 63, wid = tid >> 6;
  int lr = lane & 15, lg = lane >> 4;
  f32x4 acc[2][8];
#pragma unroll
  for (int mi = 0; mi < 2; ++mi)
#pragma unroll
    for (int li = 0; li < 8; ++li) acc[mi][li] = (f32x4){0.f, 0.f, 0.f, 0.f};
  const int KCH = CT_ / DSPLIT_;  // 256
  int kbase = sp * KCH, kend = kbase + KCH;
  for (int kk = kbase; kk < kend; kk += 32) {
    int koct = kk >> 3;
    __syncthreads();
#pragma unroll
    for (int it = 0; it < 4; ++it) {
      int sl = tid + it * 256;
      int row = sl & 127, hs = sl >> 7;
      int slot = hs & 3, half = hs >> 2;
      const unsigned short* src = half ? zlo : zhi;
      size_t ob = ((size_t)n * 1024 + koct + slot) * ZR_;
      int ra = u0 + row; ra = ra > 207 ? 207 : ra;
      *(uint4*)&As[(hs * 128 + row) * 8] = *(const uint4*)(src + (ob + ra) * 8);
      if (!dg) {
        int rb = v0 + row; rb = rb > 207 ? 207 : rb;
        *(uint4*)&Bs[(hs * 128 + row) * 8] = *(const uint4*)(src + (ob + rb) * 8);
      }
    }
    __syncthreads();
    const unsigned short* Bp = dg ? As : Bs;
    short8v ah[2], al[2];
#pragma unroll
    for (int mi = 0; mi < 2; ++mi) {
      int r = wid * 32 + mi * 16 + lr;
      ah[mi] = *(const short8v*)&As[(lg * 128 + r) * 8];
      al[mi] = *(const short8v*)&As[((4 + lg) * 128 + r) * 8];
    }
#pragma unroll
    for (int li = 0; li < 8; ++li) {
      int rv = li * 16 + lr;
      short8v bh = *(const short8v*)&Bp[(lg * 128 + rv) * 8];
      short8v bl = *(const short8v*)&Bp[((4 + lg) * 128 + rv) * 8];
#pragma unroll
      for (int mi = 0; mi < 2; ++mi) {
        acc[mi][li] = __builtin_amdgcn_mfma_f32_16x16x32_bf16(ah[mi], bh, acc[mi][li], 0, 0, 0);
        acc[mi][li] = __builtin_amdgcn_mfma_f32_16x16x32_bf16(ah[mi], bl, acc[mi][li], 0, 0, 0);
        acc[mi][li] = __builtin_amdgcn_mfma_f32_16x16x32_bf16(al[mi], bh, acc[mi][li], 0, 0, 0);
      }
    }
  }
  float* pb = pdis + ((size_t)sp * N_ + n) * VV_;
#pragma unroll
  for (int mi = 0; mi < 2; ++mi) {
#pragma unroll
    for (int li = 0; li < 8; ++li) {
      int v = v0 + li * 16 + lr;
      if (v >= V_) continue;
#pragma unroll
      for (int rr = 0; rr < 4; ++rr) {
        int u = u0 + wid * 32 + mi * 16 + lg * 4 + rr;
        if (u >= V_) continue;
        float val = acc[mi][li][rr];
        pb[(size_t)u * V_ + v] = val;
        if (!dg) pb[(size_t)v * V_ + u] = val;
      }
    }
  }
}

// ---- fused partial-sum + wave-parallel top-3 ----
__global__ void k_topk2(const float* __restrict__ pdis, int* __restrict__ idx) {
  int r = blockIdx.x;
  int n = r / V_, u = r - n * V_;
  int lane = threadIdx.x;
  float m0 = -INFINITY, m1 = -INFINITY, m2 = -INFINITY;
  int i0 = 0x7fffffff, i1 = 0x7fffffff, i2 = 0x7fffffff;
#pragma unroll
  for (int g = 0; g < 4; ++g) {
    int v = g * 64 + lane;
    if (v >= V_) break;
    float a = 0.f;
#pragma unroll
    for (int sp = 0; sp < DSPLIT_; ++sp)
      a += pdis[((size_t)sp * N_ + n) * VV_ + (size_t)u * V_ + v];
    if (a > m0 || (a == m0 && v < i0)) {
      m2 = m1; i2 = i1; m1 = m0; i1 = i0; m0 = a; i0 = v;
    } else if (a > m1 || (a == m1 && v < i1)) {
      m2 = m1; i2 = i1; m1 = a; i1 = v;
    } else if (a > m2 || (a == m2 && v < i2)) {
      m2 = a; i2 = v;
    }
  }
#pragma unroll
  for (int msk = 1; msk < 64; msk <<= 1) {
    float o0 = __shfl_xor(m0, msk, 64), o1 = __shfl_xor(m1, msk, 64),
          o2 = __shfl_xor(m2, msk, 64);
    int p0 = __shfl_xor(i0, msk, 64), p1 = __shfl_xor(i1, msk, 64),
        p2 = __shfl_xor(i2, msk, 64);
    float ov[3] = {o0, o1, o2};
    int op[3] = {p0, p1, p2};
#pragma unroll
    for (int e = 0; e < 3; ++e) {
      float a = ov[e]; int v = op[e];
      if (a > m0 || (a == m0 && v < i0)) {
        m2 = m1; i2 = i1; m1 = m0; i1 = i0; m0 = a; i0 = v;
      } else if (a > m1 || (a == m1 && v < i1)) {
        m2 = m1; i2 = i1; m1 = a; i1 = v;
      } else if (a > m2 || (a == m2 && v < i2)) {
        m2 = a; i2 = v;
      }
    }
  }
  if (lane == 0) {
    idx[r * 3 + 0] = i0; idx[r * 3 + 1] = i1; idx[r * 3 + 2] = i2;
  }
}

// ---------------- w2 ----------------
__global__ void k_w2(const float* __restrict__ cm, const int* __restrict__ idx,
                     const float* __restrict__ tw, const float* __restrict__ tb,
                     const float* __restrict__ ckw, float* __restrict__ w2) {
  int r = blockIdx.x;
  int n = r / V_;
  int lane = threadIdx.x;
  __shared__ float mv[3][C_];
  const int* ib = idx + r * 3;
  int j0 = ib[0], j1 = ib[1], j2 = ib[2];
  const float* cmn = cm + (size_t)n * C_ * V_;
  for (int c = lane; c < C_; c += 64) {
    mv[0][c] = cmn[c * V_ + j0];
    mv[1][c] = cmn[c * V_ + j1];
    mv[2][c] = cmn[c * V_ + j2];
  }
  __syncthreads();
  float p[9];
#pragma unroll
  for (int gp = 0; gp < 9; ++gp) p[gp] = 0.f;
  for (int c = lane; c < C_; c += 64) {
#pragma unroll
    for (int g = 0; g < 3; ++g) {
      float m = mv[g][c];
#pragma unroll
      for (int pp = 0; pp < 3; ++pp) p[g * 3 + pp] += m * tw[(g * 3 + pp) * C_ + c];
    }
  }
#pragma unroll
  for (int off = 32; off >= 1; off >>= 1) {
#pragma unroll
    for (int gp = 0; gp < 9; ++gp) p[gp] += __shfl_down(p[gp], off, 64);
  }
  if (lane == 0) {
    float c0 = ckw[0], c1 = ckw[1], c2 = ckw[2];
#pragma unroll
    for (int g = 0; g < 3; ++g) {
      float m0 = p[g * 3 + 0] + tb[g * 3 + 0];
      float m1 = p[g * 3 + 1] + tb[g * 3 + 1];
      float m2 = p[g * 3 + 2] + tb[g * 3 + 2];
      float mx = fmaxf(m0, fmaxf(m1, m2));
      float e0 = expf(m0 - mx), e1 = expf(m1 - mx), e2 = expf(m2 - mx);
      float inv = 1.0f / (e0 + e1 + e2);
      w2[r * 3 + g] = (e0 * c0 + e1 * c1 + e2 * c2) * inv;
    }
  }
}

// ---- x1 producer -> [n][v][t][c] bf16 only (residuals read bf16) ----
__global__ __launch_bounds__(256) void k_x1p(const float* __restrict__ x,
                                             const int* __restrict__ idx,
                                             const float* __restrict__ w2,
                                             const float* __restrict__ ckb,
                                             unsigned short* __restrict__ x1pb) {
  int t = blockIdx.x, ct = blockIdx.y, n = blockIdx.z;
  int c0 = ct * 32;
  __shared__ float Ts[32][209];
  __shared__ int iw[V_ * 3];
  __shared__ float ww[V_ * 3];
  int tid = threadIdx.x;
  const float* xb = x + ((size_t)n * C_ + c0) * TV_ + t * V_;
  for (int i = tid; i < 32 * V_; i += 256) {
    int c = i / V_, v = i - c * V_;
    Ts[c][v] = xb[(size_t)c * TV_ + v];
  }
  for (int i = tid; i < V_ * 3; i += 256) {
    iw[i] = idx[(size_t)n * V_ * 3 + i];
    ww[i] = w2[(size_t)n * V_ * 3 + i];
  }
  __syncthreads();
  float cb = ckb[0];
  for (int i = tid; i < 32 * V_; i += 256) {
    int v = i >> 5, cl = i & 31;
    int b = v * 3;
    float pooled = Ts[cl][iw[b]] * ww[b] + Ts[cl][iw[b + 1]] * ww[b + 1] +
                   Ts[cl][iw[b + 2]] * ww[b + 2] + cb;
    float val = fmaxf(pooled + Ts[cl][v], 0.f);
    x1pb[((size_t)(n * V_ + v) * T_ + t) * C_ + c0 + cl] = bf16rnd(val);
  }
}

// ---- MFMA GEMM: Y = W@X (X=[l'][c] bf16), M-loop in block, LDS-staged ----
// OBF=1: bf16 out [m][l'] + qpe bias.  OBF=0: bf16 out [l'][m] + bias, STATS partials.
template <int MCH, int OBF, int STATS>
__global__ __launch_bounds__(256) void k_gmm2(const unsigned short* __restrict__ Wb,
                                              const unsigned short* __restrict__ Xp,
                                              const float* __restrict__ addv,
                                              void* __restrict__ Yv,
                                              float* __restrict__ part) {
  int l0 = blockIdx.x * 128, n = blockIdx.z;
  __shared__ unsigned short Xs[128 * 136];
  __shared__ unsigned short Ys[64 * 128];
  int tid = threadIdx.x, lane = tid & 63, wid = tid >> 6;
  int wm = wid >> 1, wl = wid & 1;
  int lr = lane & 15, lg = lane >> 4;
  const unsigned short* xb = Xp + ((size_t)n * TV_ + l0) * 128;
#pragma unroll
  for (int it = 0; it < 8; ++it) {
    int g = tid + it * 256;
    int row = g >> 4, ch = g & 15;
    *(uint4*)&Xs[row * 136 + ch * 8] = *(const uint4*)(xb + (size_t)row * 128 + ch * 8);
  }
  __syncthreads();
  for (int mc = 0; mc < MCH; ++mc) {
    short8v a[2][4];
#pragma unroll
    for (int mi = 0; mi < 2; ++mi) {
      int m = mc * 64 + wm * 32 + mi * 16 + lr;
#pragma unroll
      for (int ks = 0; ks < 4; ++ks)
        a[mi][ks] = *(const short8v*)(Wb + (size_t)m * 128 + ks * 32 + lg * 8);
    }
    f32x4 acc[2][4];
#pragma unroll
    for (int mi = 0; mi < 2; ++mi)
#pragma unroll
      for (int li = 0; li < 4; ++li) acc[mi][li] = (f32x4){0.f, 0.f, 0.f, 0.f};
#pragma unroll
    for (int ks = 0; ks < 4; ++ks) {
#pragma unroll
      for (int li = 0; li < 4; ++li) {
        short8v b = *(const short8v*)&Xs[(wl * 64 + li * 16 + lr) * 136 + ks * 32 + lg * 8];
#pragma unroll
        for (int mi = 0; mi < 2; ++mi)
          acc[mi][li] = __builtin_amdgcn_mfma_f32_16x16x32_bf16(a[mi][ks], b, acc[mi][li], 0, 0, 0);
      }
    }
    if (OBF) {
      __syncthreads();
#pragma unroll
      for (int mi = 0; mi < 2; ++mi)
#pragma unroll
        for (int li = 0; li < 4; ++li) {
          int lloc = wl * 64 + li * 16 + lr;
          int tt = (l0 + lloc) & 63;
#pragma unroll
          for (int r = 0; r < 4; ++r) {
            int mloc = wm * 32 + mi * 16 + lg * 4 + r;
            float val = acc[mi][li][r] + addv[(mc * 64 + mloc) * 64 + tt];
            Ys[mloc * 128 + lloc] = bf16rnd(val);
          }
        }
      __syncthreads();
      unsigned short* Yh = (unsigned short*)Yv;
#pragma unroll
      for (int it = 0; it < 4; ++it) {
        int g = tid + it * 256;
        int row = g >> 4, ch = g & 15;
        *(uint4*)(Yh + ((size_t)n * O2_ + mc * 64 + row) * TV_ + l0 + ch * 8) =
            *(const uint4*)&Ys[row * 128 + ch * 8];
      }
    } else {
      unsigned short* Yh = (unsigned short*)Yv;
      float st1[2][4] = {}, st2[2][4] = {};
#pragma unroll
      for (int mi = 0; mi < 2; ++mi)
#pragma unroll
        for (int li = 0; li < 4; ++li) {
          int lp = l0 + wl * 64 + li * 16 + lr;
          int m = mc * 64 + wm * 32 + mi * 16 + lg * 4;
          unsigned short b4[4];
#pragma unroll
          for (int r = 0; r < 4; ++r) {
            float val = acc[mi][li][r] + addv[m + r];
            if (STATS) { st1[mi][r] += val; st2[mi][r] += val * val; }
            b4[r] = bf16rnd(val);
          }
          *(uint2*)(Yh + ((size_t)n * TV_ + lp) * 128 + m) = *(const uint2*)b4;
        }
      if (STATS) {
        int blk2 = ((n * gridDim.x + blockIdx.x) * 2 + wl) * 256;
#pragma unroll
        for (int mi = 0; mi < 2; ++mi)
#pragma unroll
          for (int r = 0; r < 4; ++r) {
            float a1 = st1[mi][r], a2 = st2[mi][r];
            a1 += __shfl_xor(a1, 1, 64); a2 += __shfl_xor(a2, 1, 64);
            a1 += __shfl_xor(a1, 2, 64); a2 += __shfl_xor(a2, 2, 64);
            a1 += __shfl_xor(a1, 4, 64); a2 += __shfl_xor(a2, 4, 64);
            a1 += __shfl_xor(a1, 8, 64); a2 += __shfl_xor(a2, 8, 64);
            if (lr == 0) {
              int m = mc * 64 + wm * 32 + mi * 16 + lg * 4 + r;
              part[blk2 + m] = a1;
              part[blk2 + 128 + m] = a2;
            }
          }
      }
    }
  }
}

// ---- attention partials (qkv bf16 [m][v][t]): attp[cp][n][h][t][q] ----
__global__ __launch_bounds__(256) void k_att(const unsigned short* __restrict__ qkv,
                                             float* __restrict__ attp) {
  int cp = blockIdx.x, h = blockIdx.y, n = blockIdx.z;
  __shared__ float Qs[102][68], Ks[102][68];
  int tid = threadIdx.x;
  int ty = tid >> 4, tx = tid & 15;
  float acc[4][4] = {};
  for (int cc = 0; cc < 2; ++cc) {
    int c = cp * 2 + cc;
    const unsigned short* qb = qkv + ((size_t)n * O2_ + h * QKD_ + c) * TV_;
    const unsigned short* kb = qkv + ((size_t)n * O2_ + H_ * QKD_ + h * QKD_ + c) * TV_;
    for (int vh = 0; vh < 2; ++vh) {
      for (int g = tid; g < 816; g += 256) {
        int v = g >> 3, t0 = (g & 7) * 8;
        uint4 qv = *(const uint4*)(qb + vh * 6528 + g * 8);
        uint4 kv = *(const uint4*)(kb + vh * 6528 + g * 8);
        const unsigned short* qs = (const unsigned short*)&qv;
        const unsigned short* ks2 = (const unsigned short*)&kv;
#pragma unroll
        for (int j = 0; j < 8; ++j) {
          Qs[v][t0 + j] = bf2f(qs[j]);
          Ks[v][t0 + j] = bf2f(ks2[j]);
        }
      }
      __syncthreads();
      for (int vv = 0; vv < 102; ++vv) {
        f32x4 qa = *(const f32x4*)&Qs[vv][ty * 4];
        f32x4 ka = *(const f32x4*)&Ks[vv][tx * 4];
#pragma unroll
        for (int i = 0; i < 4; ++i)
#pragma unroll
          for (int j = 0; j < 4; ++j) acc[i][j] += qa[i] * ka[j];
      }
      __syncthreads();
    }
  }
  float* ar = attp + (((size_t)cp * N_ + n) * H_ + h) * TT_;
#pragma unroll
  for (int i = 0; i < 4; ++i)
#pragma unroll
    for (int j = 0; j < 4; ++j)
      ar[(ty * 4 + i) * T_ + tx * 4 + j] = acc[i][j];
}

// ---- attT[n][q][h*64+t] = bf16(tanh(sum_cp attp /6528)*alpha + att1s) ----
__global__ void k_attfin(const float* __restrict__ attp, const float* __restrict__ alphas,
                         const float* __restrict__ att1s, unsigned short* __restrict__ attT) {
  int i = blockIdx.x * blockDim.x + threadIdx.x;
  if (i >= N_ * H_ * TT_) return;
  int tt = i % TT_;
  int h = (i / TT_) % H_;
  int n = i / (H_ * TT_);
  float raw = 0.f;
#pragma unroll
  for (int cp = 0; cp < 16; ++cp)
    raw += attp[(((size_t)cp * N_ + n) * H_ + h) * TT_ + tt];
  int t = tt >> 6, q = tt & 63;
  float v = tanhf(raw * (1.0f / 6528.0f)) * alphas[h] + att1s[h * TT_ + tt];
  attT[(size_t)(n * 64 + q) * 192 + h * 64 + t] = bf16rnd(v);
}

// ---- fused Y3+comb v2: X-frags in registers (loaded ONCE, reused 3 heads),
//      Yv double-buffered LDS (1 barrier per head), bf16 output via LDS repack,
//      fused BN stat partials. ----
__global__ __launch_bounds__(256) void k_fcomb(const unsigned short* __restrict__ x1pb,
                                               const unsigned short* __restrict__ w3b,
                                               const unsigned short* __restrict__ attT,
                                               const float* __restrict__ outb,
                                               unsigned short* __restrict__ preb,
                                               float* __restrict__ part) {
  int v = blockIdx.x, n = blockIdx.z;
  __shared__ unsigned short Yv[2][128 * 68];  // [buf][o][t] padded (136B rows)
  int tid = threadIdx.x, lane = tid & 63, wid = tid >> 6;
  int lr = lane & 15, lg = lane >> 4;
  const unsigned short* xb = x1pb + ((size_t)(n * V_ + v) * T_) * 128;
  // X fragments: 16 x 16B loads, register-resident across all 3 heads
  short8v bx[4][4];
#pragma unroll
  for (int ks = 0; ks < 4; ++ks)
#pragma unroll
    for (int li = 0; li < 4; ++li)
      bx[ks][li] = *(const short8v*)(xb + (size_t)(li * 16 + lr) * 128 + ks * 32 + lg * 8);
  f32x4 acc2[4][2];
#pragma unroll
  for (int mq = 0; mq < 4; ++mq)
#pragma unroll
    for (int oi = 0; oi < 2; ++oi) acc2[mq][oi] = (f32x4){0.f, 0.f, 0.f, 0.f};
  const unsigned short* ab = attT + (size_t)n * 64 * 192;
  for (int h = 0; h < H_; ++h) {
    unsigned short* Yc = Yv[h & 1];
    short8v a1[2][4];
#pragma unroll
    for (int mi = 0; mi < 2; ++mi) {
      int m = wid * 32 + mi * 16 + lr;
#pragma unroll
      for (int ks = 0; ks < 4; ++ks)
        a1[mi][ks] = *(const short8v*)(w3b + ((size_t)(h * 128 + m)) * 128 + ks * 32 + lg * 8);
    }
    f32x4 acc1[2][4];
#pragma unroll
    for (int mi = 0; mi < 2; ++mi)
#pragma unroll
      for (int li = 0; li < 4; ++li) acc1[mi][li] = (f32x4){0.f, 0.f, 0.f, 0.f};
#pragma unroll
    for (int ks = 0; ks < 4; ++ks)
#pragma unroll
      for (int li = 0; li < 4; ++li)
#pragma unroll
        for (int mi = 0; mi < 2; ++mi)
          acc1[mi][li] = __builtin_amdgcn_mfma_f32_16x16x32_bf16(a1[mi][ks], bx[ks][li],
                                                                 acc1[mi][li], 0, 0, 0);
    // write Yv[h&1]: WAR vs comb(h-2) reads is covered by the h-1 barrier
#pragma unroll
    for (int mi = 0; mi < 2; ++mi)
#pragma unroll
      for (int li = 0; li < 4; ++li) {
        int t = li * 16 + lr;
#pragma unroll
        for (int r = 0; r < 4; ++r) {
          int o = wid * 32 + mi * 16 + lg * 4 + r;
          Yc[o * 68 + t] = bf16rnd(acc1[mi][li][r]);
        }
      }
    __syncthreads();
#pragma unroll
    for (int ks2 = 0; ks2 < 2; ++ks2) {
      short8v bY[2];
#pragma unroll
      for (int oi = 0; oi < 2; ++oi)
        bY[oi] = *(const short8v*)&Yc[(wid * 32 + oi * 16 + lr) * 68 + ks2 * 32 + lg * 8];
#pragma unroll
      for (int mq = 0; mq < 4; ++mq) {
        short8v a2 = *(const short8v*)(ab + (size_t)(mq * 16 + lr) * 192 + h * 64 + ks2 * 32 + lg * 8);
#pragma unroll
        for (int oi = 0; oi < 2; ++oi)
          acc2[mq][oi] = __builtin_amdgcn_mfma_f32_16x16x32_bf16(a2, bY[oi], acc2[mq][oi], 0, 0, 0);
      }
    }
  }
  // epilogue: stats from registers + repack through Yv[1] (last read of Yv[1]
  // was comb(h=1), fenced by the h=2 barrier) -> coalesced bf16 store [q][o]
  unsigned short* Ys2 = Yv[1];  // [q][136-pad shorts]
  float s1[2] = {0.f, 0.f}, s2[2] = {0.f, 0.f};
#pragma unroll
  for (int mq = 0; mq < 4; ++mq)
#pragma unroll
    for (int oi = 0; oi < 2; ++oi) {
      int o = wid * 32 + oi * 16 + lr;
      float bo = outb[o];
#pragma unroll
      for (int r = 0; r < 4; ++r) {
        int q = mq * 16 + lg * 4 + r;
        float val = acc2[mq][oi][r] + bo;
        s1[oi] += val; s2[oi] += val * val;
        Ys2[q * 136 + o] = bf16rnd(val);
      }
    }
  int blk = (n * V_ + v) * 256;
#pragma unroll
  for (int oi = 0; oi < 2; ++oi) {
    float a1 = s1[oi], a2 = s2[oi];
    a1 += __shfl_xor(a1, 16, 64); a2 += __shfl_xor(a2, 16, 64);
    a1 += __shfl_xor(a1, 32, 64); a2 += __shfl_xor(a2, 32, 64);
    if ((lane & 48) == 0) {
      int o = wid * 32 + oi * 16 + lr;
      part[blk + o] = a1;
      part[blk + 128 + o] = a2;
    }
  }
  __syncthreads();
  unsigned short* ob2 = preb + ((size_t)(n * V_ + v) * T_) * 128;
#pragma unroll
  for (int it = 0; it < 4; ++it) {
    int g = tid + it * 256;
    int row = g >> 4, ch = g & 15;
    *(uint4*)(ob2 + (size_t)row * 128 + ch * 8) = *(const uint4*)&Ys2[row * 136 + ch * 8];
  }
}

// ---- fold NBLK_ stat partials -> ab[c]=a, ab[128+c]=b; grid 128 (c) ----
__global__ void k_bnab(const float* __restrict__ part, const float* __restrict__ g,
                       const float* __restrict__ beta, float* __restrict__ ab) {
  int c = blockIdx.x;
  int tid = threadIdx.x;
  float s1 = 0.f, s2 = 0.f;
  for (int b = tid; b < NBLK_; b += 256) {
    s1 += part[b * 256 + c];
    s2 += part[b * 256 + 128 + c];
  }
  __shared__ float r1[256], r2[256];
  r1[tid] = s1; r2[tid] = s2;
  __syncthreads();
  for (int off = 128; off >= 1; off >>= 1) {
    if (tid < off) { r1[tid] += r1[tid + off]; r2[tid] += r2[tid + off]; }
    __syncthreads();
  }
  if (tid == 0) {
    const float cnt = (float)(N_ * TV_);
    float mu = r1[0] / cnt;
    float rstd = rsqrtf(r2[0] / cnt - mu * mu + 1e-5f);
    float a = rstd * g[c];
    ab[c] = a;
    ab[128 + c] = beta[c] - mu * a;
  }
}

// ---- xs3pb = bf16(leaky(bn(preb)+x1pb)), elementwise [l'][c], all bf16 ----
__global__ void k_bnxt(const unsigned short* __restrict__ preb,
                       const unsigned short* __restrict__ x1pb,
                       const float* __restrict__ ab, unsigned short* __restrict__ xt) {
  __shared__ float sa[128], sb[128];
  int tid = threadIdx.x;
  if (tid < 128) { sa[tid] = ab[tid]; sb[tid] = ab[128 + tid]; }
  __syncthreads();
  const unsigned NU = (unsigned)(NCTV_ / 8);
  const uint4* p4 = (const uint4*)preb;
  const uint4* r4 = (const uint4*)x1pb;
  for (unsigned u = blockIdx.x * 256u + tid; u < NU; u += gridDim.x * 256u) {
    int c8 = (u & 15) * 8;
    uint4 pv = p4[u], rv = r4[u];
    const unsigned short* ps = (const unsigned short*)&pv;
    const unsigned short* rs = (const unsigned short*)&rv;
    unsigned short buf[8];
#pragma unroll
    for (int j = 0; j < 8; ++j) {
      float t = bf2f(ps[j]) * sa[c8 + j] + sb[c8 + j] + bf2f(rs[j]);
      buf[j] = bf16rnd(t > 0.f ? t : 0.1f * t);
    }
    *(uint4*)(xt + (size_t)u * 8) = *(const uint4*)buf;
  }
}

// ---- final: leaky(bn(preb)+x1pb), transpose [v][t][c] -> d_out [c][t][v] fp32 ----
__global__ __launch_bounds__(256) void k_bnfinal(const unsigned short* __restrict__ preb,
                                                 const unsigned short* __restrict__ x1pb,
                                                 const float* __restrict__ ab,
                                                 float* __restrict__ dout) {
  int ct = blockIdx.x, t = blockIdx.y, n = blockIdx.z;
  int c0 = ct * 32;
  __shared__ float Tf[V_][33];
  __shared__ float sa[32], sb[32];
  int tid = threadIdx.x;
  if (tid < 32) { sa[tid] = ab[c0 + tid]; sb[tid] = ab[128 + c0 + tid]; }
  __syncthreads();
  for (int i = tid; i < V_ * 4; i += 256) {
    int v = i >> 2, ch = i & 3;
    size_t a = ((size_t)(n * V_ + v) * T_ + t) * 128 + c0 + ch * 8;
    uint4 pv = *(const uint4*)(preb + a);
    uint4 rv = *(const uint4*)(x1pb + a);
    const unsigned short* ps = (const unsigned short*)&pv;
    const unsigned short* rs = (const unsigned short*)&rv;
#pragma unroll
    for (int j = 0; j < 8; ++j) {
      int cl = ch * 8 + j;
      float val = bf2f(ps[j]) * sa[cl] + sb[cl] + bf2f(rs[j]);
      Tf[v][cl] = val > 0.f ? val : 0.1f * val;
    }
  }
  __syncthreads();
  for (int i = tid; i < 32 * V_; i += 256) {
    int cl = i / V_, v = i - cl * V_;
    dout[((size_t)(n * C_ + c0 + cl) * T_ + t) * V_ + v] = Tf[v][cl];
  }
}

extern "C" void kernel_launch(void* const* d_in, const int* in_sizes, int n_in,
                              void* d_out, int out_size, void* d_ws, size_t ws_size,
                              hipStream_t stream) {
  (void)in_sizes; (void)n_in; (void)out_size; (void)ws_size;
  const float* x        = (const float*)d_in[0];
  const float* trans_w  = (const float*)d_in[1];
  const float* trans_b  = (const float*)d_in[2];
  const float* convk_w  = (const float*)d_in[3];
  const float* convk_b  = (const float*)d_in[4];
  const float* qkv_w    = (const float*)d_in[5];
  const float* qkv_b    = (const float*)d_in[6];
  const float* alphas   = (const float*)d_in[7];
  const float* att1s    = (const float*)d_in[8];
  const float* out_w    = (const float*)d_in[9];
  const float* out_b    = (const float*)d_in[10];
  const float* out_g    = (const float*)d_in[11];
  const float* out_beta = (const float*)d_in[12];
  const float* ff_w     = (const float*)d_in[13];
  const float* ff_b     = (const float*)d_in[14];
  const float* ff_g     = (const float*)d_in[15];
  const float* ff_beta  = (const float*)d_in[16];

  float* ws = (float*)d_ws;
  size_t off = 0;
  // qkvb (10.03M fl) + preb (6.69M fl) adjacent; pdis (10.65M fl) aliases both
  // (pdis lives only between k_dism and k_topk2; qkvb/preb written later).
  float* gq = ws + off; off += (size_t)N_ * O2_ * TV_ / 2 + NCTV_ / 2;
  float* pdis = gq;
  unsigned short* qkvb = (unsigned short*)gq;
  unsigned short* preb = (unsigned short*)(gq + (size_t)N_ * O2_ * TV_ / 2);
  float* sbuf = ws + off; off += (size_t)N_ * CT_;
  int*   idx  = (int*)(ws + off); off += (size_t)N_ * V_ * 3 + 4;
  float* cm   = ws + off; off += (size_t)N_ * C_ * V_;
  float* w2   = ws + off; off += (size_t)N_ * V_ * 3 + 4;
  float* attp = ws + off; off += (size_t)16 * N_ * H_ * TT_;
  unsigned short* attT = (unsigned short*)(ws + off); off += (size_t)N_ * 64 * 192 / 2;
  float* part = ws + off; off += (size_t)NBLK_ * 256;
  float* ab   = ws + off; off += 512;
  float* qpe  = ws + off; off += (size_t)O2_ * T_;
  unsigned short* wb = (unsigned short*)(ws + off); off += 704 * 128 / 2;
  const size_t ZEL = (size_t)N_ * 1024 * ZR_ * 8;
  unsigned short* zhi = (unsigned short*)(ws + off);  // overlay: x1pb after dis
  unsigned short* zlo = zhi + ZEL;                    // overlay: xs3pb after dis
  off += ZEL;
  unsigned short* x1pb  = zhi;
  unsigned short* xs3pb = zlo;
  float* dout = (float*)d_out;

  k_wprep<<<44, 256, 0, stream>>>(qkv_w, out_w, ff_w, wb);
  k_qkvpe<<<48, 256, 0, stream>>>(qkv_w, qkv_b, qpe);
  k_scale<<<(N_ * CT_ * 64) / 256, 256, 0, stream>>>(x, sbuf);
  k_zprep<<<dim3(128, 4, N_), 256, 0, stream>>>(x, sbuf, zhi, zlo, cm);
  k_dism<<<dim3(3, DSPLIT_, N_), 256, 0, stream>>>(zhi, zlo, pdis);
  k_topk2<<<N_ * V_, 64, 0, stream>>>(pdis, idx);
  k_w2<<<N_ * V_, 64, 0, stream>>>(cm, idx, trans_w, trans_b, convk_w, w2);
  k_x1p<<<dim3(64, 4, N_), 256, 0, stream>>>(x, idx, w2, convk_b, x1pb);

  // qkv = Wq@x1 + qkv_b + pe-bias -> qkvb bf16 [m][v][t]
  k_gmm2<3, 1, 0><<<dim3(102, 1, N_), 256, 0, stream>>>(wb, x1pb, qpe, qkvb, nullptr);
  k_att<<<dim3(16, H_, N_), 256, 0, stream>>>(qkvb, attp);
  k_attfin<<<384, 256, 0, stream>>>(attp, alphas, att1s, attT);

  // out_pre = fused (W3h@x1v) x attn -> preb bf16 [v][t][c], + BN stat partials
  k_fcomb<<<dim3(204, 1, N_), 256, 0, stream>>>(x1pb, wb + 192 * 128, attT, out_b, preb, part);

  k_bnab<<<128, 256, 0, stream>>>(part, out_g, out_beta, ab);
  k_bnxt<<<2048, 256, 0, stream>>>(preb, x1pb, ab, xs3pb);

  // ff_pre = Wff@xs3 + ff_b -> preb bf16 (overwrite), + BN stat partials
  k_gmm2<2, 0, 1><<<dim3(102, 1, N_), 256, 0, stream>>>(wb + 576 * 128, xs3pb, ff_b, preb, part);
  k_bnab<<<128, 256, 0, stream>>>(part, ff_g, ff_beta, ab + 256);
  k_bnfinal<<<dim3(4, 64, N_), 256, 0, stream>>>(preb, x1pb, ab + 256, dout);
}